// Round 5
// baseline (996.770 us; speedup 1.0000x reference)
//
#include <hip/hip_runtime.h>

// ---------------------------------------------------------------------------
// StrongFormPhysicsLoss, round 5: fused direct-to-slot CSR records, sized to
// fit a ~256MB workspace.
//   K1 prep_pass : pack [N][12] node block (streamed) + degree count atomics
//                  (fused in one launch so atomics overlap streaming)
//   K2-K4 scan   : exclusive scan of degrees -> offs
//   K5 elem_full : physics + cursor atomicAdd on offs + direct 48B record
//                  writes at final CSR slots (no payload, no scatter kernel)
//   K6 node_seq  : sequential record stream + masked reductions
//                  (base = offs[k]-counts[k]; offs are end-pointers now)
//   K7 finalize
// ws tiers: >=249MB new path; >=173MB legacy packed; else legacy unpacked.
// ---------------------------------------------------------------------------

typedef __attribute__((ext_vector_type(4))) float f4;
typedef __attribute__((ext_vector_type(2))) int   i2;

struct Scal {
    double rkin2, e1, e2, Lsum;
    double Fe2, F2, Mr2, Mp2;
    unsigned int qmax_bits, Lmax_bits;
    unsigned int cnt_d, cnt_r, cnt_p;
};

__device__ __forceinline__ double waveSumD(double v) {
#pragma unroll
    for (int o = 32; o > 0; o >>= 1) v += __shfl_down(v, o, 64);
    return v;
}
__device__ __forceinline__ float waveMaxF(float v) {
#pragma unroll
    for (int o = 32; o > 0; o >>= 1) v = fmaxf(v, __shfl_down(v, o, 64));
    return v;
}
__device__ __forceinline__ unsigned waveSumU(unsigned v) {
#pragma unroll
    for (int o = 32; o > 0; o >>= 1) v += __shfl_down(v, o, 64);
    return v;
}

__device__ __forceinline__ void blockAtomicAddD(double v, double* dst, double* smem) {
    v = waveSumD(v);
    const int lane = threadIdx.x & 63, wid = threadIdx.x >> 6;
    if (lane == 0) smem[wid] = v;
    __syncthreads();
    if (threadIdx.x == 0) atomicAdd(dst, smem[0] + smem[1] + smem[2] + smem[3]);
    __syncthreads();
}
__device__ __forceinline__ void blockAtomicMaxF(float v, unsigned int* dst, float* smem) {
    v = waveMaxF(v);
    const int lane = threadIdx.x & 63, wid = threadIdx.x >> 6;
    if (lane == 0) smem[wid] = v;
    __syncthreads();
    if (threadIdx.x == 0) {
        float r = fmaxf(fmaxf(smem[0], smem[1]), fmaxf(smem[2], smem[3]));
        atomicMax(dst, __float_as_uint(fmaxf(r, 0.0f)));
    }
    __syncthreads();
}
__device__ __forceinline__ void blockAtomicAddU(unsigned v, unsigned int* dst, unsigned* smem) {
    v = waveSumU(v);
    const int lane = threadIdx.x & 63, wid = threadIdx.x >> 6;
    if (lane == 0) smem[wid] = v;
    __syncthreads();
    if (threadIdx.x == 0) atomicAdd(dst, smem[0] + smem[1] + smem[2] + smem[3]);
    __syncthreads();
}

// ---------------------------------------------------------------------------
// pack[k][0:3]=pred, [3:6]=grad_ux, [6:9]=grad_uz, [9:12]=grad_phi (48B/node)
__device__ __forceinline__ void pack_one(
    const float* __restrict__ pred, const float* __restrict__ gux,
    const float* __restrict__ guz,  const float* __restrict__ gphi,
    float* __restrict__ pack, int k)
{
    const size_t b3 = 3 * (size_t)k;
    f4 A = {__builtin_nontemporal_load(pred + b3),
            __builtin_nontemporal_load(pred + b3 + 1),
            __builtin_nontemporal_load(pred + b3 + 2),
            __builtin_nontemporal_load(gux + b3)};
    f4 B = {__builtin_nontemporal_load(gux + b3 + 1),
            __builtin_nontemporal_load(gux + b3 + 2),
            __builtin_nontemporal_load(guz + b3),
            __builtin_nontemporal_load(guz + b3 + 1)};
    f4 C = {__builtin_nontemporal_load(guz + b3 + 2),
            __builtin_nontemporal_load(gphi + b3),
            __builtin_nontemporal_load(gphi + b3 + 1),
            __builtin_nontemporal_load(gphi + b3 + 2)};
    f4* o = (f4*)(pack + 12 * (size_t)k);
    o[0] = A; o[1] = B; o[2] = C;   // regular stores: want L2/L3 residency
}

__global__ __launch_bounds__(256) void pack_nodes(
    const float* __restrict__ pred, const float* __restrict__ gux,
    const float* __restrict__ guz,  const float* __restrict__ gphi,
    float* __restrict__ pack, int n)
{
    const int k = blockIdx.x * blockDim.x + threadIdx.x;
    if (k < n) pack_one(pred, gux, guz, gphi, pack, k);
}

// fused: blocks [0,nblkPack) pack nodes; blocks [nblkPack,..) count degrees
__global__ __launch_bounds__(256) void prep_pass(
    const float* __restrict__ pred, const float* __restrict__ gux,
    const float* __restrict__ guz,  const float* __restrict__ gphi,
    float* __restrict__ pack, int n_nodes, int nblkPack,
    const int* __restrict__ conn, unsigned int* __restrict__ counts, int n_elems)
{
    if ((int)blockIdx.x < nblkPack) {
        const int k = blockIdx.x * 256 + threadIdx.x;
        if (k < n_nodes) pack_one(pred, gux, guz, gphi, pack, k);
    } else {
        const int e = (blockIdx.x - nblkPack) * 256 + threadIdx.x;
        if (e < n_elems) {
            const i2 ij = __builtin_nontemporal_load((const i2*)conn + e);
            atomicAdd(&counts[ij.x], 1u);   // fire-and-forget
            atomicAdd(&counts[ij.y], 1u);
        }
    }
}

// ---------------------------------------------------------------------------
// shared physics body: computes record pieces + element reductions
struct ElemOut {
    float Fe0, Fe1, Fe2, Mi0, Mi1, Mi2, Mj0, Mj1, Mj2, E0, E1, E2;
    float rkin, d1, d2, Le, l0, l1, l2;
};

template <bool PACKED>
__device__ __forceinline__ ElemOut elem_body(
    const float* __restrict__ pred, const float* __restrict__ grad_ux,
    const float* __restrict__ grad_uz, const float* __restrict__ grad_phi,
    const float* __restrict__ pack,
    const float* __restrict__ prop_E, const float* __restrict__ prop_A,
    const float* __restrict__ prop_I22, const float* __restrict__ elemL,
    const float* __restrict__ dirs, const float* __restrict__ load,
    int e, int i, int j)
{
    const float x0 = __builtin_nontemporal_load(dirs + 3 * e);
    const float x1 = __builtin_nontemporal_load(dirs + 3 * e + 1);
    const float x2 = __builtin_nontemporal_load(dirs + 3 * e + 2);

    const bool par = fabsf(x1) > 0.99f;
    float z0, z1, z2;
    if (par) { z0 = x1; z1 = -x0; z2 = 0.0f; }
    else     { z0 = -x2; z1 = 0.0f; z2 = x0; }
    float zn = fmaxf(sqrtf(z0 * z0 + z1 * z1 + z2 * z2), 1e-8f);
    z0 /= zn; z1 /= zn; z2 /= zn;
    float y0 = z1 * x2 - z2 * x1;
    float y1 = z2 * x0 - z0 * x2;
    float y2 = z0 * x1 - z1 * x0;
    float yn = fmaxf(sqrtf(y0 * y0 + y1 * y1 + y2 * y2), 1e-8f);
    y0 /= yn; y1 /= yn; y2 /= yn;

    float uxi, uzi, phii, uxj, uzj, phij;
    float gxi, gzi, kap_i, gxj, gzj, kap_j;
    if (PACKED) {
        const f4* pi = (const f4*)(pack + 12 * (size_t)i);
        const f4 a = pi[0], b = pi[1], c = pi[2];
        uxi = a.x; uzi = a.y; phii = a.z;
        gxi   = a.w * x0 + b.x * x1 + b.y * x2;
        gzi   = b.z * x0 + b.w * x1 + c.x * x2;
        kap_i = c.y * x0 + c.z * x1 + c.w * x2;
        const f4* pj = (const f4*)(pack + 12 * (size_t)j);
        const f4 d = pj[0], f = pj[1], g = pj[2];
        uxj = d.x; uzj = d.y; phij = d.z;
        gxj   = d.w * x0 + f.x * x1 + f.y * x2;
        gzj   = f.z * x0 + f.w * x1 + g.x * x2;
        kap_j = g.y * x0 + g.z * x1 + g.w * x2;
    } else {
        uxi = pred[3 * i]; uzi = pred[3 * i + 1]; phii = pred[3 * i + 2];
        uxj = pred[3 * j]; uzj = pred[3 * j + 1]; phij = pred[3 * j + 2];
        gxi   = grad_ux[3 * i] * x0 + grad_ux[3 * i + 1] * x1 + grad_ux[3 * i + 2] * x2;
        gzi   = grad_uz[3 * i] * x0 + grad_uz[3 * i + 1] * x1 + grad_uz[3 * i + 2] * x2;
        kap_i = grad_phi[3 * i] * x0 + grad_phi[3 * i + 1] * x1 + grad_phi[3 * i + 2] * x2;
        gxj   = grad_ux[3 * j] * x0 + grad_ux[3 * j + 1] * x1 + grad_ux[3 * j + 2] * x2;
        gzj   = grad_uz[3 * j] * x0 + grad_uz[3 * j + 1] * x1 + grad_uz[3 * j + 2] * x2;
        kap_j = grad_phi[3 * j] * x0 + grad_phi[3 * j + 1] * x1 + grad_phi[3 * j + 2] * x2;
    }
    const float dux = uxj - uxi, duz = uzj - uzi;

    const float Le   = __builtin_nontemporal_load(elemL + e);
    const float invL = 1.0f / Le;
    const float pE   = __builtin_nontemporal_load(prop_E + e);
    const float EA   = pE * __builtin_nontemporal_load(prop_A + e);
    const float EI   = pE * __builtin_nontemporal_load(prop_I22 + e);

    const float du_ax  = dux * x0 + duz * x2;
    const float eps_fd = du_ax * invL;
    const float N_fd   = EA * eps_fd;
    const float du_tr  = dux * z0 + duz * z2;
    const float kappa_fd = (phij - phii) * invL;

    const float EIL = EI * invL, EIL2 = EIL * invL, EIL3 = EIL2 * invL;
    const float V_fd = 12.0f * EIL3 * du_tr - 6.0f * EIL2 * (phii + phij);
    const float M_yi = 6.0f * EIL2 * du_tr - EIL * (4.0f * phii + 2.0f * phij);
    const float M_yj = 6.0f * EIL2 * du_tr - EIL * (2.0f * phii + 4.0f * phij);

    const float eps_ag   = 0.5f * ((x0 * gxi + x2 * gzi) + (x0 * gxj + x2 * gzj));
    const float kappa_ag = 0.5f * (kap_i + kap_j);

    const float l0 = __builtin_nontemporal_load(load + 3 * e);
    const float l1 = __builtin_nontemporal_load(load + 3 * e + 1);
    const float l2 = __builtin_nontemporal_load(load + 3 * e + 2);
    const float hl = 0.5f * Le;

    ElemOut o;
    o.Fe0 = N_fd * x0 + V_fd * z0;
    o.Fe1 = N_fd * x1 + V_fd * z1;
    o.Fe2 = N_fd * x2 + V_fd * z2;
    o.Mi0 = M_yi * y0; o.Mi1 = M_yi * y1; o.Mi2 = M_yi * y2;
    o.Mj0 = M_yj * y0; o.Mj1 = M_yj * y1; o.Mj2 = M_yj * y2;
    o.E0 = l0 * hl; o.E1 = l1 * hl; o.E2 = l2 * hl;
    o.rkin = 0.5f * (phii + phij) - du_tr * invL;
    o.d1 = eps_ag - eps_fd;
    o.d2 = kappa_ag - kappa_fd;
    o.Le = Le; o.l0 = l0; o.l1 = l1; o.l2 = l2;
    return o;
}

__device__ __forceinline__ void elem_reduce_tail(
    const ElemOut& o, double& s_rkin2, double& s_e1, double& s_e2,
    double& s_Lsum, float& m_q, float& m_L)
{
    s_rkin2 += (double)(o.rkin * o.rkin);
    s_e1 += (double)(o.d1 * o.d1);
    s_e2 += (double)(o.d2 * o.d2);
    s_Lsum += (double)o.Le;
    m_q = fmaxf(m_q, fmaxf(fabsf(o.l0), fmaxf(fabsf(o.l1), fabsf(o.l2))));
    m_L = fmaxf(m_L, o.Le);
}

// --- new path: physics + direct 48B record write at cursor slot ------------
// record (12 f32): [F0,F1,F2,M0][M1,M2,E0,E1][E2,0,0,0]
__global__ __launch_bounds__(256) void elem_full(
    const float* __restrict__ pack,
    const float* __restrict__ prop_E, const float* __restrict__ prop_A,
    const float* __restrict__ prop_I22, const float* __restrict__ elemL,
    const float* __restrict__ dirs, const float* __restrict__ load,
    const int* __restrict__ conn,
    unsigned int* __restrict__ offs,     // cursors: exclusive-scan values, mutated!
    float* __restrict__ recs,
    Scal* sc, int n_elems)
{
    __shared__ double smD[4];
    __shared__ float  smF[4];

    double s_rkin2 = 0.0, s_e1 = 0.0, s_e2 = 0.0, s_Lsum = 0.0;
    float m_q = 0.0f, m_L = 0.0f;

    const int e = blockIdx.x * 256 + threadIdx.x;
    if (e < n_elems) {
        const i2 ij = __builtin_nontemporal_load((const i2*)conn + e);
        const int i = ij.x, j = ij.y;

        // claim slots early (latency overlaps the physics below)
        const unsigned slot_i = atomicAdd(&offs[i], 1u);
        const unsigned slot_j = atomicAdd(&offs[j], 1u);

        const ElemOut o = elem_body<true>(nullptr, nullptr, nullptr, nullptr, pack,
                                          prop_E, prop_A, prop_I22, elemL, dirs, load,
                                          e, i, j);

        f4* ri = (f4*)(recs + 12 * (size_t)slot_i);
        f4 a0 = {o.Fe0, o.Fe1, o.Fe2, o.Mi0};
        f4 a1 = {o.Mi1, o.Mi2, o.E0, o.E1};
        f4 a2 = {o.E2, 0.f, 0.f, 0.f};
        __builtin_nontemporal_store(a0, ri + 0);
        __builtin_nontemporal_store(a1, ri + 1);
        __builtin_nontemporal_store(a2, ri + 2);

        f4* rj = (f4*)(recs + 12 * (size_t)slot_j);
        f4 b0 = {-o.Fe0, -o.Fe1, -o.Fe2, o.Mj0};
        f4 b1 = {o.Mj1, o.Mj2, o.E0, o.E1};
        __builtin_nontemporal_store(b0, rj + 0);
        __builtin_nontemporal_store(b1, rj + 1);
        __builtin_nontemporal_store(a2, rj + 2);

        elem_reduce_tail(o, s_rkin2, s_e1, s_e2, s_Lsum, m_q, m_L);
    }

    blockAtomicAddD(s_rkin2, &sc->rkin2, smD);
    blockAtomicAddD(s_e1,    &sc->e1,    smD);
    blockAtomicAddD(s_e2,    &sc->e2,    smD);
    blockAtomicAddD(s_Lsum,  &sc->Lsum,  smD);
    blockAtomicMaxF(m_q, &sc->qmax_bits, smF);
    blockAtomicMaxF(m_L, &sc->Lmax_bits, smF);
}

__global__ __launch_bounds__(256) void node_seq(
    const float* __restrict__ recs,
    const unsigned int* __restrict__ offs_end, const unsigned int* __restrict__ counts,
    const float* __restrict__ bc_disp, const float* __restrict__ bc_rot,
    Scal* sc, int n_nodes)
{
    __shared__ double smD[4];
    __shared__ unsigned smU[4];

    double sFe2 = 0.0, sF2 = 0.0, sMr2 = 0.0, sMp2 = 0.0;
    unsigned cd = 0, cr = 0, cp = 0;

    const int k = blockIdx.x * 256 + threadIdx.x;
    if (k < n_nodes) {
        const unsigned deg  = counts[k];
        const unsigned base = offs_end[k] - deg;   // offs were incremented to end

        float F0 = 0.f, F1 = 0.f, F2 = 0.f;
        float M0 = 0.f, M1 = 0.f, M2 = 0.f;
        float E0 = 0.f, E1 = 0.f, E2 = 0.f;

        for (unsigned d = 0; d < deg; ++d) {
            const f4* r = (const f4*)(recs + 12 * (size_t)(base + d));
            const f4 r0 = __builtin_nontemporal_load(r + 0);
            const f4 r1 = __builtin_nontemporal_load(r + 1);
            const f4 r2 = __builtin_nontemporal_load(r + 2);
            F0 += r0.x; F1 += r0.y; F2 += r0.z;
            M0 += r0.w; M1 += r1.x; M2 += r1.y;
            E0 += r1.z; E1 += r1.w; E2 += r2.x;
        }

        const float bd = bc_disp[k], br = bc_rot[k];
        const bool free_d = bd < 0.5f;
        const bool free_r = br < 0.5f;
        const bool pin    = (bd > 0.5f) && free_r;

        if (free_d) {
            const float f0 = F0 + E0, f1 = F1 + E1, f2 = F2 + E2;
            sFe2 += (double)(E0 * E0 + E1 * E1 + E2 * E2);
            sF2  += (double)(f0 * f0 + f1 * f1 + f2 * f2);
            cd++;
        }
        if (free_r) { sMr2 += (double)(M0 * M0 + M1 * M1 + M2 * M2); cr++; }
        if (pin)    { sMp2 += (double)(M0 * M0 + M1 * M1 + M2 * M2); cp++; }
    }

    blockAtomicAddD(sFe2, &sc->Fe2, smD);
    blockAtomicAddD(sF2,  &sc->F2,  smD);
    blockAtomicAddD(sMr2, &sc->Mr2, smD);
    blockAtomicAddD(sMp2, &sc->Mp2, smD);
    blockAtomicAddU(cd, &sc->cnt_d, smU);
    blockAtomicAddU(cr, &sc->cnt_r, smU);
    blockAtomicAddU(cp, &sc->cnt_p, smU);
}

// --- scans ------------------------------------------------------------------
__global__ __launch_bounds__(256) void scan1(
    const unsigned int* __restrict__ counts, unsigned int* __restrict__ partial, int n)
{
    __shared__ unsigned smU[4];
    const int idx = blockIdx.x * 256 + threadIdx.x;
    unsigned v = (idx < n) ? counts[idx] : 0u;
    v = waveSumU(v);
    const int lane = threadIdx.x & 63, wid = threadIdx.x >> 6;
    if (lane == 0) smU[wid] = v;
    __syncthreads();
    if (threadIdx.x == 0) partial[blockIdx.x] = smU[0] + smU[1] + smU[2] + smU[3];
}

__global__ __launch_bounds__(1024) void scan2(unsigned int* partial, int nblk)
{
    __shared__ unsigned sm[1024];
    const int t = threadIdx.x;
    const int base = t * 4;
    unsigned v[4];
    unsigned run = 0;
#pragma unroll
    for (int c = 0; c < 4; ++c) {
        unsigned x = (base + c < nblk) ? partial[base + c] : 0u;
        v[c] = run;
        run += x;
    }
    sm[t] = run;
    __syncthreads();
    for (int off = 1; off < 1024; off <<= 1) {
        unsigned x = (t >= off) ? sm[t - off] : 0u;
        __syncthreads();
        sm[t] += x;
        __syncthreads();
    }
    const unsigned chunkExcl = (t == 0) ? 0u : sm[t - 1];
#pragma unroll
    for (int c = 0; c < 4; ++c)
        if (base + c < nblk) partial[base + c] = chunkExcl + v[c];
}

__global__ __launch_bounds__(256) void scan3(
    const unsigned int* __restrict__ counts, const unsigned int* __restrict__ partial,
    unsigned int* __restrict__ offs, int n)
{
    __shared__ unsigned sm[256];
    const int t = threadIdx.x;
    const int idx = blockIdx.x * 256 + t;
    const unsigned v = (idx < n) ? counts[idx] : 0u;
    sm[t] = v;
    __syncthreads();
    for (int off = 1; off < 256; off <<= 1) {
        unsigned x = (t >= off) ? sm[t - off] : 0u;
        __syncthreads();
        sm[t] += x;
        __syncthreads();
    }
    if (idx < n) offs[idx] = (sm[t] - v) + partial[blockIdx.x];
}

// --- legacy path (R3-style, for smaller workspaces) -------------------------
template <bool PACKED>
__global__ __launch_bounds__(256) void elem_pay(
    const float* __restrict__ pred, const float* __restrict__ grad_ux,
    const float* __restrict__ grad_uz, const float* __restrict__ grad_phi,
    const float* __restrict__ pack,
    const float* __restrict__ prop_E, const float* __restrict__ prop_A,
    const float* __restrict__ prop_I22, const float* __restrict__ elemL,
    const float* __restrict__ dirs, const float* __restrict__ load,
    const int* __restrict__ conn,
    float* __restrict__ payload,
    unsigned int* __restrict__ counts,
    unsigned char* __restrict__ pos,
    Scal* sc, int n_elems)
{
    __shared__ double smD[4];
    __shared__ float  smF[4];

    double s_rkin2 = 0.0, s_e1 = 0.0, s_e2 = 0.0, s_Lsum = 0.0;
    float m_q = 0.0f, m_L = 0.0f;

    const int e = blockIdx.x * 256 + threadIdx.x;
    if (e < n_elems) {
        const i2 ij = __builtin_nontemporal_load((const i2*)conn + e);
        const int i = ij.x, j = ij.y;
        const unsigned ri = atomicAdd(&counts[i], 1u);
        const unsigned rj = atomicAdd(&counts[j], 1u);

        const ElemOut o = elem_body<PACKED>(pred, grad_ux, grad_uz, grad_phi, pack,
                                            prop_E, prop_A, prop_I22, elemL, dirs, load,
                                            e, i, j);

        f4* pw = (f4*)(payload + 12 * (size_t)e);
        f4 P0 = {o.Fe0, o.Fe1, o.Fe2, o.Mi0};
        f4 P1 = {o.Mi1, o.Mi2, o.Mj0, o.Mj1};
        f4 P2 = {o.Mj2, o.E0, o.E1, o.E2};
        __builtin_nontemporal_store(P0, pw + 0);
        __builtin_nontemporal_store(P1, pw + 1);
        __builtin_nontemporal_store(P2, pw + 2);

        pos[2 * e]     = (unsigned char)ri;
        pos[2 * e + 1] = (unsigned char)rj;

        elem_reduce_tail(o, s_rkin2, s_e1, s_e2, s_Lsum, m_q, m_L);
    }

    blockAtomicAddD(s_rkin2, &sc->rkin2, smD);
    blockAtomicAddD(s_e1,    &sc->e1,    smD);
    blockAtomicAddD(s_e2,    &sc->e2,    smD);
    blockAtomicAddD(s_Lsum,  &sc->Lsum,  smD);
    blockAtomicMaxF(m_q, &sc->qmax_bits, smF);
    blockAtomicMaxF(m_L, &sc->Lmax_bits, smF);
}

__global__ __launch_bounds__(256) void fill_entries(
    const int* __restrict__ conn, const unsigned char* __restrict__ pos,
    const unsigned int* __restrict__ offs, unsigned int* __restrict__ entries,
    int n_elems)
{
    const int e = blockIdx.x * 256 + threadIdx.x;
    if (e >= n_elems) return;
    const int2 ij = ((const int2*)conn)[e];
    entries[offs[ij.x] + pos[2 * e]]     = ((unsigned)e << 1);
    entries[offs[ij.y] + pos[2 * e + 1]] = ((unsigned)e << 1) | 1u;
}

__global__ __launch_bounds__(256) void node_csr(
    const float* __restrict__ payload,
    const unsigned int* __restrict__ offs, const unsigned int* __restrict__ counts,
    const unsigned int* __restrict__ entries,
    const float* __restrict__ bc_disp, const float* __restrict__ bc_rot,
    Scal* sc, int n_nodes)
{
    __shared__ double smD[4];
    __shared__ unsigned smU[4];

    double sFe2 = 0.0, sF2 = 0.0, sMr2 = 0.0, sMp2 = 0.0;
    unsigned cd = 0, cr = 0, cp = 0;

    const int k = blockIdx.x * 256 + threadIdx.x;
    if (k < n_nodes) {
        const unsigned base = offs[k];
        const unsigned deg  = counts[k];

        float F0 = 0.f, F1 = 0.f, F2 = 0.f;
        float M0 = 0.f, M1 = 0.f, M2 = 0.f;
        float E0 = 0.f, E1 = 0.f, E2 = 0.f;

        for (unsigned d = 0; d < deg; ++d) {
            const unsigned idx = entries[base + d];
            const unsigned e = idx >> 1;
            const bool side_j = idx & 1u;
            const f4* p = (const f4*)(payload + 12 * (size_t)e);
            const f4 a = p[0], b = p[1], c = p[2];
            const float sgn = side_j ? -1.0f : 1.0f;
            F0 += sgn * a.x; F1 += sgn * a.y; F2 += sgn * a.z;
            if (side_j) { M0 += b.z; M1 += b.w; M2 += c.x; }
            else        { M0 += a.w; M1 += b.x; M2 += b.y; }
            E0 += c.y; E1 += c.z; E2 += c.w;
        }

        const float bd = bc_disp[k], br = bc_rot[k];
        const bool free_d = bd < 0.5f;
        const bool free_r = br < 0.5f;
        const bool pin    = (bd > 0.5f) && free_r;

        if (free_d) {
            const float f0 = F0 + E0, f1 = F1 + E1, f2 = F2 + E2;
            sFe2 += (double)(E0 * E0 + E1 * E1 + E2 * E2);
            sF2  += (double)(f0 * f0 + f1 * f1 + f2 * f2);
            cd++;
        }
        if (free_r) { sMr2 += (double)(M0 * M0 + M1 * M1 + M2 * M2); cr++; }
        if (pin)    { sMp2 += (double)(M0 * M0 + M1 * M1 + M2 * M2); cp++; }
    }

    blockAtomicAddD(sFe2, &sc->Fe2, smD);
    blockAtomicAddD(sF2,  &sc->F2,  smD);
    blockAtomicAddD(sMr2, &sc->Mr2, smD);
    blockAtomicAddD(sMp2, &sc->Mp2, smD);
    blockAtomicAddU(cd, &sc->cnt_d, smU);
    blockAtomicAddU(cr, &sc->cnt_r, smU);
    blockAtomicAddU(cp, &sc->cnt_p, smU);
}

__global__ void finalize(const Scal* sc, float* out, int n_elems)
{
    const double cnt_d = (double)max(sc->cnt_d, 1u);
    const double cnt_r = (double)max(sc->cnt_r, 1u);
    const double cnt_p = (double)max(sc->cnt_p, 1u);

    const double F_char = fmax(sqrt(sc->Fe2 / (cnt_d * 3.0)), 1.0);
    const double L_force = sc->F2 / (cnt_d * 3.0) / (F_char * F_char);

    const double qmax = fmax((double)__uint_as_float(sc->qmax_bits), 1.0);
    const double Lmax = (double)__uint_as_float(sc->Lmax_bits);
    const double M_char = fmax(qmax * Lmax * sc->Lsum / 8.0, 1.0);

    const double L_moment  = sc->Mr2 / (cnt_r * 3.0) / (M_char * M_char);
    const double L_neumann = sc->Mp2 / (cnt_p * 3.0) / (M_char * M_char);

    const double inv_ne = 1.0 / (double)n_elems;
    const double L_kin = sc->rkin2 * inv_ne;
    const double L_consist = sc->e1 * inv_ne + sc->e2 * inv_ne;

    out[0] = (float)(L_force + L_moment + L_neumann + 0.1 * L_kin + L_consist);
}

extern "C" void kernel_launch(void* const* d_in, const int* in_sizes, int n_in,
                              void* d_out, int out_size, void* d_ws, size_t ws_size,
                              hipStream_t stream)
{
    const float* pred     = (const float*)d_in[0];
    const float* grad_ux  = (const float*)d_in[1];
    const float* grad_uz  = (const float*)d_in[2];
    const float* grad_phi = (const float*)d_in[3];
    const float* prop_E   = (const float*)d_in[4];
    const float* prop_A   = (const float*)d_in[5];
    const float* prop_I22 = (const float*)d_in[6];
    const float* elemL    = (const float*)d_in[7];
    const float* dirs     = (const float*)d_in[8];
    const float* load     = (const float*)d_in[9];
    const float* bc_disp  = (const float*)d_in[10];
    const float* bc_rot   = (const float*)d_in[11];
    const int*   conn     = (const int*)d_in[12];

    const int n_elems = in_sizes[4];
    const int n_nodes = in_sizes[10];
    const int nblkN = (n_nodes + 255) / 256;   // 4096
    const int nblkE = (n_elems + 255) / 256;   // 8192

    const size_t szRecs    = (size_t)n_elems * 2 * 48;               // 192MB
    const size_t szPack    = (size_t)n_nodes * 48;                   // 48MB
    const size_t szCounts  = (size_t)n_nodes * sizeof(unsigned);     // 4MB
    const size_t szOffs    = szCounts;                               // 4MB
    const size_t szPos     = (size_t)n_elems * 2;                    // 4MB
    const size_t szPayload = (size_t)n_elems * 12 * sizeof(float);   // 96MB
    const size_t szEntries = (size_t)n_elems * 2 * sizeof(unsigned); // 16MB
    const size_t szPartial = 4096 * sizeof(unsigned);
    const size_t meta = szCounts + szOffs + szPartial + sizeof(Scal) + 256;

    char* base = (char*)d_ws;

    if (ws_size >= szRecs + szPack + meta) {
        // ---- new path (~248.1MB) ----
        float*        recs    = (float*)base;         base += szRecs;
        float*        pack    = (float*)base;         base += szPack;
        unsigned int* counts  = (unsigned int*)base;  base += szCounts;
        unsigned int* offs    = (unsigned int*)base;  base += szOffs;
        unsigned int* partial = (unsigned int*)base;  base += szPartial;
        Scal*         sc      = (Scal*)base;

        hipMemsetAsync(counts, 0, szCounts, stream);
        hipMemsetAsync(sc, 0, sizeof(Scal), stream);

        prep_pass<<<nblkN + nblkE, 256, 0, stream>>>(
            pred, grad_ux, grad_uz, grad_phi, pack, n_nodes, nblkN,
            conn, counts, n_elems);

        scan1<<<nblkN, 256, 0, stream>>>(counts, partial, n_nodes);
        scan2<<<1, 1024, 0, stream>>>(partial, nblkN);
        scan3<<<nblkN, 256, 0, stream>>>(counts, partial, offs, n_nodes);

        elem_full<<<nblkE, 256, 0, stream>>>(
            pack, prop_E, prop_A, prop_I22, elemL, dirs, load, conn,
            offs, recs, sc, n_elems);

        node_seq<<<nblkN, 256, 0, stream>>>(
            recs, offs, counts, bc_disp, bc_rot, sc, n_nodes);
        finalize<<<1, 1, 0, stream>>>(sc, (float*)d_out, n_elems);
    } else {
        // ---- legacy path (R3-style) ----
        const size_t csrCore = szPayload + szCounts + szOffs + szPos + szEntries +
                               szPartial + sizeof(Scal) + 256;
        const bool usePack = (ws_size >= csrCore + szPack);

        float* pack = nullptr;
        if (usePack) { pack = (float*)base; base += szPack; }
        float*         payload = (float*)base;         base += szPayload;
        unsigned int*  counts  = (unsigned int*)base;  base += szCounts;
        unsigned int*  offs    = (unsigned int*)base;  base += szOffs;
        unsigned char* pos     = (unsigned char*)base; base += szPos;
        unsigned int*  entries = (unsigned int*)base;  base += szEntries;
        unsigned int*  partial = (unsigned int*)base;  base += szPartial;
        Scal*          sc      = (Scal*)base;

        hipMemsetAsync(counts, 0, szCounts, stream);
        hipMemsetAsync(sc, 0, sizeof(Scal), stream);

        if (usePack) {
            pack_nodes<<<nblkN, 256, 0, stream>>>(
                pred, grad_ux, grad_uz, grad_phi, pack, n_nodes);
            elem_pay<true><<<nblkE, 256, 0, stream>>>(
                pred, grad_ux, grad_uz, grad_phi, pack,
                prop_E, prop_A, prop_I22, elemL, dirs, load, conn,
                payload, counts, pos, sc, n_elems);
        } else {
            elem_pay<false><<<nblkE, 256, 0, stream>>>(
                pred, grad_ux, grad_uz, grad_phi, nullptr,
                prop_E, prop_A, prop_I22, elemL, dirs, load, conn,
                payload, counts, pos, sc, n_elems);
        }

        scan1<<<nblkN, 256, 0, stream>>>(counts, partial, n_nodes);
        scan2<<<1, 1024, 0, stream>>>(partial, nblkN);
        scan3<<<nblkN, 256, 0, stream>>>(counts, partial, offs, n_nodes);
        fill_entries<<<nblkE, 256, 0, stream>>>(conn, pos, offs, entries, n_elems);
        node_csr<<<nblkN, 256, 0, stream>>>(
            payload, offs, counts, entries, bc_disp, bc_rot, sc, n_nodes);
        finalize<<<1, 1, 0, stream>>>(sc, (float*)d_out, n_elems);
    }
}

// Round 6
// 816.856 us; speedup vs baseline: 1.2203x; 1.2203x over previous
//
#include <hip/hip_runtime.h>

// ---------------------------------------------------------------------------
// StrongFormPhysicsLoss, round 6: single-scatter row-table CSR.
//   K0 memset     : rows table (count words) + Scal
//   K1 elem_rows  : physics + payload stream (cached) + per-endpoint
//                   {relaxed atomic rank on rows[k][0]; entry store to
//                   rows[k][1+r]} — ONE scattered-op pass, same-line fused
//   K2 node_rows  : per-node row read + payload gathers (L3) + masked sums,
//                   early-out for mask-dead nodes
//   K3 finalize
// No scan, no fill, no counting pass. rows[k] = 32 u32 = 128B.
// Overflow (deg>31) via tiny side list. Fallbacks: RS=16 rows, then
// R1-style SoA atomics.
// ---------------------------------------------------------------------------

typedef __attribute__((ext_vector_type(4))) float f4;
typedef __attribute__((ext_vector_type(2))) int   i2;

#define OVF_MAX 16384

struct Scal {
    double rkin2, e1, e2, Lsum;
    double Fe2, F2, Mr2, Mp2;
    unsigned int qmax_bits, Lmax_bits;
    unsigned int cnt_d, cnt_r, cnt_p;
    unsigned int ovf_cnt;
};

__device__ __forceinline__ double waveSumD(double v) {
#pragma unroll
    for (int o = 32; o > 0; o >>= 1) v += __shfl_down(v, o, 64);
    return v;
}
__device__ __forceinline__ float waveMaxF(float v) {
#pragma unroll
    for (int o = 32; o > 0; o >>= 1) v = fmaxf(v, __shfl_down(v, o, 64));
    return v;
}
__device__ __forceinline__ unsigned waveSumU(unsigned v) {
#pragma unroll
    for (int o = 32; o > 0; o >>= 1) v += __shfl_down(v, o, 64);
    return v;
}

__device__ __forceinline__ void blockAtomicAddD(double v, double* dst, double* smem) {
    v = waveSumD(v);
    const int lane = threadIdx.x & 63, wid = threadIdx.x >> 6;
    if (lane == 0) smem[wid] = v;
    __syncthreads();
    if (threadIdx.x == 0) atomicAdd(dst, smem[0] + smem[1] + smem[2] + smem[3]);
    __syncthreads();
}
__device__ __forceinline__ void blockAtomicMaxF(float v, unsigned int* dst, float* smem) {
    v = waveMaxF(v);
    const int lane = threadIdx.x & 63, wid = threadIdx.x >> 6;
    if (lane == 0) smem[wid] = v;
    __syncthreads();
    if (threadIdx.x == 0) {
        float r = fmaxf(fmaxf(smem[0], smem[1]), fmaxf(smem[2], smem[3]));
        atomicMax(dst, __float_as_uint(fmaxf(r, 0.0f)));
    }
    __syncthreads();
}
__device__ __forceinline__ void blockAtomicAddU(unsigned v, unsigned int* dst, unsigned* smem) {
    v = waveSumU(v);
    const int lane = threadIdx.x & 63, wid = threadIdx.x >> 6;
    if (lane == 0) smem[wid] = v;
    __syncthreads();
    if (threadIdx.x == 0) atomicAdd(dst, smem[0] + smem[1] + smem[2] + smem[3]);
    __syncthreads();
}

// ---------------------------------------------------------------------------
struct ElemOut {
    float Fe0, Fe1, Fe2, Mi0, Mi1, Mi2, Mj0, Mj1, Mj2, E0, E1, E2;
    float rkin, d1, d2, Le, l0, l1, l2;
};

__device__ __forceinline__ ElemOut elem_body(
    const float* __restrict__ pred, const float* __restrict__ grad_ux,
    const float* __restrict__ grad_uz, const float* __restrict__ grad_phi,
    const float* __restrict__ prop_E, const float* __restrict__ prop_A,
    const float* __restrict__ prop_I22, const float* __restrict__ elemL,
    const float* __restrict__ dirs, const float* __restrict__ load,
    int e, int i, int j)
{
    const float x0 = __builtin_nontemporal_load(dirs + 3 * e);
    const float x1 = __builtin_nontemporal_load(dirs + 3 * e + 1);
    const float x2 = __builtin_nontemporal_load(dirs + 3 * e + 2);

    const bool par = fabsf(x1) > 0.99f;
    float z0, z1, z2;
    if (par) { z0 = x1; z1 = -x0; z2 = 0.0f; }      // cross(x,(0,0,1))
    else     { z0 = -x2; z1 = 0.0f; z2 = x0; }      // cross(x,(0,1,0))
    float zn = fmaxf(sqrtf(z0 * z0 + z1 * z1 + z2 * z2), 1e-8f);
    z0 /= zn; z1 /= zn; z2 /= zn;
    float y0 = z1 * x2 - z2 * x1;
    float y1 = z2 * x0 - z0 * x2;
    float y2 = z0 * x1 - z1 * x0;
    float yn = fmaxf(sqrtf(y0 * y0 + y1 * y1 + y2 * y2), 1e-8f);
    y0 /= yn; y1 /= yn; y2 /= yn;

    // raw node gathers (4 arrays are 48MB total -> L3-resident)
    const float uxi = pred[3 * i], uzi = pred[3 * i + 1], phii = pred[3 * i + 2];
    const float uxj = pred[3 * j], uzj = pred[3 * j + 1], phij = pred[3 * j + 2];
    const float gxi   = grad_ux[3 * i] * x0 + grad_ux[3 * i + 1] * x1 + grad_ux[3 * i + 2] * x2;
    const float gzi   = grad_uz[3 * i] * x0 + grad_uz[3 * i + 1] * x1 + grad_uz[3 * i + 2] * x2;
    const float kap_i = grad_phi[3 * i] * x0 + grad_phi[3 * i + 1] * x1 + grad_phi[3 * i + 2] * x2;
    const float gxj   = grad_ux[3 * j] * x0 + grad_ux[3 * j + 1] * x1 + grad_ux[3 * j + 2] * x2;
    const float gzj   = grad_uz[3 * j] * x0 + grad_uz[3 * j + 1] * x1 + grad_uz[3 * j + 2] * x2;
    const float kap_j = grad_phi[3 * j] * x0 + grad_phi[3 * j + 1] * x1 + grad_phi[3 * j + 2] * x2;

    const float dux = uxj - uxi, duz = uzj - uzi;

    const float Le   = __builtin_nontemporal_load(elemL + e);
    const float invL = 1.0f / Le;
    const float pE   = __builtin_nontemporal_load(prop_E + e);
    const float EA   = pE * __builtin_nontemporal_load(prop_A + e);
    const float EI   = pE * __builtin_nontemporal_load(prop_I22 + e);

    const float du_ax  = dux * x0 + duz * x2;
    const float eps_fd = du_ax * invL;
    const float N_fd   = EA * eps_fd;
    const float du_tr  = dux * z0 + duz * z2;
    const float kappa_fd = (phij - phii) * invL;

    const float EIL = EI * invL, EIL2 = EIL * invL, EIL3 = EIL2 * invL;
    const float V_fd = 12.0f * EIL3 * du_tr - 6.0f * EIL2 * (phii + phij);
    const float M_yi = 6.0f * EIL2 * du_tr - EIL * (4.0f * phii + 2.0f * phij);
    const float M_yj = 6.0f * EIL2 * du_tr - EIL * (2.0f * phii + 4.0f * phij);

    const float eps_ag   = 0.5f * ((x0 * gxi + x2 * gzi) + (x0 * gxj + x2 * gzj));
    const float kappa_ag = 0.5f * (kap_i + kap_j);

    const float l0 = __builtin_nontemporal_load(load + 3 * e);
    const float l1 = __builtin_nontemporal_load(load + 3 * e + 1);
    const float l2 = __builtin_nontemporal_load(load + 3 * e + 2);
    const float hl = 0.5f * Le;

    ElemOut o;
    o.Fe0 = N_fd * x0 + V_fd * z0;
    o.Fe1 = N_fd * x1 + V_fd * z1;
    o.Fe2 = N_fd * x2 + V_fd * z2;
    o.Mi0 = M_yi * y0; o.Mi1 = M_yi * y1; o.Mi2 = M_yi * y2;
    o.Mj0 = M_yj * y0; o.Mj1 = M_yj * y1; o.Mj2 = M_yj * y2;
    o.E0 = l0 * hl; o.E1 = l1 * hl; o.E2 = l2 * hl;
    o.rkin = 0.5f * (phii + phij) - du_tr * invL;
    o.d1 = eps_ag - eps_fd;
    o.d2 = kappa_ag - kappa_fd;
    o.Le = Le; o.l0 = l0; o.l1 = l1; o.l2 = l2;
    return o;
}

__device__ __forceinline__ void elem_reduce_tail(
    const ElemOut& o, double& s_rkin2, double& s_e1, double& s_e2,
    double& s_Lsum, float& m_q, float& m_L)
{
    s_rkin2 += (double)(o.rkin * o.rkin);
    s_e1 += (double)(o.d1 * o.d1);
    s_e2 += (double)(o.d2 * o.d2);
    s_Lsum += (double)o.Le;
    m_q = fmaxf(m_q, fmaxf(fabsf(o.l0), fmaxf(fabsf(o.l1), fabsf(o.l2))));
    m_L = fmaxf(m_L, o.Le);
}

// ---------------------------------------------------------------------------
// Primary: row-table pass. rows[k] = RS u32: [count | RS-1 entries]
// payload per element (12 f32, cached stores):
//   P0={Fe0,Fe1,Fe2,Mi0} P1={Mi1,Mi2,Mj0,Mj1} P2={Mj2,E0,E1,E2}
template <int RS>
__global__ __launch_bounds__(256) void elem_rows(
    const float* __restrict__ pred, const float* __restrict__ grad_ux,
    const float* __restrict__ grad_uz, const float* __restrict__ grad_phi,
    const float* __restrict__ prop_E, const float* __restrict__ prop_A,
    const float* __restrict__ prop_I22, const float* __restrict__ elemL,
    const float* __restrict__ dirs, const float* __restrict__ load,
    const int* __restrict__ conn,
    float* __restrict__ payload,
    unsigned int* __restrict__ rows,
    unsigned int* __restrict__ ovf,
    Scal* sc, int n_elems)
{
    __shared__ double smD[4];
    __shared__ float  smF[4];

    double s_rkin2 = 0.0, s_e1 = 0.0, s_e2 = 0.0, s_Lsum = 0.0;
    float m_q = 0.0f, m_L = 0.0f;

    const int e = blockIdx.x * 256 + threadIdx.x;
    if (e < n_elems) {
        const i2 ij = __builtin_nontemporal_load((const i2*)conn + e);
        const int i = ij.x, j = ij.y;

        // rank claims early: latency hides under the physics
        const unsigned r_i = __hip_atomic_fetch_add(
            &rows[(size_t)RS * i], 1u, __ATOMIC_RELAXED, __HIP_MEMORY_SCOPE_AGENT);
        const unsigned r_j = __hip_atomic_fetch_add(
            &rows[(size_t)RS * j], 1u, __ATOMIC_RELAXED, __HIP_MEMORY_SCOPE_AGENT);

        const ElemOut o = elem_body(pred, grad_ux, grad_uz, grad_phi,
                                    prop_E, prop_A, prop_I22, elemL, dirs, load,
                                    e, i, j);

        f4* pw = (f4*)(payload + 12 * (size_t)e);
        f4 P0 = {o.Fe0, o.Fe1, o.Fe2, o.Mi0};
        f4 P1 = {o.Mi1, o.Mi2, o.Mj0, o.Mj1};
        f4 P2 = {o.Mj2, o.E0, o.E1, o.E2};
        pw[0] = P0; pw[1] = P1; pw[2] = P2;       // cached: node pass wants L3 hits

        const unsigned tag_i = ((unsigned)e << 1);
        const unsigned tag_j = ((unsigned)e << 1) | 1u;
        if (r_i < (unsigned)(RS - 1)) {
            rows[(size_t)RS * i + 1 + r_i] = tag_i;   // same/adjacent line as atomic
        } else {
            const unsigned oo = atomicAdd(&sc->ovf_cnt, 1u);
            if (oo < OVF_MAX) { ovf[2 * oo] = (unsigned)i; ovf[2 * oo + 1] = tag_i; }
        }
        if (r_j < (unsigned)(RS - 1)) {
            rows[(size_t)RS * j + 1 + r_j] = tag_j;
        } else {
            const unsigned oo = atomicAdd(&sc->ovf_cnt, 1u);
            if (oo < OVF_MAX) { ovf[2 * oo] = (unsigned)j; ovf[2 * oo + 1] = tag_j; }
        }

        elem_reduce_tail(o, s_rkin2, s_e1, s_e2, s_Lsum, m_q, m_L);
    }

    blockAtomicAddD(s_rkin2, &sc->rkin2, smD);
    blockAtomicAddD(s_e1,    &sc->e1,    smD);
    blockAtomicAddD(s_e2,    &sc->e2,    smD);
    blockAtomicAddD(s_Lsum,  &sc->Lsum,  smD);
    blockAtomicMaxF(m_q, &sc->qmax_bits, smF);
    blockAtomicMaxF(m_L, &sc->Lmax_bits, smF);
}

template <int RS>
__global__ __launch_bounds__(256) void node_rows(
    const float* __restrict__ payload,
    const unsigned int* __restrict__ rows,
    const unsigned int* __restrict__ ovf,
    const float* __restrict__ bc_disp, const float* __restrict__ bc_rot,
    Scal* sc, int n_nodes)
{
    __shared__ double smD[4];
    __shared__ unsigned smU[4];

    double sFe2 = 0.0, sF2 = 0.0, sMr2 = 0.0, sMp2 = 0.0;
    unsigned cd = 0, cr = 0, cp = 0;

    const int k = blockIdx.x * 256 + threadIdx.x;
    if (k < n_nodes) {
        const float bd = bc_disp[k], br = bc_rot[k];
        const bool free_d = bd < 0.5f;
        const bool free_r = br < 0.5f;
        const bool pin    = (bd > 0.5f) && free_r;

        if (free_d | free_r) {   // mask-dead nodes skip all memory work
            const unsigned cnt = rows[(size_t)RS * k];
            const unsigned lim = cnt < (unsigned)(RS - 1) ? cnt : (unsigned)(RS - 1);

            float F0 = 0.f, F1 = 0.f, F2 = 0.f;
            float M0 = 0.f, M1 = 0.f, M2 = 0.f;
            float E0 = 0.f, E1 = 0.f, E2 = 0.f;

            for (unsigned d = 0; d < lim; ++d) {
                const unsigned tag = rows[(size_t)RS * k + 1 + d];
                const unsigned e = tag >> 1;
                const bool side_j = tag & 1u;
                const f4* p = (const f4*)(payload + 12 * (size_t)e);
                const f4 a = p[0], b = p[1], c = p[2];
                const float sgn = side_j ? -1.0f : 1.0f;
                F0 += sgn * a.x; F1 += sgn * a.y; F2 += sgn * a.z;
                if (side_j) { M0 += b.z; M1 += b.w; M2 += c.x; }
                else        { M0 += a.w; M1 += b.x; M2 += b.y; }
                E0 += c.y; E1 += c.z; E2 += c.w;
            }
            if (cnt > (unsigned)(RS - 1)) {     // extremely rare overflow path
                const unsigned nov = min(sc->ovf_cnt, (unsigned)OVF_MAX);
                for (unsigned o2 = 0; o2 < nov; ++o2) {
                    if (ovf[2 * o2] == (unsigned)k) {
                        const unsigned tag = ovf[2 * o2 + 1];
                        const unsigned e = tag >> 1;
                        const bool side_j = tag & 1u;
                        const f4* p = (const f4*)(payload + 12 * (size_t)e);
                        const f4 a = p[0], b = p[1], c = p[2];
                        const float sgn = side_j ? -1.0f : 1.0f;
                        F0 += sgn * a.x; F1 += sgn * a.y; F2 += sgn * a.z;
                        if (side_j) { M0 += b.z; M1 += b.w; M2 += c.x; }
                        else        { M0 += a.w; M1 += b.x; M2 += b.y; }
                        E0 += c.y; E1 += c.z; E2 += c.w;
                    }
                }
            }

            if (free_d) {
                const float f0 = F0 + E0, f1 = F1 + E1, f2 = F2 + E2;
                sFe2 += (double)(E0 * E0 + E1 * E1 + E2 * E2);
                sF2  += (double)(f0 * f0 + f1 * f1 + f2 * f2);
                cd++;
            }
            if (free_r) { sMr2 += (double)(M0 * M0 + M1 * M1 + M2 * M2); cr++; }
            if (pin)    { sMp2 += (double)(M0 * M0 + M1 * M1 + M2 * M2); cp++; }
        }
    }

    blockAtomicAddD(sFe2, &sc->Fe2, smD);
    blockAtomicAddD(sF2,  &sc->F2,  smD);
    blockAtomicAddD(sMr2, &sc->Mr2, smD);
    blockAtomicAddD(sMp2, &sc->Mp2, smD);
    blockAtomicAddU(cd, &sc->cnt_d, smU);
    blockAtomicAddU(cr, &sc->cnt_r, smU);
    blockAtomicAddU(cp, &sc->cnt_p, smU);
}

// --- last-resort fallback: R1-style SoA atomics ----------------------------
__global__ __launch_bounds__(256) void elem_soa(
    const float* __restrict__ pred, const float* __restrict__ grad_ux,
    const float* __restrict__ grad_uz, const float* __restrict__ grad_phi,
    const float* __restrict__ prop_E, const float* __restrict__ prop_A,
    const float* __restrict__ prop_I22, const float* __restrict__ elemL,
    const float* __restrict__ dirs, const float* __restrict__ load,
    const int* __restrict__ conn,
    float* __restrict__ Fi, float* __restrict__ Mi, float* __restrict__ Fe,
    Scal* sc, int n_elems)
{
    __shared__ double smD[4];
    __shared__ float  smF[4];
    double s_rkin2 = 0.0, s_e1 = 0.0, s_e2 = 0.0, s_Lsum = 0.0;
    float m_q = 0.0f, m_L = 0.0f;

    const int e = blockIdx.x * 256 + threadIdx.x;
    if (e < n_elems) {
        const i2 ij = __builtin_nontemporal_load((const i2*)conn + e);
        const int i = ij.x, j = ij.y;
        const ElemOut o = elem_body(pred, grad_ux, grad_uz, grad_phi,
                                    prop_E, prop_A, prop_I22, elemL, dirs, load,
                                    e, i, j);
        atomicAdd(&Fi[3 * i], o.Fe0);  atomicAdd(&Fi[3 * i + 1], o.Fe1);  atomicAdd(&Fi[3 * i + 2], o.Fe2);
        atomicAdd(&Fi[3 * j], -o.Fe0); atomicAdd(&Fi[3 * j + 1], -o.Fe1); atomicAdd(&Fi[3 * j + 2], -o.Fe2);
        atomicAdd(&Mi[3 * i], o.Mi0);  atomicAdd(&Mi[3 * i + 1], o.Mi1);  atomicAdd(&Mi[3 * i + 2], o.Mi2);
        atomicAdd(&Mi[3 * j], o.Mj0);  atomicAdd(&Mi[3 * j + 1], o.Mj1);  atomicAdd(&Mi[3 * j + 2], o.Mj2);
        atomicAdd(&Fe[3 * i], o.E0);   atomicAdd(&Fe[3 * i + 1], o.E1);   atomicAdd(&Fe[3 * i + 2], o.E2);
        atomicAdd(&Fe[3 * j], o.E0);   atomicAdd(&Fe[3 * j + 1], o.E1);   atomicAdd(&Fe[3 * j + 2], o.E2);
        elem_reduce_tail(o, s_rkin2, s_e1, s_e2, s_Lsum, m_q, m_L);
    }
    blockAtomicAddD(s_rkin2, &sc->rkin2, smD);
    blockAtomicAddD(s_e1,    &sc->e1,    smD);
    blockAtomicAddD(s_e2,    &sc->e2,    smD);
    blockAtomicAddD(s_Lsum,  &sc->Lsum,  smD);
    blockAtomicMaxF(m_q, &sc->qmax_bits, smF);
    blockAtomicMaxF(m_L, &sc->Lmax_bits, smF);
}

__global__ __launch_bounds__(256) void node_soa(
    const float* __restrict__ Fi, const float* __restrict__ Mi, const float* __restrict__ Fe,
    const float* __restrict__ bc_disp, const float* __restrict__ bc_rot,
    Scal* sc, int n_nodes)
{
    __shared__ double smD[4];
    __shared__ unsigned smU[4];
    double sFe2 = 0.0, sF2 = 0.0, sMr2 = 0.0, sMp2 = 0.0;
    unsigned cd = 0, cr = 0, cp = 0;

    const int k = blockIdx.x * 256 + threadIdx.x;
    if (k < n_nodes) {
        const float bd = bc_disp[k], br = bc_rot[k];
        const bool free_d = bd < 0.5f;
        const bool free_r = br < 0.5f;
        const bool pin    = (bd > 0.5f) && free_r;
        if (free_d) {
            const float e0 = Fe[3 * k], e1 = Fe[3 * k + 1], e2 = Fe[3 * k + 2];
            const float f0 = Fi[3 * k] + e0, f1 = Fi[3 * k + 1] + e1, f2 = Fi[3 * k + 2] + e2;
            sFe2 += (double)(e0 * e0 + e1 * e1 + e2 * e2);
            sF2  += (double)(f0 * f0 + f1 * f1 + f2 * f2);
            cd++;
        }
        if (free_r | pin) {
            const float m0 = Mi[3 * k], m1 = Mi[3 * k + 1], m2 = Mi[3 * k + 2];
            const double mm = (double)(m0 * m0 + m1 * m1 + m2 * m2);
            if (free_r) { sMr2 += mm; cr++; }
            if (pin)    { sMp2 += mm; cp++; }
        }
    }
    blockAtomicAddD(sFe2, &sc->Fe2, smD);
    blockAtomicAddD(sF2,  &sc->F2,  smD);
    blockAtomicAddD(sMr2, &sc->Mr2, smD);
    blockAtomicAddD(sMp2, &sc->Mp2, smD);
    blockAtomicAddU(cd, &sc->cnt_d, smU);
    blockAtomicAddU(cr, &sc->cnt_r, smU);
    blockAtomicAddU(cp, &sc->cnt_p, smU);
}

__global__ void finalize(const Scal* sc, float* out, int n_elems)
{
    const double cnt_d = (double)max(sc->cnt_d, 1u);
    const double cnt_r = (double)max(sc->cnt_r, 1u);
    const double cnt_p = (double)max(sc->cnt_p, 1u);

    const double F_char = fmax(sqrt(sc->Fe2 / (cnt_d * 3.0)), 1.0);
    const double L_force = sc->F2 / (cnt_d * 3.0) / (F_char * F_char);

    const double qmax = fmax((double)__uint_as_float(sc->qmax_bits), 1.0);
    const double Lmax = (double)__uint_as_float(sc->Lmax_bits);
    const double M_char = fmax(qmax * Lmax * sc->Lsum / 8.0, 1.0);

    const double L_moment  = sc->Mr2 / (cnt_r * 3.0) / (M_char * M_char);
    const double L_neumann = sc->Mp2 / (cnt_p * 3.0) / (M_char * M_char);

    const double inv_ne = 1.0 / (double)n_elems;
    const double L_kin = sc->rkin2 * inv_ne;
    const double L_consist = sc->e1 * inv_ne + sc->e2 * inv_ne;

    out[0] = (float)(L_force + L_moment + L_neumann + 0.1 * L_kin + L_consist);
}

extern "C" void kernel_launch(void* const* d_in, const int* in_sizes, int n_in,
                              void* d_out, int out_size, void* d_ws, size_t ws_size,
                              hipStream_t stream)
{
    const float* pred     = (const float*)d_in[0];
    const float* grad_ux  = (const float*)d_in[1];
    const float* grad_uz  = (const float*)d_in[2];
    const float* grad_phi = (const float*)d_in[3];
    const float* prop_E   = (const float*)d_in[4];
    const float* prop_A   = (const float*)d_in[5];
    const float* prop_I22 = (const float*)d_in[6];
    const float* elemL    = (const float*)d_in[7];
    const float* dirs     = (const float*)d_in[8];
    const float* load     = (const float*)d_in[9];
    const float* bc_disp  = (const float*)d_in[10];
    const float* bc_rot   = (const float*)d_in[11];
    const int*   conn     = (const int*)d_in[12];

    const int n_elems = in_sizes[4];
    const int n_nodes = in_sizes[10];
    const int nblkE = (n_elems + 255) / 256;
    const int nblkN = (n_nodes + 255) / 256;

    const size_t szPayload = (size_t)n_elems * 12 * sizeof(float);   // 96MB
    const size_t szOvf     = (size_t)OVF_MAX * 2 * sizeof(unsigned); // 128KB
    const size_t szTail    = 256;                                    // Scal

    char* base = (char*)d_ws;

    // try RS=32 (128B rows, 128MB), then RS=16 (64B rows, 64MB)
    const size_t szRows32 = (size_t)n_nodes * 32 * sizeof(unsigned);
    const size_t szRows16 = (size_t)n_nodes * 16 * sizeof(unsigned);

    if (ws_size >= szPayload + szRows32 + szOvf + szTail) {
        float*        payload = (float*)base;        base += szPayload;
        unsigned int* rows    = (unsigned int*)base; base += szRows32;
        unsigned int* ovf     = (unsigned int*)base; base += szOvf;
        Scal*         sc      = (Scal*)base;

        hipMemsetAsync(rows, 0, szRows32, stream);
        hipMemsetAsync(sc, 0, sizeof(Scal), stream);

        elem_rows<32><<<nblkE, 256, 0, stream>>>(
            pred, grad_ux, grad_uz, grad_phi,
            prop_E, prop_A, prop_I22, elemL, dirs, load, conn,
            payload, rows, ovf, sc, n_elems);
        node_rows<32><<<nblkN, 256, 0, stream>>>(
            payload, rows, ovf, bc_disp, bc_rot, sc, n_nodes);
        finalize<<<1, 1, 0, stream>>>(sc, (float*)d_out, n_elems);
    } else if (ws_size >= szPayload + szRows16 + szOvf + szTail) {
        float*        payload = (float*)base;        base += szPayload;
        unsigned int* rows    = (unsigned int*)base; base += szRows16;
        unsigned int* ovf     = (unsigned int*)base; base += szOvf;
        Scal*         sc      = (Scal*)base;

        hipMemsetAsync(rows, 0, szRows16, stream);
        hipMemsetAsync(sc, 0, sizeof(Scal), stream);

        elem_rows<16><<<nblkE, 256, 0, stream>>>(
            pred, grad_ux, grad_uz, grad_phi,
            prop_E, prop_A, prop_I22, elemL, dirs, load, conn,
            payload, rows, ovf, sc, n_elems);
        node_rows<16><<<nblkN, 256, 0, stream>>>(
            payload, rows, ovf, bc_disp, bc_rot, sc, n_nodes);
        finalize<<<1, 1, 0, stream>>>(sc, (float*)d_out, n_elems);
    } else {
        // R1-style SoA atomic fallback (36MB + Scal)
        float* Fi = (float*)d_ws;
        float* Mi = Fi + (size_t)3 * n_nodes;
        float* Fe = Mi + (size_t)3 * n_nodes;
        const size_t nodeBytes = (size_t)9 * n_nodes * sizeof(float);
        Scal* sc = (Scal*)((char*)d_ws + nodeBytes);

        hipMemsetAsync(d_ws, 0, nodeBytes + sizeof(Scal), stream);

        elem_soa<<<nblkE, 256, 0, stream>>>(
            pred, grad_ux, grad_uz, grad_phi,
            prop_E, prop_A, prop_I22, elemL, dirs, load, conn,
            Fi, Mi, Fe, sc, n_elems);
        node_soa<<<nblkN, 256, 0, stream>>>(
            Fi, Mi, Fe, bc_disp, bc_rot, sc, n_nodes);
        finalize<<<1, 1, 0, stream>>>(sc, (float*)d_out, n_elems);
    }
}

// Round 7
// 766.779 us; speedup vs baseline: 1.2999x; 1.0653x over previous
//
#include <hip/hip_runtime.h>

// ---------------------------------------------------------------------------
// StrongFormPhysicsLoss, round 7: pack + single-scatter row-table (RS=16).
//   K1 pack_nodes : [N][12] packed node block (one 64B line per endpoint)
//   K2 elem_rows  : physics + 64B-aligned payload (cached) + per-endpoint
//                   same-line {rank atomic, entry store} into 64B row
//   K3 node_rows  : row read (1 line) + one-line payload gathers + masked sums
//   K4 finalize
// Footprint: pack 48MB + payload 128MB + rows 64MB + ovf = 240.2MB.
// Tiers: B = no pack (raw gathers); C = SoA atomic fallback.
// ---------------------------------------------------------------------------

typedef __attribute__((ext_vector_type(4))) float f4;
typedef __attribute__((ext_vector_type(2))) int   i2;

#define OVF_MAX 16384

struct Scal {
    double rkin2, e1, e2, Lsum;
    double Fe2, F2, Mr2, Mp2;
    unsigned int qmax_bits, Lmax_bits;
    unsigned int cnt_d, cnt_r, cnt_p;
    unsigned int ovf_cnt;
};

__device__ __forceinline__ double waveSumD(double v) {
#pragma unroll
    for (int o = 32; o > 0; o >>= 1) v += __shfl_down(v, o, 64);
    return v;
}
__device__ __forceinline__ float waveMaxF(float v) {
#pragma unroll
    for (int o = 32; o > 0; o >>= 1) v = fmaxf(v, __shfl_down(v, o, 64));
    return v;
}
__device__ __forceinline__ unsigned waveSumU(unsigned v) {
#pragma unroll
    for (int o = 32; o > 0; o >>= 1) v += __shfl_down(v, o, 64);
    return v;
}

__device__ __forceinline__ void blockAtomicAddD(double v, double* dst, double* smem) {
    v = waveSumD(v);
    const int lane = threadIdx.x & 63, wid = threadIdx.x >> 6;
    if (lane == 0) smem[wid] = v;
    __syncthreads();
    if (threadIdx.x == 0) atomicAdd(dst, smem[0] + smem[1] + smem[2] + smem[3]);
    __syncthreads();
}
__device__ __forceinline__ void blockAtomicMaxF(float v, unsigned int* dst, float* smem) {
    v = waveMaxF(v);
    const int lane = threadIdx.x & 63, wid = threadIdx.x >> 6;
    if (lane == 0) smem[wid] = v;
    __syncthreads();
    if (threadIdx.x == 0) {
        float r = fmaxf(fmaxf(smem[0], smem[1]), fmaxf(smem[2], smem[3]));
        atomicMax(dst, __float_as_uint(fmaxf(r, 0.0f)));
    }
    __syncthreads();
}
__device__ __forceinline__ void blockAtomicAddU(unsigned v, unsigned int* dst, unsigned* smem) {
    v = waveSumU(v);
    const int lane = threadIdx.x & 63, wid = threadIdx.x >> 6;
    if (lane == 0) smem[wid] = v;
    __syncthreads();
    if (threadIdx.x == 0) atomicAdd(dst, smem[0] + smem[1] + smem[2] + smem[3]);
    __syncthreads();
}

// ---------------------------------------------------------------------------
// pack[k][0:3]=pred, [3:6]=grad_ux, [6:9]=grad_uz, [9:12]=grad_phi (48B/node)
__global__ __launch_bounds__(256) void pack_nodes(
    const float* __restrict__ pred, const float* __restrict__ gux,
    const float* __restrict__ guz,  const float* __restrict__ gphi,
    float* __restrict__ pack, int n)
{
    const int k = blockIdx.x * blockDim.x + threadIdx.x;
    if (k >= n) return;
    const size_t b3 = 3 * (size_t)k;
    f4 A = {__builtin_nontemporal_load(pred + b3),
            __builtin_nontemporal_load(pred + b3 + 1),
            __builtin_nontemporal_load(pred + b3 + 2),
            __builtin_nontemporal_load(gux + b3)};
    f4 B = {__builtin_nontemporal_load(gux + b3 + 1),
            __builtin_nontemporal_load(gux + b3 + 2),
            __builtin_nontemporal_load(guz + b3),
            __builtin_nontemporal_load(guz + b3 + 1)};
    f4 C = {__builtin_nontemporal_load(guz + b3 + 2),
            __builtin_nontemporal_load(gphi + b3),
            __builtin_nontemporal_load(gphi + b3 + 1),
            __builtin_nontemporal_load(gphi + b3 + 2)};
    f4* o = (f4*)(pack + 12 * (size_t)k);
    o[0] = A; o[1] = B; o[2] = C;   // cached: elem pass gathers want residency
}

// ---------------------------------------------------------------------------
struct ElemOut {
    float Fe0, Fe1, Fe2, Mi0, Mi1, Mi2, Mj0, Mj1, Mj2, E0, E1, E2;
    float rkin, d1, d2, Le, l0, l1, l2;
};

template <bool PACKED>
__device__ __forceinline__ ElemOut elem_body(
    const float* __restrict__ pred, const float* __restrict__ grad_ux,
    const float* __restrict__ grad_uz, const float* __restrict__ grad_phi,
    const float* __restrict__ pack,
    const float* __restrict__ prop_E, const float* __restrict__ prop_A,
    const float* __restrict__ prop_I22, const float* __restrict__ elemL,
    const float* __restrict__ dirs, const float* __restrict__ load,
    int e, int i, int j)
{
    const float x0 = __builtin_nontemporal_load(dirs + 3 * e);
    const float x1 = __builtin_nontemporal_load(dirs + 3 * e + 1);
    const float x2 = __builtin_nontemporal_load(dirs + 3 * e + 2);

    const bool par = fabsf(x1) > 0.99f;
    float z0, z1, z2;
    if (par) { z0 = x1; z1 = -x0; z2 = 0.0f; }      // cross(x,(0,0,1))
    else     { z0 = -x2; z1 = 0.0f; z2 = x0; }      // cross(x,(0,1,0))
    float zn = fmaxf(sqrtf(z0 * z0 + z1 * z1 + z2 * z2), 1e-8f);
    z0 /= zn; z1 /= zn; z2 /= zn;
    float y0 = z1 * x2 - z2 * x1;
    float y1 = z2 * x0 - z0 * x2;
    float y2 = z0 * x1 - z1 * x0;
    float yn = fmaxf(sqrtf(y0 * y0 + y1 * y1 + y2 * y2), 1e-8f);
    y0 /= yn; y1 /= yn; y2 /= yn;

    float uxi, uzi, phii, uxj, uzj, phij;
    float gxi, gzi, kap_i, gxj, gzj, kap_j;
    if (PACKED) {
        const f4* pi = (const f4*)(pack + 12 * (size_t)i);
        const f4 a = pi[0], b = pi[1], c = pi[2];
        uxi = a.x; uzi = a.y; phii = a.z;
        gxi   = a.w * x0 + b.x * x1 + b.y * x2;
        gzi   = b.z * x0 + b.w * x1 + c.x * x2;
        kap_i = c.y * x0 + c.z * x1 + c.w * x2;
        const f4* pj = (const f4*)(pack + 12 * (size_t)j);
        const f4 d = pj[0], f = pj[1], g = pj[2];
        uxj = d.x; uzj = d.y; phij = d.z;
        gxj   = d.w * x0 + f.x * x1 + f.y * x2;
        gzj   = f.z * x0 + f.w * x1 + g.x * x2;
        kap_j = g.y * x0 + g.z * x1 + g.w * x2;
    } else {
        uxi = pred[3 * i]; uzi = pred[3 * i + 1]; phii = pred[3 * i + 2];
        uxj = pred[3 * j]; uzj = pred[3 * j + 1]; phij = pred[3 * j + 2];
        gxi   = grad_ux[3 * i] * x0 + grad_ux[3 * i + 1] * x1 + grad_ux[3 * i + 2] * x2;
        gzi   = grad_uz[3 * i] * x0 + grad_uz[3 * i + 1] * x1 + grad_uz[3 * i + 2] * x2;
        kap_i = grad_phi[3 * i] * x0 + grad_phi[3 * i + 1] * x1 + grad_phi[3 * i + 2] * x2;
        gxj   = grad_ux[3 * j] * x0 + grad_ux[3 * j + 1] * x1 + grad_ux[3 * j + 2] * x2;
        gzj   = grad_uz[3 * j] * x0 + grad_uz[3 * j + 1] * x1 + grad_uz[3 * j + 2] * x2;
        kap_j = grad_phi[3 * j] * x0 + grad_phi[3 * j + 1] * x1 + grad_phi[3 * j + 2] * x2;
    }
    const float dux = uxj - uxi, duz = uzj - uzi;

    const float Le   = __builtin_nontemporal_load(elemL + e);
    const float invL = 1.0f / Le;
    const float pE   = __builtin_nontemporal_load(prop_E + e);
    const float EA   = pE * __builtin_nontemporal_load(prop_A + e);
    const float EI   = pE * __builtin_nontemporal_load(prop_I22 + e);

    const float du_ax  = dux * x0 + duz * x2;
    const float eps_fd = du_ax * invL;
    const float N_fd   = EA * eps_fd;
    const float du_tr  = dux * z0 + duz * z2;
    const float kappa_fd = (phij - phii) * invL;

    const float EIL = EI * invL, EIL2 = EIL * invL, EIL3 = EIL2 * invL;
    const float V_fd = 12.0f * EIL3 * du_tr - 6.0f * EIL2 * (phii + phij);
    const float M_yi = 6.0f * EIL2 * du_tr - EIL * (4.0f * phii + 2.0f * phij);
    const float M_yj = 6.0f * EIL2 * du_tr - EIL * (2.0f * phii + 4.0f * phij);

    const float eps_ag   = 0.5f * ((x0 * gxi + x2 * gzi) + (x0 * gxj + x2 * gzj));
    const float kappa_ag = 0.5f * (kap_i + kap_j);

    const float l0 = __builtin_nontemporal_load(load + 3 * e);
    const float l1 = __builtin_nontemporal_load(load + 3 * e + 1);
    const float l2 = __builtin_nontemporal_load(load + 3 * e + 2);
    const float hl = 0.5f * Le;

    ElemOut o;
    o.Fe0 = N_fd * x0 + V_fd * z0;
    o.Fe1 = N_fd * x1 + V_fd * z1;
    o.Fe2 = N_fd * x2 + V_fd * z2;
    o.Mi0 = M_yi * y0; o.Mi1 = M_yi * y1; o.Mi2 = M_yi * y2;
    o.Mj0 = M_yj * y0; o.Mj1 = M_yj * y1; o.Mj2 = M_yj * y2;
    o.E0 = l0 * hl; o.E1 = l1 * hl; o.E2 = l2 * hl;
    o.rkin = 0.5f * (phii + phij) - du_tr * invL;
    o.d1 = eps_ag - eps_fd;
    o.d2 = kappa_ag - kappa_fd;
    o.Le = Le; o.l0 = l0; o.l1 = l1; o.l2 = l2;
    return o;
}

__device__ __forceinline__ void elem_reduce_tail(
    const ElemOut& o, double& s_rkin2, double& s_e1, double& s_e2,
    double& s_Lsum, float& m_q, float& m_L)
{
    s_rkin2 += (double)(o.rkin * o.rkin);
    s_e1 += (double)(o.d1 * o.d1);
    s_e2 += (double)(o.d2 * o.d2);
    s_Lsum += (double)o.Le;
    m_q = fmaxf(m_q, fmaxf(fabsf(o.l0), fmaxf(fabsf(o.l1), fabsf(o.l2))));
    m_L = fmaxf(m_L, o.Le);
}

// ---------------------------------------------------------------------------
// rows[k] = 16 u32 (one 64B line): [count | 15 entry tags]
// payload: 16 f32 per elem (64B line): P0={Fe,Mi0} P1={Mi1,Mi2,Mj0,Mj1}
//          P2={Mj2,E0,E1,E2} P3=zeros (full-line coverage, no sector RMW)
template <bool PACKED>
__global__ __launch_bounds__(256) void elem_rows(
    const float* __restrict__ pred, const float* __restrict__ grad_ux,
    const float* __restrict__ grad_uz, const float* __restrict__ grad_phi,
    const float* __restrict__ pack,
    const float* __restrict__ prop_E, const float* __restrict__ prop_A,
    const float* __restrict__ prop_I22, const float* __restrict__ elemL,
    const float* __restrict__ dirs, const float* __restrict__ load,
    const int* __restrict__ conn,
    float* __restrict__ payload,
    unsigned int* __restrict__ rows,
    unsigned int* __restrict__ ovf,
    Scal* sc, int n_elems)
{
    __shared__ double smD[4];
    __shared__ float  smF[4];

    double s_rkin2 = 0.0, s_e1 = 0.0, s_e2 = 0.0, s_Lsum = 0.0;
    float m_q = 0.0f, m_L = 0.0f;

    const int e = blockIdx.x * 256 + threadIdx.x;
    if (e < n_elems) {
        const i2 ij = __builtin_nontemporal_load((const i2*)conn + e);
        const int i = ij.x, j = ij.y;

        // rank claims early: latency hides under the physics
        const unsigned r_i = __hip_atomic_fetch_add(
            &rows[(size_t)16 * i], 1u, __ATOMIC_RELAXED, __HIP_MEMORY_SCOPE_AGENT);
        const unsigned r_j = __hip_atomic_fetch_add(
            &rows[(size_t)16 * j], 1u, __ATOMIC_RELAXED, __HIP_MEMORY_SCOPE_AGENT);

        const ElemOut o = elem_body<PACKED>(pred, grad_ux, grad_uz, grad_phi, pack,
                                            prop_E, prop_A, prop_I22, elemL, dirs, load,
                                            e, i, j);

        f4* pw = (f4*)(payload + 16 * (size_t)e);
        f4 P0 = {o.Fe0, o.Fe1, o.Fe2, o.Mi0};
        f4 P1 = {o.Mi1, o.Mi2, o.Mj0, o.Mj1};
        f4 P2 = {o.Mj2, o.E0, o.E1, o.E2};
        f4 P3 = {0.f, 0.f, 0.f, 0.f};
        pw[0] = P0; pw[1] = P1; pw[2] = P2; pw[3] = P3;   // cached: L3 residency

        const unsigned tag_i = ((unsigned)e << 1);
        const unsigned tag_j = ((unsigned)e << 1) | 1u;
        if (r_i < 15u) {
            rows[(size_t)16 * i + 1 + r_i] = tag_i;   // same line as the atomic
        } else {
            const unsigned oo = atomicAdd(&sc->ovf_cnt, 1u);
            if (oo < OVF_MAX) { ovf[2 * oo] = (unsigned)i; ovf[2 * oo + 1] = tag_i; }
        }
        if (r_j < 15u) {
            rows[(size_t)16 * j + 1 + r_j] = tag_j;
        } else {
            const unsigned oo = atomicAdd(&sc->ovf_cnt, 1u);
            if (oo < OVF_MAX) { ovf[2 * oo] = (unsigned)j; ovf[2 * oo + 1] = tag_j; }
        }

        elem_reduce_tail(o, s_rkin2, s_e1, s_e2, s_Lsum, m_q, m_L);
    }

    blockAtomicAddD(s_rkin2, &sc->rkin2, smD);
    blockAtomicAddD(s_e1,    &sc->e1,    smD);
    blockAtomicAddD(s_e2,    &sc->e2,    smD);
    blockAtomicAddD(s_Lsum,  &sc->Lsum,  smD);
    blockAtomicMaxF(m_q, &sc->qmax_bits, smF);
    blockAtomicMaxF(m_L, &sc->Lmax_bits, smF);
}

__global__ __launch_bounds__(256) void node_rows(
    const float* __restrict__ payload,
    const unsigned int* __restrict__ rows,
    const unsigned int* __restrict__ ovf,
    const float* __restrict__ bc_disp, const float* __restrict__ bc_rot,
    Scal* sc, int n_nodes)
{
    __shared__ double smD[4];
    __shared__ unsigned smU[4];

    double sFe2 = 0.0, sF2 = 0.0, sMr2 = 0.0, sMp2 = 0.0;
    unsigned cd = 0, cr = 0, cp = 0;

    const int k = blockIdx.x * 256 + threadIdx.x;
    if (k < n_nodes) {
        const float bd = bc_disp[k], br = bc_rot[k];
        const bool free_d = bd < 0.5f;
        const bool free_r = br < 0.5f;
        const bool pin    = (bd > 0.5f) && free_r;

        if (free_d | free_r) {   // mask-dead nodes (25%) skip all memory work
            const unsigned cnt = rows[(size_t)16 * k];
            const unsigned lim = cnt < 15u ? cnt : 15u;

            float F0 = 0.f, F1 = 0.f, F2 = 0.f;
            float M0 = 0.f, M1 = 0.f, M2 = 0.f;
            float E0 = 0.f, E1 = 0.f, E2 = 0.f;

            for (unsigned d = 0; d < lim; ++d) {
                const unsigned tag = rows[(size_t)16 * k + 1 + d];
                const unsigned e = tag >> 1;
                const bool side_j = tag & 1u;
                const f4* p = (const f4*)(payload + 16 * (size_t)e);  // one line
                const f4 a = p[0], b = p[1], c = p[2];
                const float sgn = side_j ? -1.0f : 1.0f;
                F0 += sgn * a.x; F1 += sgn * a.y; F2 += sgn * a.z;
                if (side_j) { M0 += b.z; M1 += b.w; M2 += c.x; }
                else        { M0 += a.w; M1 += b.x; M2 += b.y; }
                E0 += c.y; E1 += c.z; E2 += c.w;
            }
            if (cnt > 15u) {     // extremely rare overflow path
                const unsigned nov = min(sc->ovf_cnt, (unsigned)OVF_MAX);
                for (unsigned o2 = 0; o2 < nov; ++o2) {
                    if (ovf[2 * o2] == (unsigned)k) {
                        const unsigned tag = ovf[2 * o2 + 1];
                        const unsigned e = tag >> 1;
                        const bool side_j = tag & 1u;
                        const f4* p = (const f4*)(payload + 16 * (size_t)e);
                        const f4 a = p[0], b = p[1], c = p[2];
                        const float sgn = side_j ? -1.0f : 1.0f;
                        F0 += sgn * a.x; F1 += sgn * a.y; F2 += sgn * a.z;
                        if (side_j) { M0 += b.z; M1 += b.w; M2 += c.x; }
                        else        { M0 += a.w; M1 += b.x; M2 += b.y; }
                        E0 += c.y; E1 += c.z; E2 += c.w;
                    }
                }
            }

            if (free_d) {
                const float f0 = F0 + E0, f1 = F1 + E1, f2 = F2 + E2;
                sFe2 += (double)(E0 * E0 + E1 * E1 + E2 * E2);
                sF2  += (double)(f0 * f0 + f1 * f1 + f2 * f2);
                cd++;
            }
            if (free_r) { sMr2 += (double)(M0 * M0 + M1 * M1 + M2 * M2); cr++; }
            if (pin)    { sMp2 += (double)(M0 * M0 + M1 * M1 + M2 * M2); cp++; }
        }
    }

    blockAtomicAddD(sFe2, &sc->Fe2, smD);
    blockAtomicAddD(sF2,  &sc->F2,  smD);
    blockAtomicAddD(sMr2, &sc->Mr2, smD);
    blockAtomicAddD(sMp2, &sc->Mp2, smD);
    blockAtomicAddU(cd, &sc->cnt_d, smU);
    blockAtomicAddU(cr, &sc->cnt_r, smU);
    blockAtomicAddU(cp, &sc->cnt_p, smU);
}

// --- last-resort fallback: R1-style SoA atomics ----------------------------
__global__ __launch_bounds__(256) void elem_soa(
    const float* __restrict__ pred, const float* __restrict__ grad_ux,
    const float* __restrict__ grad_uz, const float* __restrict__ grad_phi,
    const float* __restrict__ prop_E, const float* __restrict__ prop_A,
    const float* __restrict__ prop_I22, const float* __restrict__ elemL,
    const float* __restrict__ dirs, const float* __restrict__ load,
    const int* __restrict__ conn,
    float* __restrict__ Fi, float* __restrict__ Mi, float* __restrict__ Fe,
    Scal* sc, int n_elems)
{
    __shared__ double smD[4];
    __shared__ float  smF[4];
    double s_rkin2 = 0.0, s_e1 = 0.0, s_e2 = 0.0, s_Lsum = 0.0;
    float m_q = 0.0f, m_L = 0.0f;

    const int e = blockIdx.x * 256 + threadIdx.x;
    if (e < n_elems) {
        const i2 ij = __builtin_nontemporal_load((const i2*)conn + e);
        const int i = ij.x, j = ij.y;
        const ElemOut o = elem_body<false>(pred, grad_ux, grad_uz, grad_phi, nullptr,
                                           prop_E, prop_A, prop_I22, elemL, dirs, load,
                                           e, i, j);
        atomicAdd(&Fi[3 * i], o.Fe0);  atomicAdd(&Fi[3 * i + 1], o.Fe1);  atomicAdd(&Fi[3 * i + 2], o.Fe2);
        atomicAdd(&Fi[3 * j], -o.Fe0); atomicAdd(&Fi[3 * j + 1], -o.Fe1); atomicAdd(&Fi[3 * j + 2], -o.Fe2);
        atomicAdd(&Mi[3 * i], o.Mi0);  atomicAdd(&Mi[3 * i + 1], o.Mi1);  atomicAdd(&Mi[3 * i + 2], o.Mi2);
        atomicAdd(&Mi[3 * j], o.Mj0);  atomicAdd(&Mi[3 * j + 1], o.Mj1);  atomicAdd(&Mi[3 * j + 2], o.Mj2);
        atomicAdd(&Fe[3 * i], o.E0);   atomicAdd(&Fe[3 * i + 1], o.E1);   atomicAdd(&Fe[3 * i + 2], o.E2);
        atomicAdd(&Fe[3 * j], o.E0);   atomicAdd(&Fe[3 * j + 1], o.E1);   atomicAdd(&Fe[3 * j + 2], o.E2);
        elem_reduce_tail(o, s_rkin2, s_e1, s_e2, s_Lsum, m_q, m_L);
    }
    blockAtomicAddD(s_rkin2, &sc->rkin2, smD);
    blockAtomicAddD(s_e1,    &sc->e1,    smD);
    blockAtomicAddD(s_e2,    &sc->e2,    smD);
    blockAtomicAddD(s_Lsum,  &sc->Lsum,  smD);
    blockAtomicMaxF(m_q, &sc->qmax_bits, smF);
    blockAtomicMaxF(m_L, &sc->Lmax_bits, smF);
}

__global__ __launch_bounds__(256) void node_soa(
    const float* __restrict__ Fi, const float* __restrict__ Mi, const float* __restrict__ Fe,
    const float* __restrict__ bc_disp, const float* __restrict__ bc_rot,
    Scal* sc, int n_nodes)
{
    __shared__ double smD[4];
    __shared__ unsigned smU[4];
    double sFe2 = 0.0, sF2 = 0.0, sMr2 = 0.0, sMp2 = 0.0;
    unsigned cd = 0, cr = 0, cp = 0;

    const int k = blockIdx.x * 256 + threadIdx.x;
    if (k < n_nodes) {
        const float bd = bc_disp[k], br = bc_rot[k];
        const bool free_d = bd < 0.5f;
        const bool free_r = br < 0.5f;
        const bool pin    = (bd > 0.5f) && free_r;
        if (free_d) {
            const float e0 = Fe[3 * k], e1 = Fe[3 * k + 1], e2 = Fe[3 * k + 2];
            const float f0 = Fi[3 * k] + e0, f1 = Fi[3 * k + 1] + e1, f2 = Fi[3 * k + 2] + e2;
            sFe2 += (double)(e0 * e0 + e1 * e1 + e2 * e2);
            sF2  += (double)(f0 * f0 + f1 * f1 + f2 * f2);
            cd++;
        }
        if (free_r | pin) {
            const float m0 = Mi[3 * k], m1 = Mi[3 * k + 1], m2 = Mi[3 * k + 2];
            const double mm = (double)(m0 * m0 + m1 * m1 + m2 * m2);
            if (free_r) { sMr2 += mm; cr++; }
            if (pin)    { sMp2 += mm; cp++; }
        }
    }
    blockAtomicAddD(sFe2, &sc->Fe2, smD);
    blockAtomicAddD(sF2,  &sc->F2,  smD);
    blockAtomicAddD(sMr2, &sc->Mr2, smD);
    blockAtomicAddD(sMp2, &sc->Mp2, smD);
    blockAtomicAddU(cd, &sc->cnt_d, smU);
    blockAtomicAddU(cr, &sc->cnt_r, smU);
    blockAtomicAddU(cp, &sc->cnt_p, smU);
}

__global__ void finalize(const Scal* sc, float* out, int n_elems)
{
    const double cnt_d = (double)max(sc->cnt_d, 1u);
    const double cnt_r = (double)max(sc->cnt_r, 1u);
    const double cnt_p = (double)max(sc->cnt_p, 1u);

    const double F_char = fmax(sqrt(sc->Fe2 / (cnt_d * 3.0)), 1.0);
    const double L_force = sc->F2 / (cnt_d * 3.0) / (F_char * F_char);

    const double qmax = fmax((double)__uint_as_float(sc->qmax_bits), 1.0);
    const double Lmax = (double)__uint_as_float(sc->Lmax_bits);
    const double M_char = fmax(qmax * Lmax * sc->Lsum / 8.0, 1.0);

    const double L_moment  = sc->Mr2 / (cnt_r * 3.0) / (M_char * M_char);
    const double L_neumann = sc->Mp2 / (cnt_p * 3.0) / (M_char * M_char);

    const double inv_ne = 1.0 / (double)n_elems;
    const double L_kin = sc->rkin2 * inv_ne;
    const double L_consist = sc->e1 * inv_ne + sc->e2 * inv_ne;

    out[0] = (float)(L_force + L_moment + L_neumann + 0.1 * L_kin + L_consist);
}

extern "C" void kernel_launch(void* const* d_in, const int* in_sizes, int n_in,
                              void* d_out, int out_size, void* d_ws, size_t ws_size,
                              hipStream_t stream)
{
    const float* pred     = (const float*)d_in[0];
    const float* grad_ux  = (const float*)d_in[1];
    const float* grad_uz  = (const float*)d_in[2];
    const float* grad_phi = (const float*)d_in[3];
    const float* prop_E   = (const float*)d_in[4];
    const float* prop_A   = (const float*)d_in[5];
    const float* prop_I22 = (const float*)d_in[6];
    const float* elemL    = (const float*)d_in[7];
    const float* dirs     = (const float*)d_in[8];
    const float* load     = (const float*)d_in[9];
    const float* bc_disp  = (const float*)d_in[10];
    const float* bc_rot   = (const float*)d_in[11];
    const int*   conn     = (const int*)d_in[12];

    const int n_elems = in_sizes[4];
    const int n_nodes = in_sizes[10];
    const int nblkE = (n_elems + 255) / 256;
    const int nblkN = (n_nodes + 255) / 256;

    const size_t szPack  = (size_t)n_nodes * 48;                  // 48MB
    const size_t szPay   = (size_t)n_elems * 16 * sizeof(float);  // 128MB
    const size_t szRows  = (size_t)n_nodes * 16 * sizeof(unsigned); // 64MB
    const size_t szOvf   = (size_t)OVF_MAX * 2 * sizeof(unsigned);  // 128KB
    const size_t szTail  = 256;

    char* base = (char*)d_ws;

    if (ws_size >= szPack + szPay + szRows + szOvf + szTail) {
        // ---- tier A: pack + row-table (240.2MB) ----
        float*        pack    = (float*)base;        base += szPack;
        float*        payload = (float*)base;        base += szPay;
        unsigned int* rows    = (unsigned int*)base; base += szRows;
        unsigned int* ovf     = (unsigned int*)base; base += szOvf;
        Scal*         sc      = (Scal*)base;

        hipMemsetAsync(rows, 0, szRows, stream);
        hipMemsetAsync(sc, 0, sizeof(Scal), stream);

        pack_nodes<<<nblkN, 256, 0, stream>>>(
            pred, grad_ux, grad_uz, grad_phi, pack, n_nodes);
        elem_rows<true><<<nblkE, 256, 0, stream>>>(
            pred, grad_ux, grad_uz, grad_phi, pack,
            prop_E, prop_A, prop_I22, elemL, dirs, load, conn,
            payload, rows, ovf, sc, n_elems);
        node_rows<<<nblkN, 256, 0, stream>>>(
            payload, rows, ovf, bc_disp, bc_rot, sc, n_nodes);
        finalize<<<1, 1, 0, stream>>>(sc, (float*)d_out, n_elems);
    } else if (ws_size >= szPay + szRows + szOvf + szTail) {
        // ---- tier B: row-table without pack (192.2MB) ----
        float*        payload = (float*)base;        base += szPay;
        unsigned int* rows    = (unsigned int*)base; base += szRows;
        unsigned int* ovf     = (unsigned int*)base; base += szOvf;
        Scal*         sc      = (Scal*)base;

        hipMemsetAsync(rows, 0, szRows, stream);
        hipMemsetAsync(sc, 0, sizeof(Scal), stream);

        elem_rows<false><<<nblkE, 256, 0, stream>>>(
            pred, grad_ux, grad_uz, grad_phi, nullptr,
            prop_E, prop_A, prop_I22, elemL, dirs, load, conn,
            payload, rows, ovf, sc, n_elems);
        node_rows<<<nblkN, 256, 0, stream>>>(
            payload, rows, ovf, bc_disp, bc_rot, sc, n_nodes);
        finalize<<<1, 1, 0, stream>>>(sc, (float*)d_out, n_elems);
    } else {
        // ---- tier C: SoA atomic fallback (36MB) ----
        float* Fi = (float*)d_ws;
        float* Mi = Fi + (size_t)3 * n_nodes;
        float* Fe = Mi + (size_t)3 * n_nodes;
        const size_t nodeBytes = (size_t)9 * n_nodes * sizeof(float);
        Scal* sc = (Scal*)((char*)d_ws + nodeBytes);

        hipMemsetAsync(d_ws, 0, nodeBytes + sizeof(Scal), stream);

        elem_soa<<<nblkE, 256, 0, stream>>>(
            pred, grad_ux, grad_uz, grad_phi,
            prop_E, prop_A, prop_I22, elemL, dirs, load, conn,
            Fi, Mi, Fe, sc, n_elems);
        node_soa<<<nblkN, 256, 0, stream>>>(
            Fi, Mi, Fe, bc_disp, bc_rot, sc, n_nodes);
        finalize<<<1, 1, 0, stream>>>(sc, (float*)d_out, n_elems);
    }
}

// Round 8
// 553.059 us; speedup vs baseline: 1.8023x; 1.3864x over previous
//
#include <hip/hip_runtime.h>

// ---------------------------------------------------------------------------
// StrongFormPhysicsLoss, round 8: R7 structure + 2x ILP batching on both
// scattered passes (MLP hypothesis test).
//   K1 pack_nodes : [N][12] packed node block
//   K2 elem_rows  : 2 elems/thread; atomics+gathers for both issued up front
//   K3 node_rows  : 2 nodes/thread; zipped entry loops (2x gathers in flight)
//   K4 finalize
// ---------------------------------------------------------------------------

typedef __attribute__((ext_vector_type(4))) float f4;
typedef __attribute__((ext_vector_type(2))) int   i2;

#define OVF_MAX 16384

struct Scal {
    double rkin2, e1, e2, Lsum;
    double Fe2, F2, Mr2, Mp2;
    unsigned int qmax_bits, Lmax_bits;
    unsigned int cnt_d, cnt_r, cnt_p;
    unsigned int ovf_cnt;
};

__device__ __forceinline__ double waveSumD(double v) {
#pragma unroll
    for (int o = 32; o > 0; o >>= 1) v += __shfl_down(v, o, 64);
    return v;
}
__device__ __forceinline__ float waveMaxF(float v) {
#pragma unroll
    for (int o = 32; o > 0; o >>= 1) v = fmaxf(v, __shfl_down(v, o, 64));
    return v;
}
__device__ __forceinline__ unsigned waveSumU(unsigned v) {
#pragma unroll
    for (int o = 32; o > 0; o >>= 1) v += __shfl_down(v, o, 64);
    return v;
}

__device__ __forceinline__ void blockAtomicAddD(double v, double* dst, double* smem) {
    v = waveSumD(v);
    const int lane = threadIdx.x & 63, wid = threadIdx.x >> 6;
    if (lane == 0) smem[wid] = v;
    __syncthreads();
    if (threadIdx.x == 0) atomicAdd(dst, smem[0] + smem[1] + smem[2] + smem[3]);
    __syncthreads();
}
__device__ __forceinline__ void blockAtomicMaxF(float v, unsigned int* dst, float* smem) {
    v = waveMaxF(v);
    const int lane = threadIdx.x & 63, wid = threadIdx.x >> 6;
    if (lane == 0) smem[wid] = v;
    __syncthreads();
    if (threadIdx.x == 0) {
        float r = fmaxf(fmaxf(smem[0], smem[1]), fmaxf(smem[2], smem[3]));
        atomicMax(dst, __float_as_uint(fmaxf(r, 0.0f)));
    }
    __syncthreads();
}
__device__ __forceinline__ void blockAtomicAddU(unsigned v, unsigned int* dst, unsigned* smem) {
    v = waveSumU(v);
    const int lane = threadIdx.x & 63, wid = threadIdx.x >> 6;
    if (lane == 0) smem[wid] = v;
    __syncthreads();
    if (threadIdx.x == 0) atomicAdd(dst, smem[0] + smem[1] + smem[2] + smem[3]);
    __syncthreads();
}

// ---------------------------------------------------------------------------
__global__ __launch_bounds__(256) void pack_nodes(
    const float* __restrict__ pred, const float* __restrict__ gux,
    const float* __restrict__ guz,  const float* __restrict__ gphi,
    float* __restrict__ pack, int n)
{
    const int k = blockIdx.x * blockDim.x + threadIdx.x;
    if (k >= n) return;
    const size_t b3 = 3 * (size_t)k;
    f4 A = {__builtin_nontemporal_load(pred + b3),
            __builtin_nontemporal_load(pred + b3 + 1),
            __builtin_nontemporal_load(pred + b3 + 2),
            __builtin_nontemporal_load(gux + b3)};
    f4 B = {__builtin_nontemporal_load(gux + b3 + 1),
            __builtin_nontemporal_load(gux + b3 + 2),
            __builtin_nontemporal_load(guz + b3),
            __builtin_nontemporal_load(guz + b3 + 1)};
    f4 C = {__builtin_nontemporal_load(guz + b3 + 2),
            __builtin_nontemporal_load(gphi + b3),
            __builtin_nontemporal_load(gphi + b3 + 1),
            __builtin_nontemporal_load(gphi + b3 + 2)};
    f4* o = (f4*)(pack + 12 * (size_t)k);
    o[0] = A; o[1] = B; o[2] = C;
}

// ---------------------------------------------------------------------------
struct NodeG { f4 a, b, c; };

__device__ __forceinline__ NodeG gather_node_pack(const float* __restrict__ pack, int k) {
    const f4* p = (const f4*)(pack + 12 * (size_t)k);
    NodeG g; g.a = p[0]; g.b = p[1]; g.c = p[2]; return g;
}
__device__ __forceinline__ NodeG gather_node_raw(
    const float* __restrict__ pred, const float* __restrict__ gux,
    const float* __restrict__ guz,  const float* __restrict__ gphi, int k) {
    const size_t b3 = 3 * (size_t)k;
    NodeG g;
    g.a = (f4){pred[b3], pred[b3+1], pred[b3+2], gux[b3]};
    g.b = (f4){gux[b3+1], gux[b3+2], guz[b3], guz[b3+1]};
    g.c = (f4){guz[b3+2], gphi[b3], gphi[b3+1], gphi[b3+2]};
    return g;
}

struct ElemOut {
    float Fe0, Fe1, Fe2, Mi0, Mi1, Mi2, Mj0, Mj1, Mj2, E0, E1, E2;
    float rkin, d1, d2, Le, l0, l1, l2;
};

// physics from pre-gathered node data + element scalars
__device__ __forceinline__ ElemOut physics(
    const NodeG& ni, const NodeG& nj,
    float x0, float x1, float x2,
    float Le, float EA, float EI,
    float l0, float l1, float l2)
{
    const bool par = fabsf(x1) > 0.99f;
    float z0, z1, z2;
    if (par) { z0 = x1; z1 = -x0; z2 = 0.0f; }
    else     { z0 = -x2; z1 = 0.0f; z2 = x0; }
    float zn = fmaxf(sqrtf(z0 * z0 + z1 * z1 + z2 * z2), 1e-8f);
    z0 /= zn; z1 /= zn; z2 /= zn;
    float y0 = z1 * x2 - z2 * x1;
    float y1 = z2 * x0 - z0 * x2;
    float y2 = z0 * x1 - z1 * x0;
    float yn = fmaxf(sqrtf(y0 * y0 + y1 * y1 + y2 * y2), 1e-8f);
    y0 /= yn; y1 /= yn; y2 /= yn;

    const float uxi = ni.a.x, uzi = ni.a.y, phii = ni.a.z;
    const float uxj = nj.a.x, uzj = nj.a.y, phij = nj.a.z;
    const float gxi   = ni.a.w * x0 + ni.b.x * x1 + ni.b.y * x2;
    const float gzi   = ni.b.z * x0 + ni.b.w * x1 + ni.c.x * x2;
    const float kap_i = ni.c.y * x0 + ni.c.z * x1 + ni.c.w * x2;
    const float gxj   = nj.a.w * x0 + nj.b.x * x1 + nj.b.y * x2;
    const float gzj   = nj.b.z * x0 + nj.b.w * x1 + nj.c.x * x2;
    const float kap_j = nj.c.y * x0 + nj.c.z * x1 + nj.c.w * x2;

    const float dux = uxj - uxi, duz = uzj - uzi;
    const float invL = 1.0f / Le;

    const float du_ax  = dux * x0 + duz * x2;
    const float eps_fd = du_ax * invL;
    const float N_fd   = EA * eps_fd;
    const float du_tr  = dux * z0 + duz * z2;
    const float kappa_fd = (phij - phii) * invL;

    const float EIL = EI * invL, EIL2 = EIL * invL, EIL3 = EIL2 * invL;
    const float V_fd = 12.0f * EIL3 * du_tr - 6.0f * EIL2 * (phii + phij);
    const float M_yi = 6.0f * EIL2 * du_tr - EIL * (4.0f * phii + 2.0f * phij);
    const float M_yj = 6.0f * EIL2 * du_tr - EIL * (2.0f * phii + 4.0f * phij);

    const float eps_ag   = 0.5f * ((x0 * gxi + x2 * gzi) + (x0 * gxj + x2 * gzj));
    const float kappa_ag = 0.5f * (kap_i + kap_j);
    const float hl = 0.5f * Le;

    ElemOut o;
    o.Fe0 = N_fd * x0 + V_fd * z0;
    o.Fe1 = N_fd * x1 + V_fd * z1;
    o.Fe2 = N_fd * x2 + V_fd * z2;
    o.Mi0 = M_yi * y0; o.Mi1 = M_yi * y1; o.Mi2 = M_yi * y2;
    o.Mj0 = M_yj * y0; o.Mj1 = M_yj * y1; o.Mj2 = M_yj * y2;
    o.E0 = l0 * hl; o.E1 = l1 * hl; o.E2 = l2 * hl;
    o.rkin = 0.5f * (phii + phij) - du_tr * invL;
    o.d1 = eps_ag - eps_fd;
    o.d2 = kappa_ag - kappa_fd;
    o.Le = Le; o.l0 = l0; o.l1 = l1; o.l2 = l2;
    return o;
}

__device__ __forceinline__ void elem_reduce_tail(
    const ElemOut& o, double& s_rkin2, double& s_e1, double& s_e2,
    double& s_Lsum, float& m_q, float& m_L)
{
    s_rkin2 += (double)(o.rkin * o.rkin);
    s_e1 += (double)(o.d1 * o.d1);
    s_e2 += (double)(o.d2 * o.d2);
    s_Lsum += (double)o.Le;
    m_q = fmaxf(m_q, fmaxf(fabsf(o.l0), fmaxf(fabsf(o.l1), fabsf(o.l2))));
    m_L = fmaxf(m_L, o.Le);
}

__device__ __forceinline__ void store_payload_entries(
    const ElemOut& o, int e, int i, int j, unsigned r_i, unsigned r_j,
    float* __restrict__ payload, unsigned int* __restrict__ rows,
    unsigned int* __restrict__ ovf, Scal* sc)
{
    f4* pw = (f4*)(payload + 16 * (size_t)e);
    pw[0] = (f4){o.Fe0, o.Fe1, o.Fe2, o.Mi0};
    pw[1] = (f4){o.Mi1, o.Mi2, o.Mj0, o.Mj1};
    pw[2] = (f4){o.Mj2, o.E0, o.E1, o.E2};
    pw[3] = (f4){0.f, 0.f, 0.f, 0.f};

    const unsigned tag_i = ((unsigned)e << 1);
    const unsigned tag_j = ((unsigned)e << 1) | 1u;
    if (r_i < 15u) {
        rows[(size_t)16 * i + 1 + r_i] = tag_i;
    } else {
        const unsigned oo = atomicAdd(&sc->ovf_cnt, 1u);
        if (oo < OVF_MAX) { ovf[2 * oo] = (unsigned)i; ovf[2 * oo + 1] = tag_i; }
    }
    if (r_j < 15u) {
        rows[(size_t)16 * j + 1 + r_j] = tag_j;
    } else {
        const unsigned oo = atomicAdd(&sc->ovf_cnt, 1u);
        if (oo < OVF_MAX) { ovf[2 * oo] = (unsigned)j; ovf[2 * oo + 1] = tag_j; }
    }
}

// rows[k] = 16 u32 (one 64B line): [count | 15 entry tags]
// 2 elements per thread, interleaved by 256 for coalescing.
template <bool PACKED>
__global__ __launch_bounds__(256) void elem_rows(
    const float* __restrict__ pred, const float* __restrict__ grad_ux,
    const float* __restrict__ grad_uz, const float* __restrict__ grad_phi,
    const float* __restrict__ pack,
    const float* __restrict__ prop_E, const float* __restrict__ prop_A,
    const float* __restrict__ prop_I22, const float* __restrict__ elemL,
    const float* __restrict__ dirs, const float* __restrict__ load,
    const int* __restrict__ conn,
    float* __restrict__ payload,
    unsigned int* __restrict__ rows,
    unsigned int* __restrict__ ovf,
    Scal* sc, int n_elems)
{
    __shared__ double smD[4];
    __shared__ float  smF[4];

    double s_rkin2 = 0.0, s_e1 = 0.0, s_e2 = 0.0, s_Lsum = 0.0;
    float m_q = 0.0f, m_L = 0.0f;

    const int e0 = blockIdx.x * 512 + threadIdx.x;
    const int e1 = e0 + 256;
    const bool v0 = e0 < n_elems;
    const bool v1 = e1 < n_elems;

    int i0 = 0, j0 = 0, i1 = 0, j1 = 0;
    unsigned r_i0 = 0, r_j0 = 0, r_i1 = 0, r_j1 = 0;

    if (v0) { const i2 ij = __builtin_nontemporal_load((const i2*)conn + e0); i0 = ij.x; j0 = ij.y; }
    if (v1) { const i2 ij = __builtin_nontemporal_load((const i2*)conn + e1); i1 = ij.x; j1 = ij.y; }

    // all rank atomics issued first (4 in flight)
    if (v0) {
        r_i0 = __hip_atomic_fetch_add(&rows[(size_t)16 * i0], 1u, __ATOMIC_RELAXED, __HIP_MEMORY_SCOPE_AGENT);
        r_j0 = __hip_atomic_fetch_add(&rows[(size_t)16 * j0], 1u, __ATOMIC_RELAXED, __HIP_MEMORY_SCOPE_AGENT);
    }
    if (v1) {
        r_i1 = __hip_atomic_fetch_add(&rows[(size_t)16 * i1], 1u, __ATOMIC_RELAXED, __HIP_MEMORY_SCOPE_AGENT);
        r_j1 = __hip_atomic_fetch_add(&rows[(size_t)16 * j1], 1u, __ATOMIC_RELAXED, __HIP_MEMORY_SCOPE_AGENT);
    }

    // all node gathers issued (4 x 3 f4 chains in flight)
    NodeG ni0, nj0, ni1, nj1;
    if (PACKED) {
        if (v0) { ni0 = gather_node_pack(pack, i0); nj0 = gather_node_pack(pack, j0); }
        if (v1) { ni1 = gather_node_pack(pack, i1); nj1 = gather_node_pack(pack, j1); }
    } else {
        if (v0) { ni0 = gather_node_raw(pred, grad_ux, grad_uz, grad_phi, i0);
                  nj0 = gather_node_raw(pred, grad_ux, grad_uz, grad_phi, j0); }
        if (v1) { ni1 = gather_node_raw(pred, grad_ux, grad_uz, grad_phi, i1);
                  nj1 = gather_node_raw(pred, grad_ux, grad_uz, grad_phi, j1); }
    }

    if (v0) {
        const float x0 = __builtin_nontemporal_load(dirs + 3 * e0);
        const float x1 = __builtin_nontemporal_load(dirs + 3 * e0 + 1);
        const float x2 = __builtin_nontemporal_load(dirs + 3 * e0 + 2);
        const float Le = __builtin_nontemporal_load(elemL + e0);
        const float pE = __builtin_nontemporal_load(prop_E + e0);
        const float EA = pE * __builtin_nontemporal_load(prop_A + e0);
        const float EI = pE * __builtin_nontemporal_load(prop_I22 + e0);
        const float l0 = __builtin_nontemporal_load(load + 3 * e0);
        const float l1 = __builtin_nontemporal_load(load + 3 * e0 + 1);
        const float l2 = __builtin_nontemporal_load(load + 3 * e0 + 2);
        const ElemOut o = physics(ni0, nj0, x0, x1, x2, Le, EA, EI, l0, l1, l2);
        store_payload_entries(o, e0, i0, j0, r_i0, r_j0, payload, rows, ovf, sc);
        elem_reduce_tail(o, s_rkin2, s_e1, s_e2, s_Lsum, m_q, m_L);
    }
    if (v1) {
        const float x0 = __builtin_nontemporal_load(dirs + 3 * e1);
        const float x1 = __builtin_nontemporal_load(dirs + 3 * e1 + 1);
        const float x2 = __builtin_nontemporal_load(dirs + 3 * e1 + 2);
        const float Le = __builtin_nontemporal_load(elemL + e1);
        const float pE = __builtin_nontemporal_load(prop_E + e1);
        const float EA = pE * __builtin_nontemporal_load(prop_A + e1);
        const float EI = pE * __builtin_nontemporal_load(prop_I22 + e1);
        const float l0 = __builtin_nontemporal_load(load + 3 * e1);
        const float l1 = __builtin_nontemporal_load(load + 3 * e1 + 1);
        const float l2 = __builtin_nontemporal_load(load + 3 * e1 + 2);
        const ElemOut o = physics(ni1, nj1, x0, x1, x2, Le, EA, EI, l0, l1, l2);
        store_payload_entries(o, e1, i1, j1, r_i1, r_j1, payload, rows, ovf, sc);
        elem_reduce_tail(o, s_rkin2, s_e1, s_e2, s_Lsum, m_q, m_L);
    }

    blockAtomicAddD(s_rkin2, &sc->rkin2, smD);
    blockAtomicAddD(s_e1,    &sc->e1,    smD);
    blockAtomicAddD(s_e2,    &sc->e2,    smD);
    blockAtomicAddD(s_Lsum,  &sc->Lsum,  smD);
    blockAtomicMaxF(m_q, &sc->qmax_bits, smF);
    blockAtomicMaxF(m_L, &sc->Lmax_bits, smF);
}

// ---------------------------------------------------------------------------
struct NodeAcc {
    float F0, F1, F2, M0, M1, M2, E0, E1, E2;
};
__device__ __forceinline__ void acc_entry(
    NodeAcc& A, const float* __restrict__ payload, unsigned tag)
{
    const unsigned e = tag >> 1;
    const bool side_j = tag & 1u;
    const f4* p = (const f4*)(payload + 16 * (size_t)e);
    const f4 a = p[0], b = p[1], c = p[2];
    const float sgn = side_j ? -1.0f : 1.0f;
    A.F0 += sgn * a.x; A.F1 += sgn * a.y; A.F2 += sgn * a.z;
    if (side_j) { A.M0 += b.z; A.M1 += b.w; A.M2 += c.x; }
    else        { A.M0 += a.w; A.M1 += b.x; A.M2 += b.y; }
    A.E0 += c.y; A.E1 += c.z; A.E2 += c.w;
}

__global__ __launch_bounds__(256) void node_rows(
    const float* __restrict__ payload,
    const unsigned int* __restrict__ rows,
    const unsigned int* __restrict__ ovf,
    const float* __restrict__ bc_disp, const float* __restrict__ bc_rot,
    Scal* sc, int n_nodes)
{
    __shared__ double smD[4];
    __shared__ unsigned smU[4];

    double sFe2 = 0.0, sF2 = 0.0, sMr2 = 0.0, sMp2 = 0.0;
    unsigned cd = 0, cr = 0, cp = 0;

    const int k0 = blockIdx.x * 512 + threadIdx.x;
    const int k1 = k0 + 256;
    const bool v0 = k0 < n_nodes;
    const bool v1 = k1 < n_nodes;

    float bd0 = 1.f, br0 = 1.f, bd1 = 1.f, br1 = 1.f;
    if (v0) { bd0 = bc_disp[k0]; br0 = bc_rot[k0]; }
    if (v1) { bd1 = bc_disp[k1]; br1 = bc_rot[k1]; }
    const bool fd0 = v0 && (bd0 < 0.5f), fr0 = v0 && (br0 < 0.5f);
    const bool fd1 = v1 && (bd1 < 0.5f), fr1 = v1 && (br1 < 0.5f);
    const bool pin0 = v0 && (bd0 > 0.5f) && fr0;
    const bool pin1 = v1 && (bd1 > 0.5f) && fr1;
    const bool act0 = fd0 | fr0;
    const bool act1 = fd1 | fr1;

    if (act0 | act1) {
        unsigned cnt0 = 0, cnt1 = 0;
        if (act0) cnt0 = rows[(size_t)16 * k0];
        if (act1) cnt1 = rows[(size_t)16 * k1];
        const unsigned lim0 = cnt0 < 15u ? cnt0 : 15u;
        const unsigned lim1 = cnt1 < 15u ? cnt1 : 15u;
        const unsigned lim = lim0 > lim1 ? lim0 : lim1;

        NodeAcc A0 = {0,0,0,0,0,0,0,0,0};
        NodeAcc A1 = {0,0,0,0,0,0,0,0,0};

        // zipped loops: tag reads + payload gathers for both nodes in flight
        for (unsigned d = 0; d < lim; ++d) {
            unsigned tag0 = 0xFFFFFFFFu, tag1 = 0xFFFFFFFFu;
            if (d < lim0) tag0 = rows[(size_t)16 * k0 + 1 + d];
            if (d < lim1) tag1 = rows[(size_t)16 * k1 + 1 + d];
            if (tag0 != 0xFFFFFFFFu) acc_entry(A0, payload, tag0);
            if (tag1 != 0xFFFFFFFFu) acc_entry(A1, payload, tag1);
        }

        // rare overflow
        if ((cnt0 > 15u) | (cnt1 > 15u)) {
            const unsigned nov = min(sc->ovf_cnt, (unsigned)OVF_MAX);
            for (unsigned o2 = 0; o2 < nov; ++o2) {
                const unsigned nk = ovf[2 * o2];
                if (cnt0 > 15u && nk == (unsigned)k0) acc_entry(A0, payload, ovf[2 * o2 + 1]);
                if (cnt1 > 15u && nk == (unsigned)k1) acc_entry(A1, payload, ovf[2 * o2 + 1]);
            }
        }

        if (fd0) {
            const float f0 = A0.F0 + A0.E0, f1 = A0.F1 + A0.E1, f2 = A0.F2 + A0.E2;
            sFe2 += (double)(A0.E0 * A0.E0 + A0.E1 * A0.E1 + A0.E2 * A0.E2);
            sF2  += (double)(f0 * f0 + f1 * f1 + f2 * f2);
            cd++;
        }
        if (fr0) { sMr2 += (double)(A0.M0 * A0.M0 + A0.M1 * A0.M1 + A0.M2 * A0.M2); cr++; }
        if (pin0){ sMp2 += (double)(A0.M0 * A0.M0 + A0.M1 * A0.M1 + A0.M2 * A0.M2); cp++; }

        if (fd1) {
            const float f0 = A1.F0 + A1.E0, f1 = A1.F1 + A1.E1, f2 = A1.F2 + A1.E2;
            sFe2 += (double)(A1.E0 * A1.E0 + A1.E1 * A1.E1 + A1.E2 * A1.E2);
            sF2  += (double)(f0 * f0 + f1 * f1 + f2 * f2);
            cd++;
        }
        if (fr1) { sMr2 += (double)(A1.M0 * A1.M0 + A1.M1 * A1.M1 + A1.M2 * A1.M2); cr++; }
        if (pin1){ sMp2 += (double)(A1.M0 * A1.M0 + A1.M1 * A1.M1 + A1.M2 * A1.M2); cp++; }
    }

    blockAtomicAddD(sFe2, &sc->Fe2, smD);
    blockAtomicAddD(sF2,  &sc->F2,  smD);
    blockAtomicAddD(sMr2, &sc->Mr2, smD);
    blockAtomicAddD(sMp2, &sc->Mp2, smD);
    blockAtomicAddU(cd, &sc->cnt_d, smU);
    blockAtomicAddU(cr, &sc->cnt_r, smU);
    blockAtomicAddU(cp, &sc->cnt_p, smU);
}

// --- last-resort fallback: R1-style SoA atomics ----------------------------
__global__ __launch_bounds__(256) void elem_soa(
    const float* __restrict__ pred, const float* __restrict__ grad_ux,
    const float* __restrict__ grad_uz, const float* __restrict__ grad_phi,
    const float* __restrict__ prop_E, const float* __restrict__ prop_A,
    const float* __restrict__ prop_I22, const float* __restrict__ elemL,
    const float* __restrict__ dirs, const float* __restrict__ load,
    const int* __restrict__ conn,
    float* __restrict__ Fi, float* __restrict__ Mi, float* __restrict__ Fe,
    Scal* sc, int n_elems)
{
    __shared__ double smD[4];
    __shared__ float  smF[4];
    double s_rkin2 = 0.0, s_e1 = 0.0, s_e2 = 0.0, s_Lsum = 0.0;
    float m_q = 0.0f, m_L = 0.0f;

    const int e = blockIdx.x * 256 + threadIdx.x;
    if (e < n_elems) {
        const i2 ij = __builtin_nontemporal_load((const i2*)conn + e);
        const int i = ij.x, j = ij.y;
        const NodeG ni = gather_node_raw(pred, grad_ux, grad_uz, grad_phi, i);
        const NodeG nj = gather_node_raw(pred, grad_ux, grad_uz, grad_phi, j);
        const float x0 = dirs[3 * e], x1 = dirs[3 * e + 1], x2 = dirs[3 * e + 2];
        const float Le = elemL[e];
        const float pE = prop_E[e];
        const float EA = pE * prop_A[e];
        const float EI = pE * prop_I22[e];
        const float l0 = load[3 * e], l1 = load[3 * e + 1], l2 = load[3 * e + 2];
        const ElemOut o = physics(ni, nj, x0, x1, x2, Le, EA, EI, l0, l1, l2);
        atomicAdd(&Fi[3 * i], o.Fe0);  atomicAdd(&Fi[3 * i + 1], o.Fe1);  atomicAdd(&Fi[3 * i + 2], o.Fe2);
        atomicAdd(&Fi[3 * j], -o.Fe0); atomicAdd(&Fi[3 * j + 1], -o.Fe1); atomicAdd(&Fi[3 * j + 2], -o.Fe2);
        atomicAdd(&Mi[3 * i], o.Mi0);  atomicAdd(&Mi[3 * i + 1], o.Mi1);  atomicAdd(&Mi[3 * i + 2], o.Mi2);
        atomicAdd(&Mi[3 * j], o.Mj0);  atomicAdd(&Mi[3 * j + 1], o.Mj1);  atomicAdd(&Mi[3 * j + 2], o.Mj2);
        atomicAdd(&Fe[3 * i], o.E0);   atomicAdd(&Fe[3 * i + 1], o.E1);   atomicAdd(&Fe[3 * i + 2], o.E2);
        atomicAdd(&Fe[3 * j], o.E0);   atomicAdd(&Fe[3 * j + 1], o.E1);   atomicAdd(&Fe[3 * j + 2], o.E2);
        elem_reduce_tail(o, s_rkin2, s_e1, s_e2, s_Lsum, m_q, m_L);
    }
    blockAtomicAddD(s_rkin2, &sc->rkin2, smD);
    blockAtomicAddD(s_e1,    &sc->e1,    smD);
    blockAtomicAddD(s_e2,    &sc->e2,    smD);
    blockAtomicAddD(s_Lsum,  &sc->Lsum,  smD);
    blockAtomicMaxF(m_q, &sc->qmax_bits, smF);
    blockAtomicMaxF(m_L, &sc->Lmax_bits, smF);
}

__global__ __launch_bounds__(256) void node_soa(
    const float* __restrict__ Fi, const float* __restrict__ Mi, const float* __restrict__ Fe,
    const float* __restrict__ bc_disp, const float* __restrict__ bc_rot,
    Scal* sc, int n_nodes)
{
    __shared__ double smD[4];
    __shared__ unsigned smU[4];
    double sFe2 = 0.0, sF2 = 0.0, sMr2 = 0.0, sMp2 = 0.0;
    unsigned cd = 0, cr = 0, cp = 0;

    const int k = blockIdx.x * 256 + threadIdx.x;
    if (k < n_nodes) {
        const float bd = bc_disp[k], br = bc_rot[k];
        const bool free_d = bd < 0.5f;
        const bool free_r = br < 0.5f;
        const bool pin    = (bd > 0.5f) && free_r;
        if (free_d) {
            const float e0 = Fe[3 * k], e1 = Fe[3 * k + 1], e2 = Fe[3 * k + 2];
            const float f0 = Fi[3 * k] + e0, f1 = Fi[3 * k + 1] + e1, f2 = Fi[3 * k + 2] + e2;
            sFe2 += (double)(e0 * e0 + e1 * e1 + e2 * e2);
            sF2  += (double)(f0 * f0 + f1 * f1 + f2 * f2);
            cd++;
        }
        if (free_r | pin) {
            const float m0 = Mi[3 * k], m1 = Mi[3 * k + 1], m2 = Mi[3 * k + 2];
            const double mm = (double)(m0 * m0 + m1 * m1 + m2 * m2);
            if (free_r) { sMr2 += mm; cr++; }
            if (pin)    { sMp2 += mm; cp++; }
        }
    }
    blockAtomicAddD(sFe2, &sc->Fe2, smD);
    blockAtomicAddD(sF2,  &sc->F2,  smD);
    blockAtomicAddD(sMr2, &sc->Mr2, smD);
    blockAtomicAddD(sMp2, &sc->Mp2, smD);
    blockAtomicAddU(cd, &sc->cnt_d, smU);
    blockAtomicAddU(cr, &sc->cnt_r, smU);
    blockAtomicAddU(cp, &sc->cnt_p, smU);
}

__global__ void finalize(const Scal* sc, float* out, int n_elems)
{
    const double cnt_d = (double)max(sc->cnt_d, 1u);
    const double cnt_r = (double)max(sc->cnt_r, 1u);
    const double cnt_p = (double)max(sc->cnt_p, 1u);

    const double F_char = fmax(sqrt(sc->Fe2 / (cnt_d * 3.0)), 1.0);
    const double L_force = sc->F2 / (cnt_d * 3.0) / (F_char * F_char);

    const double qmax = fmax((double)__uint_as_float(sc->qmax_bits), 1.0);
    const double Lmax = (double)__uint_as_float(sc->Lmax_bits);
    const double M_char = fmax(qmax * Lmax * sc->Lsum / 8.0, 1.0);

    const double L_moment  = sc->Mr2 / (cnt_r * 3.0) / (M_char * M_char);
    const double L_neumann = sc->Mp2 / (cnt_p * 3.0) / (M_char * M_char);

    const double inv_ne = 1.0 / (double)n_elems;
    const double L_kin = sc->rkin2 * inv_ne;
    const double L_consist = sc->e1 * inv_ne + sc->e2 * inv_ne;

    out[0] = (float)(L_force + L_moment + L_neumann + 0.1 * L_kin + L_consist);
}

extern "C" void kernel_launch(void* const* d_in, const int* in_sizes, int n_in,
                              void* d_out, int out_size, void* d_ws, size_t ws_size,
                              hipStream_t stream)
{
    const float* pred     = (const float*)d_in[0];
    const float* grad_ux  = (const float*)d_in[1];
    const float* grad_uz  = (const float*)d_in[2];
    const float* grad_phi = (const float*)d_in[3];
    const float* prop_E   = (const float*)d_in[4];
    const float* prop_A   = (const float*)d_in[5];
    const float* prop_I22 = (const float*)d_in[6];
    const float* elemL    = (const float*)d_in[7];
    const float* dirs     = (const float*)d_in[8];
    const float* load     = (const float*)d_in[9];
    const float* bc_disp  = (const float*)d_in[10];
    const float* bc_rot   = (const float*)d_in[11];
    const int*   conn     = (const int*)d_in[12];

    const int n_elems = in_sizes[4];
    const int n_nodes = in_sizes[10];
    const int nblkN  = (n_nodes + 255) / 256;
    const int nblkE2 = (n_elems + 511) / 512;   // 2 elems/thread
    const int nblkN2 = (n_nodes + 511) / 512;   // 2 nodes/thread

    const size_t szPack  = (size_t)n_nodes * 48;                    // 48MB
    const size_t szPay   = (size_t)n_elems * 16 * sizeof(float);    // 128MB
    const size_t szRows  = (size_t)n_nodes * 16 * sizeof(unsigned); // 64MB
    const size_t szOvf   = (size_t)OVF_MAX * 2 * sizeof(unsigned);  // 128KB
    const size_t szTail  = 256;

    char* base = (char*)d_ws;

    if (ws_size >= szPack + szPay + szRows + szOvf + szTail) {
        // ---- tier A: pack + row-table (240.2MB) ----
        float*        pack    = (float*)base;        base += szPack;
        float*        payload = (float*)base;        base += szPay;
        unsigned int* rows    = (unsigned int*)base; base += szRows;
        unsigned int* ovf     = (unsigned int*)base; base += szOvf;
        Scal*         sc      = (Scal*)base;

        hipMemsetAsync(rows, 0, szRows, stream);
        hipMemsetAsync(sc, 0, sizeof(Scal), stream);

        pack_nodes<<<nblkN, 256, 0, stream>>>(
            pred, grad_ux, grad_uz, grad_phi, pack, n_nodes);
        elem_rows<true><<<nblkE2, 256, 0, stream>>>(
            pred, grad_ux, grad_uz, grad_phi, pack,
            prop_E, prop_A, prop_I22, elemL, dirs, load, conn,
            payload, rows, ovf, sc, n_elems);
        node_rows<<<nblkN2, 256, 0, stream>>>(
            payload, rows, ovf, bc_disp, bc_rot, sc, n_nodes);
        finalize<<<1, 1, 0, stream>>>(sc, (float*)d_out, n_elems);
    } else if (ws_size >= szPay + szRows + szOvf + szTail) {
        // ---- tier B: row-table without pack (192.2MB) ----
        float*        payload = (float*)base;        base += szPay;
        unsigned int* rows    = (unsigned int*)base; base += szRows;
        unsigned int* ovf     = (unsigned int*)base; base += szOvf;
        Scal*         sc      = (Scal*)base;

        hipMemsetAsync(rows, 0, szRows, stream);
        hipMemsetAsync(sc, 0, sizeof(Scal), stream);

        elem_rows<false><<<nblkE2, 256, 0, stream>>>(
            pred, grad_ux, grad_uz, grad_phi, nullptr,
            prop_E, prop_A, prop_I22, elemL, dirs, load, conn,
            payload, rows, ovf, sc, n_elems);
        node_rows<<<nblkN2, 256, 0, stream>>>(
            payload, rows, ovf, bc_disp, bc_rot, sc, n_nodes);
        finalize<<<1, 1, 0, stream>>>(sc, (float*)d_out, n_elems);
    } else {
        // ---- tier C: SoA atomic fallback (36MB) ----
        float* Fi = (float*)d_ws;
        float* Mi = Fi + (size_t)3 * n_nodes;
        float* Fe = Mi + (size_t)3 * n_nodes;
        const size_t nodeBytes = (size_t)9 * n_nodes * sizeof(float);
        Scal* sc = (Scal*)((char*)d_ws + nodeBytes);

        hipMemsetAsync(d_ws, 0, nodeBytes + sizeof(Scal), stream);

        elem_soa<<<(n_elems + 255) / 256, 256, 0, stream>>>(
            pred, grad_ux, grad_uz, grad_phi,
            prop_E, prop_A, prop_I22, elemL, dirs, load, conn,
            Fi, Mi, Fe, sc, n_elems);
        node_soa<<<nblkN, 256, 0, stream>>>(
            Fi, Mi, Fe, bc_disp, bc_rot, sc, n_nodes);
        finalize<<<1, 1, 0, stream>>>(sc, (float*)d_out, n_elems);
    }
}

// Round 9
// 523.437 us; speedup vs baseline: 1.9043x; 1.0566x over previous
//
#include <hip/hip_runtime.h>

// ---------------------------------------------------------------------------
// StrongFormPhysicsLoss, round 9: ILP=4 on both scattered passes.
//   K1 pack_nodes : [N][12] packed node block
//   K2 elem_rows  : 4 elems/thread; 8 rank atomics + 8 pack-gathers in flight
//   K3 node_rows  : 4 nodes/thread; zipped row/payload gathers
//   K4 finalize
// rows[k] = 16 u32 (64B line): [count | 15 tags]; payload 64B/elem.
// ---------------------------------------------------------------------------

typedef __attribute__((ext_vector_type(4))) float f4;
typedef __attribute__((ext_vector_type(2))) int   i2;

#define OVF_MAX 16384
#define ILP 4

struct Scal {
    double rkin2, e1, e2, Lsum;
    double Fe2, F2, Mr2, Mp2;
    unsigned int qmax_bits, Lmax_bits;
    unsigned int cnt_d, cnt_r, cnt_p;
    unsigned int ovf_cnt;
};

__device__ __forceinline__ double waveSumD(double v) {
#pragma unroll
    for (int o = 32; o > 0; o >>= 1) v += __shfl_down(v, o, 64);
    return v;
}
__device__ __forceinline__ float waveMaxF(float v) {
#pragma unroll
    for (int o = 32; o > 0; o >>= 1) v = fmaxf(v, __shfl_down(v, o, 64));
    return v;
}
__device__ __forceinline__ unsigned waveSumU(unsigned v) {
#pragma unroll
    for (int o = 32; o > 0; o >>= 1) v += __shfl_down(v, o, 64);
    return v;
}

__device__ __forceinline__ void blockAtomicAddD(double v, double* dst, double* smem) {
    v = waveSumD(v);
    const int lane = threadIdx.x & 63, wid = threadIdx.x >> 6;
    if (lane == 0) smem[wid] = v;
    __syncthreads();
    if (threadIdx.x == 0) atomicAdd(dst, smem[0] + smem[1] + smem[2] + smem[3]);
    __syncthreads();
}
__device__ __forceinline__ void blockAtomicMaxF(float v, unsigned int* dst, float* smem) {
    v = waveMaxF(v);
    const int lane = threadIdx.x & 63, wid = threadIdx.x >> 6;
    if (lane == 0) smem[wid] = v;
    __syncthreads();
    if (threadIdx.x == 0) {
        float r = fmaxf(fmaxf(smem[0], smem[1]), fmaxf(smem[2], smem[3]));
        atomicMax(dst, __float_as_uint(fmaxf(r, 0.0f)));
    }
    __syncthreads();
}
__device__ __forceinline__ void blockAtomicAddU(unsigned v, unsigned int* dst, unsigned* smem) {
    v = waveSumU(v);
    const int lane = threadIdx.x & 63, wid = threadIdx.x >> 6;
    if (lane == 0) smem[wid] = v;
    __syncthreads();
    if (threadIdx.x == 0) atomicAdd(dst, smem[0] + smem[1] + smem[2] + smem[3]);
    __syncthreads();
}

// ---------------------------------------------------------------------------
__global__ __launch_bounds__(256) void pack_nodes(
    const float* __restrict__ pred, const float* __restrict__ gux,
    const float* __restrict__ guz,  const float* __restrict__ gphi,
    float* __restrict__ pack, int n)
{
    const int k = blockIdx.x * blockDim.x + threadIdx.x;
    if (k >= n) return;
    const size_t b3 = 3 * (size_t)k;
    f4 A = {__builtin_nontemporal_load(pred + b3),
            __builtin_nontemporal_load(pred + b3 + 1),
            __builtin_nontemporal_load(pred + b3 + 2),
            __builtin_nontemporal_load(gux + b3)};
    f4 B = {__builtin_nontemporal_load(gux + b3 + 1),
            __builtin_nontemporal_load(gux + b3 + 2),
            __builtin_nontemporal_load(guz + b3),
            __builtin_nontemporal_load(guz + b3 + 1)};
    f4 C = {__builtin_nontemporal_load(guz + b3 + 2),
            __builtin_nontemporal_load(gphi + b3),
            __builtin_nontemporal_load(gphi + b3 + 1),
            __builtin_nontemporal_load(gphi + b3 + 2)};
    f4* o = (f4*)(pack + 12 * (size_t)k);
    o[0] = A; o[1] = B; o[2] = C;
}

// ---------------------------------------------------------------------------
struct NodeG { f4 a, b, c; };

__device__ __forceinline__ NodeG gather_node_pack(const float* __restrict__ pack, int k) {
    const f4* p = (const f4*)(pack + 12 * (size_t)k);
    NodeG g; g.a = p[0]; g.b = p[1]; g.c = p[2]; return g;
}
__device__ __forceinline__ NodeG gather_node_raw(
    const float* __restrict__ pred, const float* __restrict__ gux,
    const float* __restrict__ guz,  const float* __restrict__ gphi, int k) {
    const size_t b3 = 3 * (size_t)k;
    NodeG g;
    g.a = (f4){pred[b3], pred[b3+1], pred[b3+2], gux[b3]};
    g.b = (f4){gux[b3+1], gux[b3+2], guz[b3], guz[b3+1]};
    g.c = (f4){guz[b3+2], gphi[b3], gphi[b3+1], gphi[b3+2]};
    return g;
}

struct ElemOut {
    float Fe0, Fe1, Fe2, Mi0, Mi1, Mi2, Mj0, Mj1, Mj2, E0, E1, E2;
    float rkin, d1, d2, Le, l0, l1, l2;
};

__device__ __forceinline__ ElemOut physics(
    const NodeG& ni, const NodeG& nj,
    float x0, float x1, float x2,
    float Le, float EA, float EI,
    float l0, float l1, float l2)
{
    const bool par = fabsf(x1) > 0.99f;
    float z0, z1, z2;
    if (par) { z0 = x1; z1 = -x0; z2 = 0.0f; }
    else     { z0 = -x2; z1 = 0.0f; z2 = x0; }
    float zn = fmaxf(sqrtf(z0 * z0 + z1 * z1 + z2 * z2), 1e-8f);
    z0 /= zn; z1 /= zn; z2 /= zn;
    float y0 = z1 * x2 - z2 * x1;
    float y1 = z2 * x0 - z0 * x2;
    float y2 = z0 * x1 - z1 * x0;
    float yn = fmaxf(sqrtf(y0 * y0 + y1 * y1 + y2 * y2), 1e-8f);
    y0 /= yn; y1 /= yn; y2 /= yn;

    const float uxi = ni.a.x, uzi = ni.a.y, phii = ni.a.z;
    const float uxj = nj.a.x, uzj = nj.a.y, phij = nj.a.z;
    const float gxi   = ni.a.w * x0 + ni.b.x * x1 + ni.b.y * x2;
    const float gzi   = ni.b.z * x0 + ni.b.w * x1 + ni.c.x * x2;
    const float kap_i = ni.c.y * x0 + ni.c.z * x1 + ni.c.w * x2;
    const float gxj   = nj.a.w * x0 + nj.b.x * x1 + nj.b.y * x2;
    const float gzj   = nj.b.z * x0 + nj.b.w * x1 + nj.c.x * x2;
    const float kap_j = nj.c.y * x0 + nj.c.z * x1 + nj.c.w * x2;

    const float dux = uxj - uxi, duz = uzj - uzi;
    const float invL = 1.0f / Le;

    const float du_ax  = dux * x0 + duz * x2;
    const float eps_fd = du_ax * invL;
    const float N_fd   = EA * eps_fd;
    const float du_tr  = dux * z0 + duz * z2;
    const float kappa_fd = (phij - phii) * invL;

    const float EIL = EI * invL, EIL2 = EIL * invL, EIL3 = EIL2 * invL;
    const float V_fd = 12.0f * EIL3 * du_tr - 6.0f * EIL2 * (phii + phij);
    const float M_yi = 6.0f * EIL2 * du_tr - EIL * (4.0f * phii + 2.0f * phij);
    const float M_yj = 6.0f * EIL2 * du_tr - EIL * (2.0f * phii + 4.0f * phij);

    const float eps_ag   = 0.5f * ((x0 * gxi + x2 * gzi) + (x0 * gxj + x2 * gzj));
    const float kappa_ag = 0.5f * (kap_i + kap_j);
    const float hl = 0.5f * Le;

    ElemOut o;
    o.Fe0 = N_fd * x0 + V_fd * z0;
    o.Fe1 = N_fd * x1 + V_fd * z1;
    o.Fe2 = N_fd * x2 + V_fd * z2;
    o.Mi0 = M_yi * y0; o.Mi1 = M_yi * y1; o.Mi2 = M_yi * y2;
    o.Mj0 = M_yj * y0; o.Mj1 = M_yj * y1; o.Mj2 = M_yj * y2;
    o.E0 = l0 * hl; o.E1 = l1 * hl; o.E2 = l2 * hl;
    o.rkin = 0.5f * (phii + phij) - du_tr * invL;
    o.d1 = eps_ag - eps_fd;
    o.d2 = kappa_ag - kappa_fd;
    o.Le = Le; o.l0 = l0; o.l1 = l1; o.l2 = l2;
    return o;
}

__device__ __forceinline__ void elem_reduce_tail(
    const ElemOut& o, double& s_rkin2, double& s_e1, double& s_e2,
    double& s_Lsum, float& m_q, float& m_L)
{
    s_rkin2 += (double)(o.rkin * o.rkin);
    s_e1 += (double)(o.d1 * o.d1);
    s_e2 += (double)(o.d2 * o.d2);
    s_Lsum += (double)o.Le;
    m_q = fmaxf(m_q, fmaxf(fabsf(o.l0), fmaxf(fabsf(o.l1), fabsf(o.l2))));
    m_L = fmaxf(m_L, o.Le);
}

__device__ __forceinline__ void store_payload_entries(
    const ElemOut& o, int e, int i, int j, unsigned r_i, unsigned r_j,
    float* __restrict__ payload, unsigned int* __restrict__ rows,
    unsigned int* __restrict__ ovf, Scal* sc)
{
    f4* pw = (f4*)(payload + 16 * (size_t)e);
    pw[0] = (f4){o.Fe0, o.Fe1, o.Fe2, o.Mi0};
    pw[1] = (f4){o.Mi1, o.Mi2, o.Mj0, o.Mj1};
    pw[2] = (f4){o.Mj2, o.E0, o.E1, o.E2};
    pw[3] = (f4){0.f, 0.f, 0.f, 0.f};

    const unsigned tag_i = ((unsigned)e << 1);
    const unsigned tag_j = ((unsigned)e << 1) | 1u;
    if (r_i < 15u) {
        rows[(size_t)16 * i + 1 + r_i] = tag_i;
    } else {
        const unsigned oo = atomicAdd(&sc->ovf_cnt, 1u);
        if (oo < OVF_MAX) { ovf[2 * oo] = (unsigned)i; ovf[2 * oo + 1] = tag_i; }
    }
    if (r_j < 15u) {
        rows[(size_t)16 * j + 1 + r_j] = tag_j;
    } else {
        const unsigned oo = atomicAdd(&sc->ovf_cnt, 1u);
        if (oo < OVF_MAX) { ovf[2 * oo] = (unsigned)j; ovf[2 * oo + 1] = tag_j; }
    }
}

// ---------------------------------------------------------------------------
template <bool PACKED>
__global__ __launch_bounds__(256) void elem_rows(
    const float* __restrict__ pred, const float* __restrict__ grad_ux,
    const float* __restrict__ grad_uz, const float* __restrict__ grad_phi,
    const float* __restrict__ pack,
    const float* __restrict__ prop_E, const float* __restrict__ prop_A,
    const float* __restrict__ prop_I22, const float* __restrict__ elemL,
    const float* __restrict__ dirs, const float* __restrict__ load,
    const int* __restrict__ conn,
    float* __restrict__ payload,
    unsigned int* __restrict__ rows,
    unsigned int* __restrict__ ovf,
    Scal* sc, int n_elems)
{
    __shared__ double smD[4];
    __shared__ float  smF[4];

    double s_rkin2 = 0.0, s_e1 = 0.0, s_e2 = 0.0, s_Lsum = 0.0;
    float m_q = 0.0f, m_L = 0.0f;

    int  e[ILP];
    bool v[ILP];
    int  ii[ILP], jj[ILP];
    unsigned ri[ILP], rj[ILP];

#pragma unroll
    for (int c = 0; c < ILP; ++c) {
        e[c] = blockIdx.x * (256 * ILP) + c * 256 + threadIdx.x;
        v[c] = e[c] < n_elems;
        ii[c] = 0; jj[c] = 0; ri[c] = 0; rj[c] = 0;
    }

#pragma unroll
    for (int c = 0; c < ILP; ++c)
        if (v[c]) { const i2 ij = __builtin_nontemporal_load((const i2*)conn + e[c]); ii[c] = ij.x; jj[c] = ij.y; }

    // all rank atomics issued first (up to 8 in flight)
#pragma unroll
    for (int c = 0; c < ILP; ++c)
        if (v[c]) {
            ri[c] = __hip_atomic_fetch_add(&rows[(size_t)16 * ii[c]], 1u, __ATOMIC_RELAXED, __HIP_MEMORY_SCOPE_AGENT);
            rj[c] = __hip_atomic_fetch_add(&rows[(size_t)16 * jj[c]], 1u, __ATOMIC_RELAXED, __HIP_MEMORY_SCOPE_AGENT);
        }

    // all node gathers issued (up to 8 lines in flight)
    NodeG ni[ILP], nj[ILP];
#pragma unroll
    for (int c = 0; c < ILP; ++c)
        if (v[c]) {
            if (PACKED) { ni[c] = gather_node_pack(pack, ii[c]); nj[c] = gather_node_pack(pack, jj[c]); }
            else        { ni[c] = gather_node_raw(pred, grad_ux, grad_uz, grad_phi, ii[c]);
                          nj[c] = gather_node_raw(pred, grad_ux, grad_uz, grad_phi, jj[c]); }
        }

#pragma unroll
    for (int c = 0; c < ILP; ++c)
        if (v[c]) {
            const int ec = e[c];
            const float x0 = __builtin_nontemporal_load(dirs + 3 * ec);
            const float x1 = __builtin_nontemporal_load(dirs + 3 * ec + 1);
            const float x2 = __builtin_nontemporal_load(dirs + 3 * ec + 2);
            const float Le = __builtin_nontemporal_load(elemL + ec);
            const float pE = __builtin_nontemporal_load(prop_E + ec);
            const float EA = pE * __builtin_nontemporal_load(prop_A + ec);
            const float EI = pE * __builtin_nontemporal_load(prop_I22 + ec);
            const float l0 = __builtin_nontemporal_load(load + 3 * ec);
            const float l1 = __builtin_nontemporal_load(load + 3 * ec + 1);
            const float l2 = __builtin_nontemporal_load(load + 3 * ec + 2);
            const ElemOut o = physics(ni[c], nj[c], x0, x1, x2, Le, EA, EI, l0, l1, l2);
            store_payload_entries(o, ec, ii[c], jj[c], ri[c], rj[c], payload, rows, ovf, sc);
            elem_reduce_tail(o, s_rkin2, s_e1, s_e2, s_Lsum, m_q, m_L);
        }

    blockAtomicAddD(s_rkin2, &sc->rkin2, smD);
    blockAtomicAddD(s_e1,    &sc->e1,    smD);
    blockAtomicAddD(s_e2,    &sc->e2,    smD);
    blockAtomicAddD(s_Lsum,  &sc->Lsum,  smD);
    blockAtomicMaxF(m_q, &sc->qmax_bits, smF);
    blockAtomicMaxF(m_L, &sc->Lmax_bits, smF);
}

// ---------------------------------------------------------------------------
struct NodeAcc { float F0, F1, F2, M0, M1, M2, E0, E1, E2; };

__device__ __forceinline__ void acc_entry(
    NodeAcc& A, const float* __restrict__ payload, unsigned tag)
{
    const unsigned e = tag >> 1;
    const bool side_j = tag & 1u;
    const f4* p = (const f4*)(payload + 16 * (size_t)e);
    const f4 a = p[0], b = p[1], c = p[2];
    const float sgn = side_j ? -1.0f : 1.0f;
    A.F0 += sgn * a.x; A.F1 += sgn * a.y; A.F2 += sgn * a.z;
    if (side_j) { A.M0 += b.z; A.M1 += b.w; A.M2 += c.x; }
    else        { A.M0 += a.w; A.M1 += b.x; A.M2 += b.y; }
    A.E0 += c.y; A.E1 += c.z; A.E2 += c.w;
}

__global__ __launch_bounds__(256) void node_rows(
    const float* __restrict__ payload,
    const unsigned int* __restrict__ rows,
    const unsigned int* __restrict__ ovf,
    const float* __restrict__ bc_disp, const float* __restrict__ bc_rot,
    Scal* sc, int n_nodes)
{
    __shared__ double smD[4];
    __shared__ unsigned smU[4];

    double sFe2 = 0.0, sF2 = 0.0, sMr2 = 0.0, sMp2 = 0.0;
    unsigned cd = 0, cr = 0, cp = 0;

    int  k[ILP];
    bool fd[ILP], fr[ILP], pin[ILP], act[ILP];
    unsigned cnt[ILP], lim[ILP];
    NodeAcc A[ILP];

    unsigned maxlim = 0;
#pragma unroll
    for (int c = 0; c < ILP; ++c) {
        k[c] = blockIdx.x * (256 * ILP) + c * 256 + threadIdx.x;
        const bool vc = k[c] < n_nodes;
        float bd = 1.f, br = 1.f;
        if (vc) { bd = bc_disp[k[c]]; br = bc_rot[k[c]]; }
        fd[c] = vc && (bd < 0.5f);
        fr[c] = vc && (br < 0.5f);
        pin[c] = vc && (bd > 0.5f) && fr[c];
        act[c] = fd[c] | fr[c];
        cnt[c] = 0;
        A[c] = (NodeAcc){0,0,0,0,0,0,0,0,0};
    }

    // row count reads (4 lines in flight)
#pragma unroll
    for (int c = 0; c < ILP; ++c)
        if (act[c]) cnt[c] = rows[(size_t)16 * k[c]];
#pragma unroll
    for (int c = 0; c < ILP; ++c) {
        lim[c] = cnt[c] < 15u ? cnt[c] : 15u;
        if (lim[c] > maxlim) maxlim = lim[c];
    }

    // zipped: 4 tag reads then 4 payload gathers per iteration
    for (unsigned d = 0; d < maxlim; ++d) {
        unsigned tag[ILP];
#pragma unroll
        for (int c = 0; c < ILP; ++c) {
            tag[c] = 0xFFFFFFFFu;
            if (d < lim[c]) tag[c] = rows[(size_t)16 * k[c] + 1 + d];
        }
#pragma unroll
        for (int c = 0; c < ILP; ++c)
            if (tag[c] != 0xFFFFFFFFu) acc_entry(A[c], payload, tag[c]);
    }

    // rare overflow
    bool anyOvf = false;
#pragma unroll
    for (int c = 0; c < ILP; ++c) anyOvf |= (cnt[c] > 15u);
    if (anyOvf) {
        const unsigned nov = min(sc->ovf_cnt, (unsigned)OVF_MAX);
        for (unsigned o2 = 0; o2 < nov; ++o2) {
            const unsigned nk = ovf[2 * o2];
#pragma unroll
            for (int c = 0; c < ILP; ++c)
                if (cnt[c] > 15u && nk == (unsigned)k[c])
                    acc_entry(A[c], payload, ovf[2 * o2 + 1]);
        }
    }

#pragma unroll
    for (int c = 0; c < ILP; ++c) {
        if (fd[c]) {
            const float f0 = A[c].F0 + A[c].E0, f1 = A[c].F1 + A[c].E1, f2 = A[c].F2 + A[c].E2;
            sFe2 += (double)(A[c].E0 * A[c].E0 + A[c].E1 * A[c].E1 + A[c].E2 * A[c].E2);
            sF2  += (double)(f0 * f0 + f1 * f1 + f2 * f2);
            cd++;
        }
        const double mm = (double)(A[c].M0 * A[c].M0 + A[c].M1 * A[c].M1 + A[c].M2 * A[c].M2);
        if (fr[c])  { sMr2 += mm; cr++; }
        if (pin[c]) { sMp2 += mm; cp++; }
    }

    blockAtomicAddD(sFe2, &sc->Fe2, smD);
    blockAtomicAddD(sF2,  &sc->F2,  smD);
    blockAtomicAddD(sMr2, &sc->Mr2, smD);
    blockAtomicAddD(sMp2, &sc->Mp2, smD);
    blockAtomicAddU(cd, &sc->cnt_d, smU);
    blockAtomicAddU(cr, &sc->cnt_r, smU);
    blockAtomicAddU(cp, &sc->cnt_p, smU);
}

// --- last-resort fallback: R1-style SoA atomics ----------------------------
__global__ __launch_bounds__(256) void elem_soa(
    const float* __restrict__ pred, const float* __restrict__ grad_ux,
    const float* __restrict__ grad_uz, const float* __restrict__ grad_phi,
    const float* __restrict__ prop_E, const float* __restrict__ prop_A,
    const float* __restrict__ prop_I22, const float* __restrict__ elemL,
    const float* __restrict__ dirs, const float* __restrict__ load,
    const int* __restrict__ conn,
    float* __restrict__ Fi, float* __restrict__ Mi, float* __restrict__ Fe,
    Scal* sc, int n_elems)
{
    __shared__ double smD[4];
    __shared__ float  smF[4];
    double s_rkin2 = 0.0, s_e1 = 0.0, s_e2 = 0.0, s_Lsum = 0.0;
    float m_q = 0.0f, m_L = 0.0f;

    const int e = blockIdx.x * 256 + threadIdx.x;
    if (e < n_elems) {
        const i2 ij = __builtin_nontemporal_load((const i2*)conn + e);
        const int i = ij.x, j = ij.y;
        const NodeG ni = gather_node_raw(pred, grad_ux, grad_uz, grad_phi, i);
        const NodeG nj = gather_node_raw(pred, grad_ux, grad_uz, grad_phi, j);
        const float x0 = dirs[3 * e], x1 = dirs[3 * e + 1], x2 = dirs[3 * e + 2];
        const float Le = elemL[e];
        const float pE = prop_E[e];
        const float EA = pE * prop_A[e];
        const float EI = pE * prop_I22[e];
        const float l0 = load[3 * e], l1 = load[3 * e + 1], l2 = load[3 * e + 2];
        const ElemOut o = physics(ni, nj, x0, x1, x2, Le, EA, EI, l0, l1, l2);
        atomicAdd(&Fi[3 * i], o.Fe0);  atomicAdd(&Fi[3 * i + 1], o.Fe1);  atomicAdd(&Fi[3 * i + 2], o.Fe2);
        atomicAdd(&Fi[3 * j], -o.Fe0); atomicAdd(&Fi[3 * j + 1], -o.Fe1); atomicAdd(&Fi[3 * j + 2], -o.Fe2);
        atomicAdd(&Mi[3 * i], o.Mi0);  atomicAdd(&Mi[3 * i + 1], o.Mi1);  atomicAdd(&Mi[3 * i + 2], o.Mi2);
        atomicAdd(&Mi[3 * j], o.Mj0);  atomicAdd(&Mi[3 * j + 1], o.Mj1);  atomicAdd(&Mi[3 * j + 2], o.Mj2);
        atomicAdd(&Fe[3 * i], o.E0);   atomicAdd(&Fe[3 * i + 1], o.E1);   atomicAdd(&Fe[3 * i + 2], o.E2);
        atomicAdd(&Fe[3 * j], o.E0);   atomicAdd(&Fe[3 * j + 1], o.E1);   atomicAdd(&Fe[3 * j + 2], o.E2);
        elem_reduce_tail(o, s_rkin2, s_e1, s_e2, s_Lsum, m_q, m_L);
    }
    blockAtomicAddD(s_rkin2, &sc->rkin2, smD);
    blockAtomicAddD(s_e1,    &sc->e1,    smD);
    blockAtomicAddD(s_e2,    &sc->e2,    smD);
    blockAtomicAddD(s_Lsum,  &sc->Lsum,  smD);
    blockAtomicMaxF(m_q, &sc->qmax_bits, smF);
    blockAtomicMaxF(m_L, &sc->Lmax_bits, smF);
}

__global__ __launch_bounds__(256) void node_soa(
    const float* __restrict__ Fi, const float* __restrict__ Mi, const float* __restrict__ Fe,
    const float* __restrict__ bc_disp, const float* __restrict__ bc_rot,
    Scal* sc, int n_nodes)
{
    __shared__ double smD[4];
    __shared__ unsigned smU[4];
    double sFe2 = 0.0, sF2 = 0.0, sMr2 = 0.0, sMp2 = 0.0;
    unsigned cd = 0, cr = 0, cp = 0;

    const int k = blockIdx.x * 256 + threadIdx.x;
    if (k < n_nodes) {
        const float bd = bc_disp[k], br = bc_rot[k];
        const bool free_d = bd < 0.5f;
        const bool free_r = br < 0.5f;
        const bool pin    = (bd > 0.5f) && free_r;
        if (free_d) {
            const float e0 = Fe[3 * k], e1 = Fe[3 * k + 1], e2 = Fe[3 * k + 2];
            const float f0 = Fi[3 * k] + e0, f1 = Fi[3 * k + 1] + e1, f2 = Fi[3 * k + 2] + e2;
            sFe2 += (double)(e0 * e0 + e1 * e1 + e2 * e2);
            sF2  += (double)(f0 * f0 + f1 * f1 + f2 * f2);
            cd++;
        }
        if (free_r | pin) {
            const float m0 = Mi[3 * k], m1 = Mi[3 * k + 1], m2 = Mi[3 * k + 2];
            const double mm = (double)(m0 * m0 + m1 * m1 + m2 * m2);
            if (free_r) { sMr2 += mm; cr++; }
            if (pin)    { sMp2 += mm; cp++; }
        }
    }
    blockAtomicAddD(sFe2, &sc->Fe2, smD);
    blockAtomicAddD(sF2,  &sc->F2,  smD);
    blockAtomicAddD(sMr2, &sc->Mr2, smD);
    blockAtomicAddD(sMp2, &sc->Mp2, smD);
    blockAtomicAddU(cd, &sc->cnt_d, smU);
    blockAtomicAddU(cr, &sc->cnt_r, smU);
    blockAtomicAddU(cp, &sc->cnt_p, smU);
}

__global__ void finalize(const Scal* sc, float* out, int n_elems)
{
    const double cnt_d = (double)max(sc->cnt_d, 1u);
    const double cnt_r = (double)max(sc->cnt_r, 1u);
    const double cnt_p = (double)max(sc->cnt_p, 1u);

    const double F_char = fmax(sqrt(sc->Fe2 / (cnt_d * 3.0)), 1.0);
    const double L_force = sc->F2 / (cnt_d * 3.0) / (F_char * F_char);

    const double qmax = fmax((double)__uint_as_float(sc->qmax_bits), 1.0);
    const double Lmax = (double)__uint_as_float(sc->Lmax_bits);
    const double M_char = fmax(qmax * Lmax * sc->Lsum / 8.0, 1.0);

    const double L_moment  = sc->Mr2 / (cnt_r * 3.0) / (M_char * M_char);
    const double L_neumann = sc->Mp2 / (cnt_p * 3.0) / (M_char * M_char);

    const double inv_ne = 1.0 / (double)n_elems;
    const double L_kin = sc->rkin2 * inv_ne;
    const double L_consist = sc->e1 * inv_ne + sc->e2 * inv_ne;

    out[0] = (float)(L_force + L_moment + L_neumann + 0.1 * L_kin + L_consist);
}

extern "C" void kernel_launch(void* const* d_in, const int* in_sizes, int n_in,
                              void* d_out, int out_size, void* d_ws, size_t ws_size,
                              hipStream_t stream)
{
    const float* pred     = (const float*)d_in[0];
    const float* grad_ux  = (const float*)d_in[1];
    const float* grad_uz  = (const float*)d_in[2];
    const float* grad_phi = (const float*)d_in[3];
    const float* prop_E   = (const float*)d_in[4];
    const float* prop_A   = (const float*)d_in[5];
    const float* prop_I22 = (const float*)d_in[6];
    const float* elemL    = (const float*)d_in[7];
    const float* dirs     = (const float*)d_in[8];
    const float* load     = (const float*)d_in[9];
    const float* bc_disp  = (const float*)d_in[10];
    const float* bc_rot   = (const float*)d_in[11];
    const int*   conn     = (const int*)d_in[12];

    const int n_elems = in_sizes[4];
    const int n_nodes = in_sizes[10];
    const int nblkN  = (n_nodes + 255) / 256;
    const int perBlk = 256 * ILP;
    const int nblkE4 = (n_elems + perBlk - 1) / perBlk;
    const int nblkN4 = (n_nodes + perBlk - 1) / perBlk;

    const size_t szPack  = (size_t)n_nodes * 48;                    // 48MB
    const size_t szPay   = (size_t)n_elems * 16 * sizeof(float);    // 128MB
    const size_t szRows  = (size_t)n_nodes * 16 * sizeof(unsigned); // 64MB
    const size_t szOvf   = (size_t)OVF_MAX * 2 * sizeof(unsigned);  // 128KB
    const size_t szTail  = 256;

    char* base = (char*)d_ws;

    if (ws_size >= szPack + szPay + szRows + szOvf + szTail) {
        // ---- tier A: pack + row-table (240.2MB) ----
        float*        pack    = (float*)base;        base += szPack;
        float*        payload = (float*)base;        base += szPay;
        unsigned int* rows    = (unsigned int*)base; base += szRows;
        unsigned int* ovf     = (unsigned int*)base; base += szOvf;
        Scal*         sc      = (Scal*)base;

        hipMemsetAsync(rows, 0, szRows, stream);
        hipMemsetAsync(sc, 0, sizeof(Scal), stream);

        pack_nodes<<<nblkN, 256, 0, stream>>>(
            pred, grad_ux, grad_uz, grad_phi, pack, n_nodes);
        elem_rows<true><<<nblkE4, 256, 0, stream>>>(
            pred, grad_ux, grad_uz, grad_phi, pack,
            prop_E, prop_A, prop_I22, elemL, dirs, load, conn,
            payload, rows, ovf, sc, n_elems);
        node_rows<<<nblkN4, 256, 0, stream>>>(
            payload, rows, ovf, bc_disp, bc_rot, sc, n_nodes);
        finalize<<<1, 1, 0, stream>>>(sc, (float*)d_out, n_elems);
    } else if (ws_size >= szPay + szRows + szOvf + szTail) {
        // ---- tier B: row-table without pack (192.2MB) ----
        float*        payload = (float*)base;        base += szPay;
        unsigned int* rows    = (unsigned int*)base; base += szRows;
        unsigned int* ovf     = (unsigned int*)base; base += szOvf;
        Scal*         sc      = (Scal*)base;

        hipMemsetAsync(rows, 0, szRows, stream);
        hipMemsetAsync(sc, 0, sizeof(Scal), stream);

        elem_rows<false><<<nblkE4, 256, 0, stream>>>(
            pred, grad_ux, grad_uz, grad_phi, nullptr,
            prop_E, prop_A, prop_I22, elemL, dirs, load, conn,
            payload, rows, ovf, sc, n_elems);
        node_rows<<<nblkN4, 256, 0, stream>>>(
            payload, rows, ovf, bc_disp, bc_rot, sc, n_nodes);
        finalize<<<1, 1, 0, stream>>>(sc, (float*)d_out, n_elems);
    } else {
        // ---- tier C: SoA atomic fallback (36MB) ----
        float* Fi = (float*)d_ws;
        float* Mi = Fi + (size_t)3 * n_nodes;
        float* Fe = Mi + (size_t)3 * n_nodes;
        const size_t nodeBytes = (size_t)9 * n_nodes * sizeof(float);
        Scal* sc = (Scal*)((char*)d_ws + nodeBytes);

        hipMemsetAsync(d_ws, 0, nodeBytes + sizeof(Scal), stream);

        elem_soa<<<(n_elems + 255) / 256, 256, 0, stream>>>(
            pred, grad_ux, grad_uz, grad_phi,
            prop_E, prop_A, prop_I22, elemL, dirs, load, conn,
            Fi, Mi, Fe, sc, n_elems);
        node_soa<<<nblkN, 256, 0, stream>>>(
            Fi, Mi, Fe, bc_disp, bc_rot, sc, n_nodes);
        finalize<<<1, 1, 0, stream>>>(sc, (float*)d_out, n_elems);
    }
}

// Round 10
// 407.865 us; speedup vs baseline: 2.4439x; 1.2834x over previous
//
#include <hip/hip_runtime.h>

// ---------------------------------------------------------------------------
// StrongFormPhysicsLoss, round 10: atomicExch linked-list inverse map —
// minimum scattered ops (1 atomic per endpoint, info-carrying).
//   K1 pack_nodes : [N][12] f32 packed node block (48MB)
//   K2 elem_ll    : ILP=4 physics; per endpoint ONE atomicExch(head[k], tag)
//                   (returns old head -> stored in payload pad, streamed);
//                   payload cached 64B/elem
//   K3 node_ll    : ILP=4 chains; head[] read COALESCED; chase payload lines
//                   (next-ptr embedded in the line being read anyway)
//   K4 finalize
// Footprint: pack 48MB + payload 128MB + head 4MB = 180MB.
// ---------------------------------------------------------------------------

typedef __attribute__((ext_vector_type(4))) float    f4;
typedef __attribute__((ext_vector_type(4))) unsigned u4;
typedef __attribute__((ext_vector_type(2))) int      i2;

#define ILP 4
#define ENDTAG 0xFFFFFFFFu

struct Scal {
    double rkin2, e1, e2, Lsum;
    double Fe2, F2, Mr2, Mp2;
    unsigned int qmax_bits, Lmax_bits;
    unsigned int cnt_d, cnt_r, cnt_p;
};

__device__ __forceinline__ double waveSumD(double v) {
#pragma unroll
    for (int o = 32; o > 0; o >>= 1) v += __shfl_down(v, o, 64);
    return v;
}
__device__ __forceinline__ float waveMaxF(float v) {
#pragma unroll
    for (int o = 32; o > 0; o >>= 1) v = fmaxf(v, __shfl_down(v, o, 64));
    return v;
}
__device__ __forceinline__ unsigned waveSumU(unsigned v) {
#pragma unroll
    for (int o = 32; o > 0; o >>= 1) v += __shfl_down(v, o, 64);
    return v;
}

__device__ __forceinline__ void blockAtomicAddD(double v, double* dst, double* smem) {
    v = waveSumD(v);
    const int lane = threadIdx.x & 63, wid = threadIdx.x >> 6;
    if (lane == 0) smem[wid] = v;
    __syncthreads();
    if (threadIdx.x == 0) atomicAdd(dst, smem[0] + smem[1] + smem[2] + smem[3]);
    __syncthreads();
}
__device__ __forceinline__ void blockAtomicMaxF(float v, unsigned int* dst, float* smem) {
    v = waveMaxF(v);
    const int lane = threadIdx.x & 63, wid = threadIdx.x >> 6;
    if (lane == 0) smem[wid] = v;
    __syncthreads();
    if (threadIdx.x == 0) {
        float r = fmaxf(fmaxf(smem[0], smem[1]), fmaxf(smem[2], smem[3]));
        atomicMax(dst, __float_as_uint(fmaxf(r, 0.0f)));
    }
    __syncthreads();
}
__device__ __forceinline__ void blockAtomicAddU(unsigned v, unsigned int* dst, unsigned* smem) {
    v = waveSumU(v);
    const int lane = threadIdx.x & 63, wid = threadIdx.x >> 6;
    if (lane == 0) smem[wid] = v;
    __syncthreads();
    if (threadIdx.x == 0) atomicAdd(dst, smem[0] + smem[1] + smem[2] + smem[3]);
    __syncthreads();
}

// ---------------------------------------------------------------------------
__global__ __launch_bounds__(256) void pack_nodes(
    const float* __restrict__ pred, const float* __restrict__ gux,
    const float* __restrict__ guz,  const float* __restrict__ gphi,
    float* __restrict__ pack, int n)
{
    const int k = blockIdx.x * blockDim.x + threadIdx.x;
    if (k >= n) return;
    const size_t b3 = 3 * (size_t)k;
    f4 A = {__builtin_nontemporal_load(pred + b3),
            __builtin_nontemporal_load(pred + b3 + 1),
            __builtin_nontemporal_load(pred + b3 + 2),
            __builtin_nontemporal_load(gux + b3)};
    f4 B = {__builtin_nontemporal_load(gux + b3 + 1),
            __builtin_nontemporal_load(gux + b3 + 2),
            __builtin_nontemporal_load(guz + b3),
            __builtin_nontemporal_load(guz + b3 + 1)};
    f4 C = {__builtin_nontemporal_load(guz + b3 + 2),
            __builtin_nontemporal_load(gphi + b3),
            __builtin_nontemporal_load(gphi + b3 + 1),
            __builtin_nontemporal_load(gphi + b3 + 2)};
    f4* o = (f4*)(pack + 12 * (size_t)k);
    o[0] = A; o[1] = B; o[2] = C;   // cached: elem gathers want residency
}

// ---------------------------------------------------------------------------
struct NodeG { f4 a, b, c; };

__device__ __forceinline__ NodeG gather_node_pack(const float* __restrict__ pack, int k) {
    const f4* p = (const f4*)(pack + 12 * (size_t)k);
    NodeG g; g.a = p[0]; g.b = p[1]; g.c = p[2]; return g;
}
__device__ __forceinline__ NodeG gather_node_raw(
    const float* __restrict__ pred, const float* __restrict__ gux,
    const float* __restrict__ guz,  const float* __restrict__ gphi, int k) {
    const size_t b3 = 3 * (size_t)k;
    NodeG g;
    g.a = (f4){pred[b3], pred[b3+1], pred[b3+2], gux[b3]};
    g.b = (f4){gux[b3+1], gux[b3+2], guz[b3], guz[b3+1]};
    g.c = (f4){guz[b3+2], gphi[b3], gphi[b3+1], gphi[b3+2]};
    return g;
}

struct ElemOut {
    float Fe0, Fe1, Fe2, Mi0, Mi1, Mi2, Mj0, Mj1, Mj2, E0, E1, E2;
    float rkin, d1, d2, Le, l0, l1, l2;
};

__device__ __forceinline__ ElemOut physics(
    const NodeG& ni, const NodeG& nj,
    float x0, float x1, float x2,
    float Le, float EA, float EI,
    float l0, float l1, float l2)
{
    const bool par = fabsf(x1) > 0.99f;
    float z0, z1, z2;
    if (par) { z0 = x1; z1 = -x0; z2 = 0.0f; }
    else     { z0 = -x2; z1 = 0.0f; z2 = x0; }
    float zn = fmaxf(sqrtf(z0 * z0 + z1 * z1 + z2 * z2), 1e-8f);
    z0 /= zn; z1 /= zn; z2 /= zn;
    float y0 = z1 * x2 - z2 * x1;
    float y1 = z2 * x0 - z0 * x2;
    float y2 = z0 * x1 - z1 * x0;
    float yn = fmaxf(sqrtf(y0 * y0 + y1 * y1 + y2 * y2), 1e-8f);
    y0 /= yn; y1 /= yn; y2 /= yn;

    const float uxi = ni.a.x, uzi = ni.a.y, phii = ni.a.z;
    const float uxj = nj.a.x, uzj = nj.a.y, phij = nj.a.z;
    const float gxi   = ni.a.w * x0 + ni.b.x * x1 + ni.b.y * x2;
    const float gzi   = ni.b.z * x0 + ni.b.w * x1 + ni.c.x * x2;
    const float kap_i = ni.c.y * x0 + ni.c.z * x1 + ni.c.w * x2;
    const float gxj   = nj.a.w * x0 + nj.b.x * x1 + nj.b.y * x2;
    const float gzj   = nj.b.z * x0 + nj.b.w * x1 + nj.c.x * x2;
    const float kap_j = nj.c.y * x0 + nj.c.z * x1 + nj.c.w * x2;

    const float dux = uxj - uxi, duz = uzj - uzi;
    const float invL = 1.0f / Le;

    const float du_ax  = dux * x0 + duz * x2;
    const float eps_fd = du_ax * invL;
    const float N_fd   = EA * eps_fd;
    const float du_tr  = dux * z0 + duz * z2;
    const float kappa_fd = (phij - phii) * invL;

    const float EIL = EI * invL, EIL2 = EIL * invL, EIL3 = EIL2 * invL;
    const float V_fd = 12.0f * EIL3 * du_tr - 6.0f * EIL2 * (phii + phij);
    const float M_yi = 6.0f * EIL2 * du_tr - EIL * (4.0f * phii + 2.0f * phij);
    const float M_yj = 6.0f * EIL2 * du_tr - EIL * (2.0f * phii + 4.0f * phij);

    const float eps_ag   = 0.5f * ((x0 * gxi + x2 * gzi) + (x0 * gxj + x2 * gzj));
    const float kappa_ag = 0.5f * (kap_i + kap_j);
    const float hl = 0.5f * Le;

    ElemOut o;
    o.Fe0 = N_fd * x0 + V_fd * z0;
    o.Fe1 = N_fd * x1 + V_fd * z1;
    o.Fe2 = N_fd * x2 + V_fd * z2;
    o.Mi0 = M_yi * y0; o.Mi1 = M_yi * y1; o.Mi2 = M_yi * y2;
    o.Mj0 = M_yj * y0; o.Mj1 = M_yj * y1; o.Mj2 = M_yj * y2;
    o.E0 = l0 * hl; o.E1 = l1 * hl; o.E2 = l2 * hl;
    o.rkin = 0.5f * (phii + phij) - du_tr * invL;
    o.d1 = eps_ag - eps_fd;
    o.d2 = kappa_ag - kappa_fd;
    o.Le = Le; o.l0 = l0; o.l1 = l1; o.l2 = l2;
    return o;
}

__device__ __forceinline__ void elem_reduce_tail(
    const ElemOut& o, double& s_rkin2, double& s_e1, double& s_e2,
    double& s_Lsum, float& m_q, float& m_L)
{
    s_rkin2 += (double)(o.rkin * o.rkin);
    s_e1 += (double)(o.d1 * o.d1);
    s_e2 += (double)(o.d2 * o.d2);
    s_Lsum += (double)o.Le;
    m_q = fmaxf(m_q, fmaxf(fabsf(o.l0), fmaxf(fabsf(o.l1), fabsf(o.l2))));
    m_L = fmaxf(m_L, o.Le);
}

// ---------------------------------------------------------------------------
// payload[e] (16 f32 = 64B line):
//   pw0={Fe0,Fe1,Fe2,Mi0} pw1={Mi1,Mi2,Mj0,Mj1} pw2={Mj2,E0,E1,E2}
//   pw3(u4)={next_i, next_j, 0, 0}
template <bool PACKED>
__global__ __launch_bounds__(256) void elem_ll(
    const float* __restrict__ pred, const float* __restrict__ grad_ux,
    const float* __restrict__ grad_uz, const float* __restrict__ grad_phi,
    const float* __restrict__ pack,
    const float* __restrict__ prop_E, const float* __restrict__ prop_A,
    const float* __restrict__ prop_I22, const float* __restrict__ elemL,
    const float* __restrict__ dirs, const float* __restrict__ load,
    const int* __restrict__ conn,
    float* __restrict__ payload,
    unsigned int* __restrict__ head,
    Scal* sc, int n_elems)
{
    __shared__ double smD[4];
    __shared__ float  smF[4];

    double s_rkin2 = 0.0, s_e1 = 0.0, s_e2 = 0.0, s_Lsum = 0.0;
    float m_q = 0.0f, m_L = 0.0f;

    int  e[ILP];
    bool v[ILP];
    int  ii[ILP], jj[ILP];
    unsigned nx_i[ILP], nx_j[ILP];

#pragma unroll
    for (int c = 0; c < ILP; ++c) {
        e[c] = blockIdx.x * (256 * ILP) + c * 256 + threadIdx.x;
        v[c] = e[c] < n_elems;
        ii[c] = 0; jj[c] = 0; nx_i[c] = ENDTAG; nx_j[c] = ENDTAG;
    }

#pragma unroll
    for (int c = 0; c < ILP; ++c)
        if (v[c]) { const i2 ij = __builtin_nontemporal_load((const i2*)conn + e[c]); ii[c] = ij.x; jj[c] = ij.y; }

    // THE scattered op: one info-carrying atomicExch per endpoint (8 in flight)
#pragma unroll
    for (int c = 0; c < ILP; ++c)
        if (v[c]) {
            nx_i[c] = __hip_atomic_exchange(&head[ii[c]], ((unsigned)e[c] << 1),
                                            __ATOMIC_RELAXED, __HIP_MEMORY_SCOPE_AGENT);
            nx_j[c] = __hip_atomic_exchange(&head[jj[c]], ((unsigned)e[c] << 1) | 1u,
                                            __ATOMIC_RELAXED, __HIP_MEMORY_SCOPE_AGENT);
        }

    // node gathers (8 lines in flight)
    NodeG ni[ILP], nj[ILP];
#pragma unroll
    for (int c = 0; c < ILP; ++c)
        if (v[c]) {
            if (PACKED) { ni[c] = gather_node_pack(pack, ii[c]); nj[c] = gather_node_pack(pack, jj[c]); }
            else        { ni[c] = gather_node_raw(pred, grad_ux, grad_uz, grad_phi, ii[c]);
                          nj[c] = gather_node_raw(pred, grad_ux, grad_uz, grad_phi, jj[c]); }
        }

#pragma unroll
    for (int c = 0; c < ILP; ++c)
        if (v[c]) {
            const int ec = e[c];
            const float x0 = __builtin_nontemporal_load(dirs + 3 * ec);
            const float x1 = __builtin_nontemporal_load(dirs + 3 * ec + 1);
            const float x2 = __builtin_nontemporal_load(dirs + 3 * ec + 2);
            const float Le = __builtin_nontemporal_load(elemL + ec);
            const float pE = __builtin_nontemporal_load(prop_E + ec);
            const float EA = pE * __builtin_nontemporal_load(prop_A + ec);
            const float EI = pE * __builtin_nontemporal_load(prop_I22 + ec);
            const float l0 = __builtin_nontemporal_load(load + 3 * ec);
            const float l1 = __builtin_nontemporal_load(load + 3 * ec + 1);
            const float l2 = __builtin_nontemporal_load(load + 3 * ec + 2);
            const ElemOut o = physics(ni[c], nj[c], x0, x1, x2, Le, EA, EI, l0, l1, l2);

            // payload write: streamed, CACHED (node pass wants L3 hits)
            f4* pw = (f4*)(payload + 16 * (size_t)ec);
            pw[0] = (f4){o.Fe0, o.Fe1, o.Fe2, o.Mi0};
            pw[1] = (f4){o.Mi1, o.Mi2, o.Mj0, o.Mj1};
            pw[2] = (f4){o.Mj2, o.E0, o.E1, o.E2};
            *(u4*)(pw + 3) = (u4){nx_i[c], nx_j[c], 0u, 0u};

            elem_reduce_tail(o, s_rkin2, s_e1, s_e2, s_Lsum, m_q, m_L);
        }

    blockAtomicAddD(s_rkin2, &sc->rkin2, smD);
    blockAtomicAddD(s_e1,    &sc->e1,    smD);
    blockAtomicAddD(s_e2,    &sc->e2,    smD);
    blockAtomicAddD(s_Lsum,  &sc->Lsum,  smD);
    blockAtomicMaxF(m_q, &sc->qmax_bits, smF);
    blockAtomicMaxF(m_L, &sc->Lmax_bits, smF);
}

// ---------------------------------------------------------------------------
struct NodeAcc { float F0, F1, F2, M0, M1, M2, E0, E1, E2; };

__global__ __launch_bounds__(256) void node_ll(
    const float* __restrict__ payload,
    const unsigned int* __restrict__ head,
    const float* __restrict__ bc_disp, const float* __restrict__ bc_rot,
    Scal* sc, int n_nodes)
{
    __shared__ double smD[4];
    __shared__ unsigned smU[4];

    double sFe2 = 0.0, sF2 = 0.0, sMr2 = 0.0, sMp2 = 0.0;
    unsigned cd = 0, cr = 0, cp = 0;

    int  k[ILP];
    bool fd[ILP], fr[ILP], pin[ILP];
    unsigned cur[ILP];
    NodeAcc A[ILP];

#pragma unroll
    for (int c = 0; c < ILP; ++c) {
        k[c] = blockIdx.x * (256 * ILP) + c * 256 + threadIdx.x;
        const bool vc = k[c] < n_nodes;
        float bd = 1.f, br = 1.f;
        if (vc) { bd = bc_disp[k[c]]; br = bc_rot[k[c]]; }
        fd[c] = vc && (bd < 0.5f);
        fr[c] = vc && (br < 0.5f);
        pin[c] = vc && (bd > 0.5f) && fr[c];
        cur[c] = ENDTAG;
        // head read is COALESCED (node-major): only for mask-live nodes
        if (fd[c] | fr[c]) cur[c] = head[k[c]];
        A[c] = (NodeAcc){0,0,0,0,0,0,0,0,0};
    }

    // chase: up to ILP independent chains in flight per thread
    while (true) {
        bool any = false;
#pragma unroll
        for (int c = 0; c < ILP; ++c) any |= (cur[c] != ENDTAG);
        if (!any) break;

        f4 r0[ILP], r1[ILP], r2[ILP];
        u4 r3[ILP];
        // issue all chain loads first
#pragma unroll
        for (int c = 0; c < ILP; ++c)
            if (cur[c] != ENDTAG) {
                const f4* p = (const f4*)(payload + 16 * (size_t)(cur[c] >> 1));
                r0[c] = p[0]; r1[c] = p[1]; r2[c] = p[2]; r3[c] = *(const u4*)(p + 3);
            }
        // consume
#pragma unroll
        for (int c = 0; c < ILP; ++c)
            if (cur[c] != ENDTAG) {
                const bool side_j = cur[c] & 1u;
                const float sgn = side_j ? -1.0f : 1.0f;
                A[c].F0 += sgn * r0[c].x; A[c].F1 += sgn * r0[c].y; A[c].F2 += sgn * r0[c].z;
                if (side_j) { A[c].M0 += r1[c].z; A[c].M1 += r1[c].w; A[c].M2 += r2[c].x; }
                else        { A[c].M0 += r0[c].w; A[c].M1 += r1[c].x; A[c].M2 += r1[c].y; }
                A[c].E0 += r2[c].y; A[c].E1 += r2[c].z; A[c].E2 += r2[c].w;
                cur[c] = side_j ? r3[c].y : r3[c].x;
            }
    }

#pragma unroll
    for (int c = 0; c < ILP; ++c) {
        if (fd[c]) {
            const float f0 = A[c].F0 + A[c].E0, f1 = A[c].F1 + A[c].E1, f2 = A[c].F2 + A[c].E2;
            sFe2 += (double)(A[c].E0 * A[c].E0 + A[c].E1 * A[c].E1 + A[c].E2 * A[c].E2);
            sF2  += (double)(f0 * f0 + f1 * f1 + f2 * f2);
            cd++;
        }
        const double mm = (double)(A[c].M0 * A[c].M0 + A[c].M1 * A[c].M1 + A[c].M2 * A[c].M2);
        if (fr[c])  { sMr2 += mm; cr++; }
        if (pin[c]) { sMp2 += mm; cp++; }
    }

    blockAtomicAddD(sFe2, &sc->Fe2, smD);
    blockAtomicAddD(sF2,  &sc->F2,  smD);
    blockAtomicAddD(sMr2, &sc->Mr2, smD);
    blockAtomicAddD(sMp2, &sc->Mp2, smD);
    blockAtomicAddU(cd, &sc->cnt_d, smU);
    blockAtomicAddU(cr, &sc->cnt_r, smU);
    blockAtomicAddU(cp, &sc->cnt_p, smU);
}

// --- last-resort fallback: R1-style SoA atomics ----------------------------
__global__ __launch_bounds__(256) void elem_soa(
    const float* __restrict__ pred, const float* __restrict__ grad_ux,
    const float* __restrict__ grad_uz, const float* __restrict__ grad_phi,
    const float* __restrict__ prop_E, const float* __restrict__ prop_A,
    const float* __restrict__ prop_I22, const float* __restrict__ elemL,
    const float* __restrict__ dirs, const float* __restrict__ load,
    const int* __restrict__ conn,
    float* __restrict__ Fi, float* __restrict__ Mi, float* __restrict__ Fe,
    Scal* sc, int n_elems)
{
    __shared__ double smD[4];
    __shared__ float  smF[4];
    double s_rkin2 = 0.0, s_e1 = 0.0, s_e2 = 0.0, s_Lsum = 0.0;
    float m_q = 0.0f, m_L = 0.0f;

    const int e = blockIdx.x * 256 + threadIdx.x;
    if (e < n_elems) {
        const i2 ij = __builtin_nontemporal_load((const i2*)conn + e);
        const int i = ij.x, j = ij.y;
        const NodeG ni = gather_node_raw(pred, grad_ux, grad_uz, grad_phi, i);
        const NodeG nj = gather_node_raw(pred, grad_ux, grad_uz, grad_phi, j);
        const float x0 = dirs[3 * e], x1 = dirs[3 * e + 1], x2 = dirs[3 * e + 2];
        const float Le = elemL[e];
        const float pE = prop_E[e];
        const float EA = pE * prop_A[e];
        const float EI = pE * prop_I22[e];
        const float l0 = load[3 * e], l1 = load[3 * e + 1], l2 = load[3 * e + 2];
        const ElemOut o = physics(ni, nj, x0, x1, x2, Le, EA, EI, l0, l1, l2);
        atomicAdd(&Fi[3 * i], o.Fe0);  atomicAdd(&Fi[3 * i + 1], o.Fe1);  atomicAdd(&Fi[3 * i + 2], o.Fe2);
        atomicAdd(&Fi[3 * j], -o.Fe0); atomicAdd(&Fi[3 * j + 1], -o.Fe1); atomicAdd(&Fi[3 * j + 2], -o.Fe2);
        atomicAdd(&Mi[3 * i], o.Mi0);  atomicAdd(&Mi[3 * i + 1], o.Mi1);  atomicAdd(&Mi[3 * i + 2], o.Mi2);
        atomicAdd(&Mi[3 * j], o.Mj0);  atomicAdd(&Mi[3 * j + 1], o.Mj1);  atomicAdd(&Mi[3 * j + 2], o.Mj2);
        atomicAdd(&Fe[3 * i], o.E0);   atomicAdd(&Fe[3 * i + 1], o.E1);   atomicAdd(&Fe[3 * i + 2], o.E2);
        atomicAdd(&Fe[3 * j], o.E0);   atomicAdd(&Fe[3 * j + 1], o.E1);   atomicAdd(&Fe[3 * j + 2], o.E2);
        elem_reduce_tail(o, s_rkin2, s_e1, s_e2, s_Lsum, m_q, m_L);
    }
    blockAtomicAddD(s_rkin2, &sc->rkin2, smD);
    blockAtomicAddD(s_e1,    &sc->e1,    smD);
    blockAtomicAddD(s_e2,    &sc->e2,    smD);
    blockAtomicAddD(s_Lsum,  &sc->Lsum,  smD);
    blockAtomicMaxF(m_q, &sc->qmax_bits, smF);
    blockAtomicMaxF(m_L, &sc->Lmax_bits, smF);
}

__global__ __launch_bounds__(256) void node_soa(
    const float* __restrict__ Fi, const float* __restrict__ Mi, const float* __restrict__ Fe,
    const float* __restrict__ bc_disp, const float* __restrict__ bc_rot,
    Scal* sc, int n_nodes)
{
    __shared__ double smD[4];
    __shared__ unsigned smU[4];
    double sFe2 = 0.0, sF2 = 0.0, sMr2 = 0.0, sMp2 = 0.0;
    unsigned cd = 0, cr = 0, cp = 0;

    const int k = blockIdx.x * 256 + threadIdx.x;
    if (k < n_nodes) {
        const float bd = bc_disp[k], br = bc_rot[k];
        const bool free_d = bd < 0.5f;
        const bool free_r = br < 0.5f;
        const bool pin    = (bd > 0.5f) && free_r;
        if (free_d) {
            const float e0 = Fe[3 * k], e1 = Fe[3 * k + 1], e2 = Fe[3 * k + 2];
            const float f0 = Fi[3 * k] + e0, f1 = Fi[3 * k + 1] + e1, f2 = Fi[3 * k + 2] + e2;
            sFe2 += (double)(e0 * e0 + e1 * e1 + e2 * e2);
            sF2  += (double)(f0 * f0 + f1 * f1 + f2 * f2);
            cd++;
        }
        if (free_r | pin) {
            const float m0 = Mi[3 * k], m1 = Mi[3 * k + 1], m2 = Mi[3 * k + 2];
            const double mm = (double)(m0 * m0 + m1 * m1 + m2 * m2);
            if (free_r) { sMr2 += mm; cr++; }
            if (pin)    { sMp2 += mm; cp++; }
        }
    }
    blockAtomicAddD(sFe2, &sc->Fe2, smD);
    blockAtomicAddD(sF2,  &sc->F2,  smD);
    blockAtomicAddD(sMr2, &sc->Mr2, smD);
    blockAtomicAddD(sMp2, &sc->Mp2, smD);
    blockAtomicAddU(cd, &sc->cnt_d, smU);
    blockAtomicAddU(cr, &sc->cnt_r, smU);
    blockAtomicAddU(cp, &sc->cnt_p, smU);
}

__global__ void finalize(const Scal* sc, float* out, int n_elems)
{
    const double cnt_d = (double)max(sc->cnt_d, 1u);
    const double cnt_r = (double)max(sc->cnt_r, 1u);
    const double cnt_p = (double)max(sc->cnt_p, 1u);

    const double F_char = fmax(sqrt(sc->Fe2 / (cnt_d * 3.0)), 1.0);
    const double L_force = sc->F2 / (cnt_d * 3.0) / (F_char * F_char);

    const double qmax = fmax((double)__uint_as_float(sc->qmax_bits), 1.0);
    const double Lmax = (double)__uint_as_float(sc->Lmax_bits);
    const double M_char = fmax(qmax * Lmax * sc->Lsum / 8.0, 1.0);

    const double L_moment  = sc->Mr2 / (cnt_r * 3.0) / (M_char * M_char);
    const double L_neumann = sc->Mp2 / (cnt_p * 3.0) / (M_char * M_char);

    const double inv_ne = 1.0 / (double)n_elems;
    const double L_kin = sc->rkin2 * inv_ne;
    const double L_consist = sc->e1 * inv_ne + sc->e2 * inv_ne;

    out[0] = (float)(L_force + L_moment + L_neumann + 0.1 * L_kin + L_consist);
}

extern "C" void kernel_launch(void* const* d_in, const int* in_sizes, int n_in,
                              void* d_out, int out_size, void* d_ws, size_t ws_size,
                              hipStream_t stream)
{
    const float* pred     = (const float*)d_in[0];
    const float* grad_ux  = (const float*)d_in[1];
    const float* grad_uz  = (const float*)d_in[2];
    const float* grad_phi = (const float*)d_in[3];
    const float* prop_E   = (const float*)d_in[4];
    const float* prop_A   = (const float*)d_in[5];
    const float* prop_I22 = (const float*)d_in[6];
    const float* elemL    = (const float*)d_in[7];
    const float* dirs     = (const float*)d_in[8];
    const float* load     = (const float*)d_in[9];
    const float* bc_disp  = (const float*)d_in[10];
    const float* bc_rot   = (const float*)d_in[11];
    const int*   conn     = (const int*)d_in[12];

    const int n_elems = in_sizes[4];
    const int n_nodes = in_sizes[10];
    const int nblkN  = (n_nodes + 255) / 256;
    const int perBlk = 256 * ILP;
    const int nblkE4 = (n_elems + perBlk - 1) / perBlk;
    const int nblkN4 = (n_nodes + perBlk - 1) / perBlk;

    const size_t szPack = (size_t)n_nodes * 48;                  // 48MB
    const size_t szPay  = (size_t)n_elems * 16 * sizeof(float);  // 128MB
    const size_t szHead = (size_t)n_nodes * sizeof(unsigned);    // 4MB
    const size_t szTail = 256;

    char* base = (char*)d_ws;

    if (ws_size >= szPack + szPay + szHead + szTail) {
        // ---- tier A: pack + linked-list (180MB) ----
        float*        pack    = (float*)base;        base += szPack;
        float*        payload = (float*)base;        base += szPay;
        unsigned int* head    = (unsigned int*)base; base += szHead;
        Scal*         sc      = (Scal*)base;

        hipMemsetAsync(head, 0xFF, szHead, stream);   // all-ENDTAG
        hipMemsetAsync(sc, 0, sizeof(Scal), stream);

        pack_nodes<<<nblkN, 256, 0, stream>>>(
            pred, grad_ux, grad_uz, grad_phi, pack, n_nodes);
        elem_ll<true><<<nblkE4, 256, 0, stream>>>(
            pred, grad_ux, grad_uz, grad_phi, pack,
            prop_E, prop_A, prop_I22, elemL, dirs, load, conn,
            payload, head, sc, n_elems);
        node_ll<<<nblkN4, 256, 0, stream>>>(
            payload, head, bc_disp, bc_rot, sc, n_nodes);
        finalize<<<1, 1, 0, stream>>>(sc, (float*)d_out, n_elems);
    } else if (ws_size >= szPay + szHead + szTail) {
        // ---- tier B: linked-list without pack (132MB) ----
        float*        payload = (float*)base;        base += szPay;
        unsigned int* head    = (unsigned int*)base; base += szHead;
        Scal*         sc      = (Scal*)base;

        hipMemsetAsync(head, 0xFF, szHead, stream);
        hipMemsetAsync(sc, 0, sizeof(Scal), stream);

        elem_ll<false><<<nblkE4, 256, 0, stream>>>(
            pred, grad_ux, grad_uz, grad_phi, nullptr,
            prop_E, prop_A, prop_I22, elemL, dirs, load, conn,
            payload, head, sc, n_elems);
        node_ll<<<nblkN4, 256, 0, stream>>>(
            payload, head, bc_disp, bc_rot, sc, n_nodes);
        finalize<<<1, 1, 0, stream>>>(sc, (float*)d_out, n_elems);
    } else {
        // ---- tier C: SoA atomic fallback (36MB) ----
        float* Fi = (float*)d_ws;
        float* Mi = Fi + (size_t)3 * n_nodes;
        float* Fe = Mi + (size_t)3 * n_nodes;
        const size_t nodeBytes = (size_t)9 * n_nodes * sizeof(float);
        Scal* sc = (Scal*)((char*)d_ws + nodeBytes);

        hipMemsetAsync(d_ws, 0, nodeBytes + sizeof(Scal), stream);

        elem_soa<<<(n_elems + 255) / 256, 256, 0, stream>>>(
            pred, grad_ux, grad_uz, grad_phi,
            prop_E, prop_A, prop_I22, elemL, dirs, load, conn,
            Fi, Mi, Fe, sc, n_elems);
        node_soa<<<nblkN, 256, 0, stream>>>(
            Fi, Mi, Fe, bc_disp, bc_rot, sc, n_nodes);
        finalize<<<1, 1, 0, stream>>>(sc, (float*)d_out, n_elems);
    }
}

// Round 11
// 389.029 us; speedup vs baseline: 2.5622x; 1.0484x over previous
//
#include <hip/hip_runtime.h>
#include <hip/hip_fp16.h>

// ---------------------------------------------------------------------------
// StrongFormPhysicsLoss, round 11: R10 linked-list + fp16 intermediates so
// the whole random-access working set (pack 32MB + payload 64MB + head 4MB
// = 100MB) is L3-resident -> lower latency per scattered op.
//   K1 pack_nodes : [N] 32B fp16 node rows + head[k]=ENDTAG init
//   K2 elem_ll    : ILP=4 physics; 1 atomicExch per endpoint; 32B fp16
//                   payload records w/ embedded next-pointers
//   K3 node_ll    : ILP=4 chain chase over 32B records
//   K4 finalize
// ---------------------------------------------------------------------------

typedef __attribute__((ext_vector_type(4))) float    f4;
typedef __attribute__((ext_vector_type(4))) unsigned u4;
typedef __attribute__((ext_vector_type(2))) int      i2;

#define ILP 4
#define ENDTAG 0xFFFFFFFFu

struct Scal {
    double rkin2, e1, e2, Lsum;
    double Fe2, F2, Mr2, Mp2;
    unsigned int qmax_bits, Lmax_bits;
    unsigned int cnt_d, cnt_r, cnt_p;
};

__device__ __forceinline__ unsigned pkh(float a, float b) {
    __half2 h = __floats2half2_rn(a, b);
    return *reinterpret_cast<unsigned*>(&h);
}
__device__ __forceinline__ float2 unpkh(unsigned u) {
    __half2 h = *reinterpret_cast<__half2*>(&u);
    return __half22float2(h);
}

__device__ __forceinline__ double waveSumD(double v) {
#pragma unroll
    for (int o = 32; o > 0; o >>= 1) v += __shfl_down(v, o, 64);
    return v;
}
__device__ __forceinline__ float waveMaxF(float v) {
#pragma unroll
    for (int o = 32; o > 0; o >>= 1) v = fmaxf(v, __shfl_down(v, o, 64));
    return v;
}
__device__ __forceinline__ unsigned waveSumU(unsigned v) {
#pragma unroll
    for (int o = 32; o > 0; o >>= 1) v += __shfl_down(v, o, 64);
    return v;
}

__device__ __forceinline__ void blockAtomicAddD(double v, double* dst, double* smem) {
    v = waveSumD(v);
    const int lane = threadIdx.x & 63, wid = threadIdx.x >> 6;
    if (lane == 0) smem[wid] = v;
    __syncthreads();
    if (threadIdx.x == 0) atomicAdd(dst, smem[0] + smem[1] + smem[2] + smem[3]);
    __syncthreads();
}
__device__ __forceinline__ void blockAtomicMaxF(float v, unsigned int* dst, float* smem) {
    v = waveMaxF(v);
    const int lane = threadIdx.x & 63, wid = threadIdx.x >> 6;
    if (lane == 0) smem[wid] = v;
    __syncthreads();
    if (threadIdx.x == 0) {
        float r = fmaxf(fmaxf(smem[0], smem[1]), fmaxf(smem[2], smem[3]));
        atomicMax(dst, __float_as_uint(fmaxf(r, 0.0f)));
    }
    __syncthreads();
}
__device__ __forceinline__ void blockAtomicAddU(unsigned v, unsigned int* dst, unsigned* smem) {
    v = waveSumU(v);
    const int lane = threadIdx.x & 63, wid = threadIdx.x >> 6;
    if (lane == 0) smem[wid] = v;
    __syncthreads();
    if (threadIdx.x == 0) atomicAdd(dst, smem[0] + smem[1] + smem[2] + smem[3]);
    __syncthreads();
}

// ---------------------------------------------------------------------------
// fp16 pack row (32B = 8 u32): u0=(ux,uz) u1=(phi,gux0) u2=(gux1,gux2)
//   u3=(guz0,guz1) u4=(guz2,gphi0) u5=(gphi1,gphi2) u6,u7 pad
__global__ __launch_bounds__(256) void pack_nodes(
    const float* __restrict__ pred, const float* __restrict__ gux,
    const float* __restrict__ guz,  const float* __restrict__ gphi,
    unsigned* __restrict__ pack, unsigned* __restrict__ head, int n)
{
    const int k = blockIdx.x * blockDim.x + threadIdx.x;
    if (k >= n) return;
    const size_t b3 = 3 * (size_t)k;
    const float p0 = __builtin_nontemporal_load(pred + b3);
    const float p1 = __builtin_nontemporal_load(pred + b3 + 1);
    const float p2 = __builtin_nontemporal_load(pred + b3 + 2);
    const float a0 = __builtin_nontemporal_load(gux + b3);
    const float a1 = __builtin_nontemporal_load(gux + b3 + 1);
    const float a2 = __builtin_nontemporal_load(gux + b3 + 2);
    const float z0 = __builtin_nontemporal_load(guz + b3);
    const float z1 = __builtin_nontemporal_load(guz + b3 + 1);
    const float z2 = __builtin_nontemporal_load(guz + b3 + 2);
    const float f0 = __builtin_nontemporal_load(gphi + b3);
    const float f1 = __builtin_nontemporal_load(gphi + b3 + 1);
    const float f2 = __builtin_nontemporal_load(gphi + b3 + 2);

    u4* o = (u4*)(pack + 8 * (size_t)k);
    o[0] = (u4){pkh(p0, p1), pkh(p2, a0), pkh(a1, a2), pkh(z0, z1)};
    o[1] = (u4){pkh(z2, f0), pkh(f1, f2), 0u, 0u};
    head[k] = ENDTAG;
}

// ---------------------------------------------------------------------------
struct NodeG { f4 a, b, c; };

__device__ __forceinline__ NodeG gather_node_h(const unsigned* __restrict__ pack, int k) {
    const u4* p = (const u4*)(pack + 8 * (size_t)k);
    const u4 q0 = p[0], q1 = p[1];
    const float2 uu = unpkh(q0.x), pg = unpkh(q0.y), g12 = unpkh(q0.z);
    const float2 zz = unpkh(q0.w), zp = unpkh(q1.x), pp = unpkh(q1.y);
    NodeG g;
    g.a = (f4){uu.x, uu.y, pg.x, pg.y};
    g.b = (f4){g12.x, g12.y, zz.x, zz.y};
    g.c = (f4){zp.x, zp.y, pp.x, pp.y};
    return g;
}
__device__ __forceinline__ NodeG gather_node_raw(
    const float* __restrict__ pred, const float* __restrict__ gux,
    const float* __restrict__ guz,  const float* __restrict__ gphi, int k) {
    const size_t b3 = 3 * (size_t)k;
    NodeG g;
    g.a = (f4){pred[b3], pred[b3+1], pred[b3+2], gux[b3]};
    g.b = (f4){gux[b3+1], gux[b3+2], guz[b3], guz[b3+1]};
    g.c = (f4){guz[b3+2], gphi[b3], gphi[b3+1], gphi[b3+2]};
    return g;
}

struct ElemOut {
    float Fe0, Fe1, Fe2, Mi0, Mi1, Mi2, Mj0, Mj1, Mj2, E0, E1, E2;
    float rkin, d1, d2, Le, l0, l1, l2;
};

__device__ __forceinline__ ElemOut physics(
    const NodeG& ni, const NodeG& nj,
    float x0, float x1, float x2,
    float Le, float EA, float EI,
    float l0, float l1, float l2)
{
    const bool par = fabsf(x1) > 0.99f;
    float z0, z1, z2;
    if (par) { z0 = x1; z1 = -x0; z2 = 0.0f; }
    else     { z0 = -x2; z1 = 0.0f; z2 = x0; }
    float zn = fmaxf(sqrtf(z0 * z0 + z1 * z1 + z2 * z2), 1e-8f);
    z0 /= zn; z1 /= zn; z2 /= zn;
    float y0 = z1 * x2 - z2 * x1;
    float y1 = z2 * x0 - z0 * x2;
    float y2 = z0 * x1 - z1 * x0;
    float yn = fmaxf(sqrtf(y0 * y0 + y1 * y1 + y2 * y2), 1e-8f);
    y0 /= yn; y1 /= yn; y2 /= yn;

    const float uxi = ni.a.x, uzi = ni.a.y, phii = ni.a.z;
    const float uxj = nj.a.x, uzj = nj.a.y, phij = nj.a.z;
    const float gxi   = ni.a.w * x0 + ni.b.x * x1 + ni.b.y * x2;
    const float gzi   = ni.b.z * x0 + ni.b.w * x1 + ni.c.x * x2;
    const float kap_i = ni.c.y * x0 + ni.c.z * x1 + ni.c.w * x2;
    const float gxj   = nj.a.w * x0 + nj.b.x * x1 + nj.b.y * x2;
    const float gzj   = nj.b.z * x0 + nj.b.w * x1 + nj.c.x * x2;
    const float kap_j = nj.c.y * x0 + nj.c.z * x1 + nj.c.w * x2;

    const float dux = uxj - uxi, duz = uzj - uzi;
    const float invL = 1.0f / Le;

    const float du_ax  = dux * x0 + duz * x2;
    const float eps_fd = du_ax * invL;
    const float N_fd   = EA * eps_fd;
    const float du_tr  = dux * z0 + duz * z2;
    const float kappa_fd = (phij - phii) * invL;

    const float EIL = EI * invL, EIL2 = EIL * invL, EIL3 = EIL2 * invL;
    const float V_fd = 12.0f * EIL3 * du_tr - 6.0f * EIL2 * (phii + phij);
    const float M_yi = 6.0f * EIL2 * du_tr - EIL * (4.0f * phii + 2.0f * phij);
    const float M_yj = 6.0f * EIL2 * du_tr - EIL * (2.0f * phii + 4.0f * phij);

    const float eps_ag   = 0.5f * ((x0 * gxi + x2 * gzi) + (x0 * gxj + x2 * gzj));
    const float kappa_ag = 0.5f * (kap_i + kap_j);
    const float hl = 0.5f * Le;

    ElemOut o;
    o.Fe0 = N_fd * x0 + V_fd * z0;
    o.Fe1 = N_fd * x1 + V_fd * z1;
    o.Fe2 = N_fd * x2 + V_fd * z2;
    o.Mi0 = M_yi * y0; o.Mi1 = M_yi * y1; o.Mi2 = M_yi * y2;
    o.Mj0 = M_yj * y0; o.Mj1 = M_yj * y1; o.Mj2 = M_yj * y2;
    o.E0 = l0 * hl; o.E1 = l1 * hl; o.E2 = l2 * hl;
    o.rkin = 0.5f * (phii + phij) - du_tr * invL;
    o.d1 = eps_ag - eps_fd;
    o.d2 = kappa_ag - kappa_fd;
    o.Le = Le; o.l0 = l0; o.l1 = l1; o.l2 = l2;
    return o;
}

__device__ __forceinline__ void elem_reduce_tail(
    const ElemOut& o, double& s_rkin2, double& s_e1, double& s_e2,
    double& s_Lsum, float& m_q, float& m_L)
{
    s_rkin2 += (double)(o.rkin * o.rkin);
    s_e1 += (double)(o.d1 * o.d1);
    s_e2 += (double)(o.d2 * o.d2);
    s_Lsum += (double)o.Le;
    m_q = fmaxf(m_q, fmaxf(fabsf(o.l0), fmaxf(fabsf(o.l1), fabsf(o.l2))));
    m_L = fmaxf(m_L, o.Le);
}

// ---------------------------------------------------------------------------
// fp16 payload record (32B = 8 u32):
//   u0=(Fe0,Fe1) u1=(Fe2,Mi0) u2=(Mi1,Mi2) u3=(Mj0,Mj1)
//   u4=(Mj2,E0)  u5=(E1,E2)   u6=next_i    u7=next_j
template <bool PACKED>
__global__ __launch_bounds__(256) void elem_ll(
    const float* __restrict__ pred, const float* __restrict__ grad_ux,
    const float* __restrict__ grad_uz, const float* __restrict__ grad_phi,
    const unsigned* __restrict__ pack,
    const float* __restrict__ prop_E, const float* __restrict__ prop_A,
    const float* __restrict__ prop_I22, const float* __restrict__ elemL,
    const float* __restrict__ dirs, const float* __restrict__ load,
    const int* __restrict__ conn,
    unsigned* __restrict__ payload,
    unsigned int* __restrict__ head,
    Scal* sc, int n_elems)
{
    __shared__ double smD[4];
    __shared__ float  smF[4];

    double s_rkin2 = 0.0, s_e1 = 0.0, s_e2 = 0.0, s_Lsum = 0.0;
    float m_q = 0.0f, m_L = 0.0f;

    int  e[ILP];
    bool v[ILP];
    int  ii[ILP], jj[ILP];
    unsigned nx_i[ILP], nx_j[ILP];

#pragma unroll
    for (int c = 0; c < ILP; ++c) {
        e[c] = blockIdx.x * (256 * ILP) + c * 256 + threadIdx.x;
        v[c] = e[c] < n_elems;
        ii[c] = 0; jj[c] = 0; nx_i[c] = ENDTAG; nx_j[c] = ENDTAG;
    }

#pragma unroll
    for (int c = 0; c < ILP; ++c)
        if (v[c]) { const i2 ij = __builtin_nontemporal_load((const i2*)conn + e[c]); ii[c] = ij.x; jj[c] = ij.y; }

    // THE scattered op: one info-carrying atomicExch per endpoint (8 in flight)
#pragma unroll
    for (int c = 0; c < ILP; ++c)
        if (v[c]) {
            nx_i[c] = __hip_atomic_exchange(&head[ii[c]], ((unsigned)e[c] << 1),
                                            __ATOMIC_RELAXED, __HIP_MEMORY_SCOPE_AGENT);
            nx_j[c] = __hip_atomic_exchange(&head[jj[c]], ((unsigned)e[c] << 1) | 1u,
                                            __ATOMIC_RELAXED, __HIP_MEMORY_SCOPE_AGENT);
        }

    // node gathers (8 lines in flight; pack is L3-resident 32MB)
    NodeG ni[ILP], nj[ILP];
#pragma unroll
    for (int c = 0; c < ILP; ++c)
        if (v[c]) {
            if (PACKED) { ni[c] = gather_node_h(pack, ii[c]); nj[c] = gather_node_h(pack, jj[c]); }
            else        { ni[c] = gather_node_raw(pred, grad_ux, grad_uz, grad_phi, ii[c]);
                          nj[c] = gather_node_raw(pred, grad_ux, grad_uz, grad_phi, jj[c]); }
        }

#pragma unroll
    for (int c = 0; c < ILP; ++c)
        if (v[c]) {
            const int ec = e[c];
            const float x0 = __builtin_nontemporal_load(dirs + 3 * ec);
            const float x1 = __builtin_nontemporal_load(dirs + 3 * ec + 1);
            const float x2 = __builtin_nontemporal_load(dirs + 3 * ec + 2);
            const float Le = __builtin_nontemporal_load(elemL + ec);
            const float pE = __builtin_nontemporal_load(prop_E + ec);
            const float EA = pE * __builtin_nontemporal_load(prop_A + ec);
            const float EI = pE * __builtin_nontemporal_load(prop_I22 + ec);
            const float l0 = __builtin_nontemporal_load(load + 3 * ec);
            const float l1 = __builtin_nontemporal_load(load + 3 * ec + 1);
            const float l2 = __builtin_nontemporal_load(load + 3 * ec + 2);
            const ElemOut o = physics(ni[c], nj[c], x0, x1, x2, Le, EA, EI, l0, l1, l2);

            // fp16 payload record: streamed, cached (node pass wants L3 hits)
            u4* pw = (u4*)(payload + 8 * (size_t)ec);
            pw[0] = (u4){pkh(o.Fe0, o.Fe1), pkh(o.Fe2, o.Mi0),
                         pkh(o.Mi1, o.Mi2), pkh(o.Mj0, o.Mj1)};
            pw[1] = (u4){pkh(o.Mj2, o.E0), pkh(o.E1, o.E2), nx_i[c], nx_j[c]};

            elem_reduce_tail(o, s_rkin2, s_e1, s_e2, s_Lsum, m_q, m_L);
        }

    blockAtomicAddD(s_rkin2, &sc->rkin2, smD);
    blockAtomicAddD(s_e1,    &sc->e1,    smD);
    blockAtomicAddD(s_e2,    &sc->e2,    smD);
    blockAtomicAddD(s_Lsum,  &sc->Lsum,  smD);
    blockAtomicMaxF(m_q, &sc->qmax_bits, smF);
    blockAtomicMaxF(m_L, &sc->Lmax_bits, smF);
}

// ---------------------------------------------------------------------------
struct NodeAcc { float F0, F1, F2, M0, M1, M2, E0, E1, E2; };

__global__ __launch_bounds__(256) void node_ll(
    const unsigned* __restrict__ payload,
    const unsigned int* __restrict__ head,
    const float* __restrict__ bc_disp, const float* __restrict__ bc_rot,
    Scal* sc, int n_nodes)
{
    __shared__ double smD[4];
    __shared__ unsigned smU[4];

    double sFe2 = 0.0, sF2 = 0.0, sMr2 = 0.0, sMp2 = 0.0;
    unsigned cd = 0, cr = 0, cp = 0;

    int  k[ILP];
    bool fd[ILP], fr[ILP], pin[ILP];
    unsigned cur[ILP];
    NodeAcc A[ILP];

#pragma unroll
    for (int c = 0; c < ILP; ++c) {
        k[c] = blockIdx.x * (256 * ILP) + c * 256 + threadIdx.x;
        const bool vc = k[c] < n_nodes;
        float bd = 1.f, br = 1.f;
        if (vc) { bd = bc_disp[k[c]]; br = bc_rot[k[c]]; }
        fd[c] = vc && (bd < 0.5f);
        fr[c] = vc && (br < 0.5f);
        pin[c] = vc && (bd > 0.5f) && fr[c];
        cur[c] = ENDTAG;
        if (fd[c] | fr[c]) cur[c] = head[k[c]];   // coalesced head read
        A[c] = (NodeAcc){0,0,0,0,0,0,0,0,0};
    }

    // chase: up to ILP independent chains in flight per thread
    while (true) {
        bool any = false;
#pragma unroll
        for (int c = 0; c < ILP; ++c) any |= (cur[c] != ENDTAG);
        if (!any) break;

        u4 q0[ILP], q1[ILP];
#pragma unroll
        for (int c = 0; c < ILP; ++c)
            if (cur[c] != ENDTAG) {
                const u4* p = (const u4*)(payload + 8 * (size_t)(cur[c] >> 1));
                q0[c] = p[0]; q1[c] = p[1];
            }
#pragma unroll
        for (int c = 0; c < ILP; ++c)
            if (cur[c] != ENDTAG) {
                const bool side_j = cur[c] & 1u;
                const float2 Fe01 = unpkh(q0[c].x), Fe2Mi0 = unpkh(q0[c].y);
                const float2 Mi12 = unpkh(q0[c].z), Mj01 = unpkh(q0[c].w);
                const float2 Mj2E0 = unpkh(q1[c].x), E12 = unpkh(q1[c].y);
                const float sgn = side_j ? -1.0f : 1.0f;
                A[c].F0 += sgn * Fe01.x; A[c].F1 += sgn * Fe01.y; A[c].F2 += sgn * Fe2Mi0.x;
                if (side_j) { A[c].M0 += Mj01.x;   A[c].M1 += Mj01.y; A[c].M2 += Mj2E0.x; }
                else        { A[c].M0 += Fe2Mi0.y; A[c].M1 += Mi12.x; A[c].M2 += Mi12.y; }
                A[c].E0 += Mj2E0.y; A[c].E1 += E12.x; A[c].E2 += E12.y;
                cur[c] = side_j ? q1[c].w : q1[c].z;
            }
    }

#pragma unroll
    for (int c = 0; c < ILP; ++c) {
        if (fd[c]) {
            const float f0 = A[c].F0 + A[c].E0, f1 = A[c].F1 + A[c].E1, f2 = A[c].F2 + A[c].E2;
            sFe2 += (double)(A[c].E0 * A[c].E0 + A[c].E1 * A[c].E1 + A[c].E2 * A[c].E2);
            sF2  += (double)(f0 * f0 + f1 * f1 + f2 * f2);
            cd++;
        }
        const double mm = (double)(A[c].M0 * A[c].M0 + A[c].M1 * A[c].M1 + A[c].M2 * A[c].M2);
        if (fr[c])  { sMr2 += mm; cr++; }
        if (pin[c]) { sMp2 += mm; cp++; }
    }

    blockAtomicAddD(sFe2, &sc->Fe2, smD);
    blockAtomicAddD(sF2,  &sc->F2,  smD);
    blockAtomicAddD(sMr2, &sc->Mr2, smD);
    blockAtomicAddD(sMp2, &sc->Mp2, smD);
    blockAtomicAddU(cd, &sc->cnt_d, smU);
    blockAtomicAddU(cr, &sc->cnt_r, smU);
    blockAtomicAddU(cp, &sc->cnt_p, smU);
}

// --- last-resort fallback: R1-style SoA atomics ----------------------------
__global__ __launch_bounds__(256) void elem_soa(
    const float* __restrict__ pred, const float* __restrict__ grad_ux,
    const float* __restrict__ grad_uz, const float* __restrict__ grad_phi,
    const float* __restrict__ prop_E, const float* __restrict__ prop_A,
    const float* __restrict__ prop_I22, const float* __restrict__ elemL,
    const float* __restrict__ dirs, const float* __restrict__ load,
    const int* __restrict__ conn,
    float* __restrict__ Fi, float* __restrict__ Mi, float* __restrict__ Fe,
    Scal* sc, int n_elems)
{
    __shared__ double smD[4];
    __shared__ float  smF[4];
    double s_rkin2 = 0.0, s_e1 = 0.0, s_e2 = 0.0, s_Lsum = 0.0;
    float m_q = 0.0f, m_L = 0.0f;

    const int e = blockIdx.x * 256 + threadIdx.x;
    if (e < n_elems) {
        const i2 ij = __builtin_nontemporal_load((const i2*)conn + e);
        const int i = ij.x, j = ij.y;
        const NodeG ni = gather_node_raw(pred, grad_ux, grad_uz, grad_phi, i);
        const NodeG nj = gather_node_raw(pred, grad_ux, grad_uz, grad_phi, j);
        const float x0 = dirs[3 * e], x1 = dirs[3 * e + 1], x2 = dirs[3 * e + 2];
        const float Le = elemL[e];
        const float pE = prop_E[e];
        const float EA = pE * prop_A[e];
        const float EI = pE * prop_I22[e];
        const float l0 = load[3 * e], l1 = load[3 * e + 1], l2 = load[3 * e + 2];
        const ElemOut o = physics(ni, nj, x0, x1, x2, Le, EA, EI, l0, l1, l2);
        atomicAdd(&Fi[3 * i], o.Fe0);  atomicAdd(&Fi[3 * i + 1], o.Fe1);  atomicAdd(&Fi[3 * i + 2], o.Fe2);
        atomicAdd(&Fi[3 * j], -o.Fe0); atomicAdd(&Fi[3 * j + 1], -o.Fe1); atomicAdd(&Fi[3 * j + 2], -o.Fe2);
        atomicAdd(&Mi[3 * i], o.Mi0);  atomicAdd(&Mi[3 * i + 1], o.Mi1);  atomicAdd(&Mi[3 * i + 2], o.Mi2);
        atomicAdd(&Mi[3 * j], o.Mj0);  atomicAdd(&Mi[3 * j + 1], o.Mj1);  atomicAdd(&Mi[3 * j + 2], o.Mj2);
        atomicAdd(&Fe[3 * i], o.E0);   atomicAdd(&Fe[3 * i + 1], o.E1);   atomicAdd(&Fe[3 * i + 2], o.E2);
        atomicAdd(&Fe[3 * j], o.E0);   atomicAdd(&Fe[3 * j + 1], o.E1);   atomicAdd(&Fe[3 * j + 2], o.E2);
        elem_reduce_tail(o, s_rkin2, s_e1, s_e2, s_Lsum, m_q, m_L);
    }
    blockAtomicAddD(s_rkin2, &sc->rkin2, smD);
    blockAtomicAddD(s_e1,    &sc->e1,    smD);
    blockAtomicAddD(s_e2,    &sc->e2,    smD);
    blockAtomicAddD(s_Lsum,  &sc->Lsum,  smD);
    blockAtomicMaxF(m_q, &sc->qmax_bits, smF);
    blockAtomicMaxF(m_L, &sc->Lmax_bits, smF);
}

__global__ __launch_bounds__(256) void node_soa(
    const float* __restrict__ Fi, const float* __restrict__ Mi, const float* __restrict__ Fe,
    const float* __restrict__ bc_disp, const float* __restrict__ bc_rot,
    Scal* sc, int n_nodes)
{
    __shared__ double smD[4];
    __shared__ unsigned smU[4];
    double sFe2 = 0.0, sF2 = 0.0, sMr2 = 0.0, sMp2 = 0.0;
    unsigned cd = 0, cr = 0, cp = 0;

    const int k = blockIdx.x * 256 + threadIdx.x;
    if (k < n_nodes) {
        const float bd = bc_disp[k], br = bc_rot[k];
        const bool free_d = bd < 0.5f;
        const bool free_r = br < 0.5f;
        const bool pin    = (bd > 0.5f) && free_r;
        if (free_d) {
            const float e0 = Fe[3 * k], e1 = Fe[3 * k + 1], e2 = Fe[3 * k + 2];
            const float f0 = Fi[3 * k] + e0, f1 = Fi[3 * k + 1] + e1, f2 = Fi[3 * k + 2] + e2;
            sFe2 += (double)(e0 * e0 + e1 * e1 + e2 * e2);
            sF2  += (double)(f0 * f0 + f1 * f1 + f2 * f2);
            cd++;
        }
        if (free_r | pin) {
            const float m0 = Mi[3 * k], m1 = Mi[3 * k + 1], m2 = Mi[3 * k + 2];
            const double mm = (double)(m0 * m0 + m1 * m1 + m2 * m2);
            if (free_r) { sMr2 += mm; cr++; }
            if (pin)    { sMp2 += mm; cp++; }
        }
    }
    blockAtomicAddD(sFe2, &sc->Fe2, smD);
    blockAtomicAddD(sF2,  &sc->F2,  smD);
    blockAtomicAddD(sMr2, &sc->Mr2, smD);
    blockAtomicAddD(sMp2, &sc->Mp2, smD);
    blockAtomicAddU(cd, &sc->cnt_d, smU);
    blockAtomicAddU(cr, &sc->cnt_r, smU);
    blockAtomicAddU(cp, &sc->cnt_p, smU);
}

__global__ void finalize(const Scal* sc, float* out, int n_elems)
{
    const double cnt_d = (double)max(sc->cnt_d, 1u);
    const double cnt_r = (double)max(sc->cnt_r, 1u);
    const double cnt_p = (double)max(sc->cnt_p, 1u);

    const double F_char = fmax(sqrt(sc->Fe2 / (cnt_d * 3.0)), 1.0);
    const double L_force = sc->F2 / (cnt_d * 3.0) / (F_char * F_char);

    const double qmax = fmax((double)__uint_as_float(sc->qmax_bits), 1.0);
    const double Lmax = (double)__uint_as_float(sc->Lmax_bits);
    const double M_char = fmax(qmax * Lmax * sc->Lsum / 8.0, 1.0);

    const double L_moment  = sc->Mr2 / (cnt_r * 3.0) / (M_char * M_char);
    const double L_neumann = sc->Mp2 / (cnt_p * 3.0) / (M_char * M_char);

    const double inv_ne = 1.0 / (double)n_elems;
    const double L_kin = sc->rkin2 * inv_ne;
    const double L_consist = sc->e1 * inv_ne + sc->e2 * inv_ne;

    out[0] = (float)(L_force + L_moment + L_neumann + 0.1 * L_kin + L_consist);
}

extern "C" void kernel_launch(void* const* d_in, const int* in_sizes, int n_in,
                              void* d_out, int out_size, void* d_ws, size_t ws_size,
                              hipStream_t stream)
{
    const float* pred     = (const float*)d_in[0];
    const float* grad_ux  = (const float*)d_in[1];
    const float* grad_uz  = (const float*)d_in[2];
    const float* grad_phi = (const float*)d_in[3];
    const float* prop_E   = (const float*)d_in[4];
    const float* prop_A   = (const float*)d_in[5];
    const float* prop_I22 = (const float*)d_in[6];
    const float* elemL    = (const float*)d_in[7];
    const float* dirs     = (const float*)d_in[8];
    const float* load     = (const float*)d_in[9];
    const float* bc_disp  = (const float*)d_in[10];
    const float* bc_rot   = (const float*)d_in[11];
    const int*   conn     = (const int*)d_in[12];

    const int n_elems = in_sizes[4];
    const int n_nodes = in_sizes[10];
    const int nblkN  = (n_nodes + 255) / 256;
    const int perBlk = 256 * ILP;
    const int nblkE4 = (n_elems + perBlk - 1) / perBlk;
    const int nblkN4 = (n_nodes + perBlk - 1) / perBlk;

    const size_t szPack = (size_t)n_nodes * 32;                  // 32MB fp16
    const size_t szPay  = (size_t)n_elems * 32;                  // 64MB fp16
    const size_t szHead = (size_t)n_nodes * sizeof(unsigned);    // 4MB
    const size_t szTail = 256;

    char* base = (char*)d_ws;

    if (ws_size >= szPack + szPay + szHead + szTail) {
        // ---- tier A: fp16 pack + linked-list (100MB, L3-resident) ----
        unsigned*     pack    = (unsigned*)base;     base += szPack;
        unsigned*     payload = (unsigned*)base;     base += szPay;
        unsigned int* head    = (unsigned int*)base; base += szHead;
        Scal*         sc      = (Scal*)base;

        hipMemsetAsync(sc, 0, sizeof(Scal), stream);

        pack_nodes<<<nblkN, 256, 0, stream>>>(
            pred, grad_ux, grad_uz, grad_phi, pack, head, n_nodes);
        elem_ll<true><<<nblkE4, 256, 0, stream>>>(
            pred, grad_ux, grad_uz, grad_phi, pack,
            prop_E, prop_A, prop_I22, elemL, dirs, load, conn,
            payload, head, sc, n_elems);
        node_ll<<<nblkN4, 256, 0, stream>>>(
            payload, head, bc_disp, bc_rot, sc, n_nodes);
        finalize<<<1, 1, 0, stream>>>(sc, (float*)d_out, n_elems);
    } else if (ws_size >= szPay + szHead + szTail) {
        // ---- tier B: fp16 linked-list without pack (68MB) ----
        unsigned*     payload = (unsigned*)base;     base += szPay;
        unsigned int* head    = (unsigned int*)base; base += szHead;
        Scal*         sc      = (Scal*)base;

        hipMemsetAsync(head, 0xFF, szHead, stream);
        hipMemsetAsync(sc, 0, sizeof(Scal), stream);

        elem_ll<false><<<nblkE4, 256, 0, stream>>>(
            pred, grad_ux, grad_uz, grad_phi, nullptr,
            prop_E, prop_A, prop_I22, elemL, dirs, load, conn,
            payload, head, sc, n_elems);
        node_ll<<<nblkN4, 256, 0, stream>>>(
            payload, head, bc_disp, bc_rot, sc, n_nodes);
        finalize<<<1, 1, 0, stream>>>(sc, (float*)d_out, n_elems);
    } else {
        // ---- tier C: SoA atomic fallback (36MB) ----
        float* Fi = (float*)d_ws;
        float* Mi = Fi + (size_t)3 * n_nodes;
        float* Fe = Mi + (size_t)3 * n_nodes;
        const size_t nodeBytes = (size_t)9 * n_nodes * sizeof(float);
        Scal* sc = (Scal*)((char*)d_ws + nodeBytes);

        hipMemsetAsync(d_ws, 0, nodeBytes + sizeof(Scal), stream);

        elem_soa<<<(n_elems + 255) / 256, 256, 0, stream>>>(
            pred, grad_ux, grad_uz, grad_phi,
            prop_E, prop_A, prop_I22, elemL, dirs, load, conn,
            Fi, Mi, Fe, sc, n_elems);
        node_soa<<<nblkN, 256, 0, stream>>>(
            Fi, Mi, Fe, bc_disp, bc_rot, sc, n_nodes);
        finalize<<<1, 1, 0, stream>>>(sc, (float*)d_out, n_elems);
    }
}